// Round 1
// baseline (3501.617 us; speedup 1.0000x reference)
//
#include <hip/hip_runtime.h>
#include <math.h>

#define BATCH   8
#define LSEQ    197
#define NPATCH  196
#define NPTOK   (BATCH * NPATCH)   // 1568
#define NTOK    (BATCH * LSEQ)     // 1576
#define DMODEL  512
#define DINNER  1024
#define NSTATE  16
#define DRANK   32
#define NLAYER  8
#define NCLS    1000
#define PDIM    3840               // 16*16*15

__device__ __forceinline__ float sp_silu(float x) { return x / (1.0f + expf(-x)); }
__device__ __forceinline__ float sp_softplus(float x) {
    return x > 0.0f ? x + log1pf(expf(-x)) : log1pf(expf(x));
}

// 256-thread block reduction of two values; lds must be 8 floats.
__device__ __forceinline__ float2 block_reduce2(float a, float b, float* lds) {
#pragma unroll
    for (int off = 32; off > 0; off >>= 1) {
        a += __shfl_down(a, off);
        b += __shfl_down(b, off);
    }
    int lane = threadIdx.x & 63, w = threadIdx.x >> 6;
    if (lane == 0) { lds[w] = a; lds[4 + w] = b; }
    __syncthreads();
    float sa = lds[0] + lds[1] + lds[2] + lds[3];
    float sb = lds[4] + lds[5] + lds[6] + lds[7];
    return make_float2(sa, sb);
}

// ---------------------------------------------------------------- patch stage
// One block per patch token: gather 3840 vals (5 shift-groups x 3ch x 16x16),
// LayerNorm over the 3840, write normalized row to Xp.
__global__ __launch_bounds__(256) void k_patch_ln(
    const float* __restrict__ img, const float* __restrict__ lnw,
    const float* __restrict__ lnb, float* __restrict__ Xp) {
    __shared__ float vals[PDIM];
    __shared__ float red[8];
    int tok = blockIdx.x;
    int b = tok / NPATCH, p = tok % NPATCH;
    int gy = p / 14, gx = p % 14;
    int tid = threadIdx.x;
    int py = tid >> 4, px = tid & 15;
    int h0 = gy * 16 + py, w0 = gx * 16 + px;
    const int dh[5] = {0, 0, 0, -1, 1};
    const int dw[5] = {0, -1, 1, 0, 0};
    float s = 0.f, ss = 0.f;
#pragma unroll
    for (int c = 0; c < 15; ++c) {
        int g = c / 3, ch = c % 3;
        int h = h0 + dh[g], w = w0 + dw[g];
        float v = 0.f;
        if ((unsigned)h < 224u && (unsigned)w < 224u)
            v = img[((b * 3 + ch) * 224 + h) * 224 + w];
        vals[tid * 15 + c] = v;
        s += v; ss += v * v;
    }
    float2 t2 = block_reduce2(s, ss, red);   // internal syncthreads orders vals[]
    float mean = t2.x * (1.0f / PDIM);
    float var  = t2.y * (1.0f / PDIM) - mean * mean;
    float rstd = 1.0f / sqrtf(var + 1e-5f);
    for (int j = 0; j < 15; ++j) {
        int e = tid + j * 256;
        float v = vals[e];
        Xp[(size_t)tok * PDIM + e] = (v - mean) * rstd * lnw[e] + lnb[e];
    }
}

// ------------------------------------------------------------------- token LN
__global__ __launch_bounds__(256) void k_ln(
    const float* __restrict__ x, const float* __restrict__ w,
    const float* __restrict__ b, float* __restrict__ y) {
    __shared__ float red[8];
    int t = blockIdx.x, tid = threadIdx.x;
    const float* xr = x + (size_t)t * DMODEL;
    float v0 = xr[tid], v1 = xr[tid + 256];
    float2 t2 = block_reduce2(v0 + v1, v0 * v0 + v1 * v1, red);
    float mean = t2.x * (1.0f / DMODEL);
    float var  = t2.y * (1.0f / DMODEL) - mean * mean;
    float rstd = 1.0f / sqrtf(var + 1e-5f);
    float* yr = y + (size_t)t * DMODEL;
    yr[tid]       = (v0 - mean) * rstd * w[tid] + b[tid];
    yr[tid + 256] = (v1 - mean) * rstd * w[tid + 256] + b[tid + 256];
}

// ------------------------------------------------------ generic fp32 GEMM
// C[M,N] (=|+=) A[M,K] @ B[K,N]; 64x64 block tile, 16 K-tile, 4x4 per thread.
// Requires K%16==0, N%64==0 (M may be ragged).
template <bool ACC>
__global__ __launch_bounds__(256) void k_gemm(
    const float* __restrict__ A, const float* __restrict__ B,
    float* __restrict__ C, int M, int N, int K) {
    __shared__ float As[16][64];
    __shared__ float Bs[16][64];
    int tid = threadIdx.x;
    int m0 = blockIdx.y * 64, n0 = blockIdx.x * 64;
    int tm = tid >> 4, tn = tid & 15;
    int la_m = tid >> 2, la_k = (tid & 3) << 2;
    int lb_k = tid >> 4, lb_n = (tid & 15) << 2;
    float acc[4][4] = {};
    for (int k0 = 0; k0 < K; k0 += 16) {
        int gm = m0 + la_m;
        float4 av = make_float4(0.f, 0.f, 0.f, 0.f);
        if (gm < M) av = *(const float4*)(A + (size_t)gm * K + k0 + la_k);
        As[la_k + 0][la_m] = av.x;
        As[la_k + 1][la_m] = av.y;
        As[la_k + 2][la_m] = av.z;
        As[la_k + 3][la_m] = av.w;
        *(float4*)(&Bs[lb_k][lb_n]) =
            *(const float4*)(B + (size_t)(k0 + lb_k) * N + n0 + lb_n);
        __syncthreads();
#pragma unroll
        for (int k = 0; k < 16; ++k) {
            float4 a  = *(const float4*)(&As[k][tm << 2]);
            float4 bv = *(const float4*)(&Bs[k][tn << 2]);
            acc[0][0] += a.x * bv.x; acc[0][1] += a.x * bv.y;
            acc[0][2] += a.x * bv.z; acc[0][3] += a.x * bv.w;
            acc[1][0] += a.y * bv.x; acc[1][1] += a.y * bv.y;
            acc[1][2] += a.y * bv.z; acc[1][3] += a.y * bv.w;
            acc[2][0] += a.z * bv.x; acc[2][1] += a.z * bv.y;
            acc[2][2] += a.z * bv.z; acc[2][3] += a.z * bv.w;
            acc[3][0] += a.w * bv.x; acc[3][1] += a.w * bv.y;
            acc[3][2] += a.w * bv.z; acc[3][3] += a.w * bv.w;
        }
        __syncthreads();
    }
#pragma unroll
    for (int i = 0; i < 4; ++i) {
        int gm = m0 + (tm << 2) + i;
        if (gm < M) {
            float* row = C + (size_t)gm * N + n0 + (tn << 2);
#pragma unroll
            for (int j = 0; j < 4; ++j) {
                if (ACC) row[j] += acc[i][j]; else row[j] = acc[i][j];
            }
        }
    }
}

// ---------------------------------------------- assemble tokens (+cls, +pos)
__global__ __launch_bounds__(256) void k_assemble(
    const float* __restrict__ Pe, const float* __restrict__ patch_b,
    const float* __restrict__ cls, const float* __restrict__ pos,
    float* __restrict__ xtok) {
    int idx = blockIdx.x * 256 + threadIdx.x;
    if (idx >= NTOK * DMODEL) return;
    int d = idx % DMODEL;
    int t = (idx / DMODEL) % LSEQ;
    int b = idx / (DMODEL * LSEQ);
    float v = (t < NPATCH) ? (Pe[((size_t)b * NPATCH + t) * DMODEL + d] + patch_b[d])
                           : cls[d];
    xtok[idx] = v + pos[t * DMODEL + d];
}

// ------------------------------------------- causal depthwise conv (K=4)+SiLU
__global__ __launch_bounds__(256) void k_conv(
    const float* __restrict__ xz, const float* __restrict__ cw,
    const float* __restrict__ cb, float* __restrict__ u) {
    int d = blockIdx.x * 256 + threadIdx.x;   // 0..1023
    int b = blockIdx.y;
    float w0 = cw[d * 4 + 0], w1 = cw[d * 4 + 1],
          w2 = cw[d * 4 + 2], w3 = cw[d * 4 + 3];
    float bias = cb[d];
    float x0 = 0.f, x1 = 0.f, x2 = 0.f;
    for (int l = 0; l < LSEQ; ++l) {
        float x3 = xz[((size_t)(b * LSEQ + l)) * (2 * DINNER) + d];
        float c = bias + w0 * x0 + w1 * x1 + w2 * x2 + w3 * x3;
        u[(size_t)(b * LSEQ + l) * DINNER + d] = sp_silu(c);
        x0 = x1; x1 = x2; x2 = x3;
    }
}

// -------------------------------------------------- dt = softplus(dbc@dtw+b)
__global__ __launch_bounds__(256) void k_dt(
    const float* __restrict__ dbc, const float* __restrict__ dtw,
    const float* __restrict__ dtb, float* __restrict__ dt) {
    __shared__ float r[DRANK];
    int t = blockIdx.x, tid = threadIdx.x;
    if (tid < DRANK) r[tid] = dbc[(size_t)t * 64 + tid];
    __syncthreads();
#pragma unroll
    for (int j = 0; j < 4; ++j) {
        int d = tid + j * 256;
        float acc = dtb[d];
#pragma unroll
        for (int k = 0; k < DRANK; ++k) acc += r[k] * dtw[k * DINNER + d];
        dt[(size_t)t * DINNER + d] = sp_softplus(acc);
    }
}

// ------------------------------------------------------ selective scan (SSM)
__global__ __launch_bounds__(256) void k_scan(
    const float* __restrict__ dt, const float* __restrict__ u,
    const float* __restrict__ dbc, const float* __restrict__ Alog,
    const float* __restrict__ Dp, float* __restrict__ y) {
    int d = blockIdx.x * 256 + threadIdx.x;
    int b = blockIdx.y;
    float A[NSTATE];
#pragma unroll
    for (int n = 0; n < NSTATE; ++n) A[n] = -expf(Alog[d * NSTATE + n]);
    float Dv = Dp[d];
    float h[NSTATE];
#pragma unroll
    for (int n = 0; n < NSTATE; ++n) h[n] = 0.f;
    for (int l = 0; l < LSEQ; ++l) {
        int t = b * LSEQ + l;
        float dtv = dt[(size_t)t * DINNER + d];
        float uv  = u[(size_t)t * DINNER + d];
        float du = dtv * uv;
        const float* r = dbc + (size_t)t * 64;
        float yv = 0.f;
#pragma unroll
        for (int n = 0; n < NSTATE; ++n) {
            float hn = expf(dtv * A[n]) * h[n] + du * r[DRANK + n];
            h[n] = hn;
            yv += hn * r[DRANK + NSTATE + n];
        }
        y[(size_t)t * DINNER + d] = yv + uv * Dv;
    }
}

// ------------------------------------------------------------- gate y*silu(z)
__global__ __launch_bounds__(256) void k_gate(
    const float* __restrict__ y, const float* __restrict__ xz,
    float* __restrict__ g) {
    int idx = blockIdx.x * 256 + threadIdx.x;
    if (idx >= NTOK * DINNER) return;
    int t = idx / DINNER, d = idx % DINNER;
    float z = xz[(size_t)t * (2 * DINNER) + DINNER + d];
    g[idx] = y[idx] * sp_silu(z);
}

// ------------------------------------------------------------ head: LN + FC
__global__ __launch_bounds__(256) void k_head(
    const float* __restrict__ xtok, const float* __restrict__ lnw,
    const float* __restrict__ lnb, const float* __restrict__ hw,
    const float* __restrict__ hb, float* __restrict__ out) {
    __shared__ float red[8];
    __shared__ float xr[DMODEL];
    int b = blockIdx.y, tid = threadIdx.x;
    const float* row = xtok + ((size_t)(b * LSEQ + NPATCH)) * DMODEL;
    float v0 = row[tid], v1 = row[tid + 256];
    float2 t2 = block_reduce2(v0 + v1, v0 * v0 + v1 * v1, red);
    float mean = t2.x * (1.0f / DMODEL);
    float var  = t2.y * (1.0f / DMODEL) - mean * mean;
    float rstd = 1.0f / sqrtf(var + 1e-5f);
    xr[tid]       = (v0 - mean) * rstd * lnw[tid] + lnb[tid];
    xr[tid + 256] = (v1 - mean) * rstd * lnw[tid + 256] + lnb[tid + 256];
    __syncthreads();
    int c = blockIdx.x * 256 + tid;
    if (c < NCLS) {
        float acc = hb[c];
#pragma unroll 8
        for (int k = 0; k < DMODEL; ++k) acc += xr[k] * hw[k * NCLS + c];
        out[b * NCLS + c] = acc;
    }
}

extern "C" void kernel_launch(void* const* d_in, const int* in_sizes, int n_in,
                              void* d_out, int out_size, void* d_ws, size_t ws_size,
                              hipStream_t stream) {
    const float* img     = (const float*)d_in[0];
    const float* plnw    = (const float*)d_in[1];
    const float* plnb    = (const float*)d_in[2];
    const float* patch_w = (const float*)d_in[3];
    const float* patch_b = (const float*)d_in[4];
    const float* pos     = (const float*)d_in[5];
    const float* cls     = (const float*)d_in[6];
    const float* ln_w    = (const float*)d_in[7];
    const float* ln_b    = (const float*)d_in[8];
    const float* in_w    = (const float*)d_in[9];
    const float* conv_w  = (const float*)d_in[10];
    const float* conv_b  = (const float*)d_in[11];
    const float* xproj   = (const float*)d_in[12];
    const float* dt_w    = (const float*)d_in[13];
    const float* dt_b    = (const float*)d_in[14];
    const float* A_log   = (const float*)d_in[15];
    const float* Dp      = (const float*)d_in[16];
    const float* out_w   = (const float*)d_in[17];
    const float* hlnw    = (const float*)d_in[18];
    const float* hlnb    = (const float*)d_in[19];
    const float* head_w  = (const float*)d_in[20];
    const float* head_b  = (const float*)d_in[21];
    float* out = (float*)d_out;

    float* ws   = (float*)d_ws;
    float* xtok = ws;                                  // NTOK*DMODEL
    float* yln  = xtok + (size_t)NTOK * DMODEL;        // NTOK*DMODEL
    float* xz   = yln  + (size_t)NTOK * DMODEL;        // NTOK*2*DINNER
    float* u    = xz   + (size_t)NTOK * 2 * DINNER;    // NTOK*DINNER
    float* dbc  = u    + (size_t)NTOK * DINNER;        // NTOK*64
    float* dt   = dbc  + (size_t)NTOK * 64;            // NTOK*DINNER
    float* ysc  = dt   + (size_t)NTOK * DINNER;        // NTOK*DINNER
    float* Xp   = ysc  + (size_t)NTOK * DINNER;        // NPTOK*PDIM
    float* Pe   = Xp   + (size_t)NPTOK * PDIM;         // NPTOK*DMODEL

    // ---- patch embedding ----
    k_patch_ln<<<NPTOK, 256, 0, stream>>>(img, plnw, plnb, Xp);
    {
        dim3 g(DMODEL / 64, (NPTOK + 63) / 64);
        k_gemm<false><<<g, 256, 0, stream>>>(Xp, patch_w, Pe, NPTOK, DMODEL, PDIM);
    }
    k_assemble<<<(NTOK * DMODEL + 255) / 256, 256, 0, stream>>>(Pe, patch_b, cls, pos, xtok);

    // ---- mamba layers ----
    for (int i = 0; i < NLAYER; ++i) {
        k_ln<<<NTOK, 256, 0, stream>>>(xtok, ln_w + i * DMODEL, ln_b + i * DMODEL, yln);
        {
            dim3 g(2 * DINNER / 64, (NTOK + 63) / 64);
            k_gemm<false><<<g, 256, 0, stream>>>(
                yln, in_w + (size_t)i * DMODEL * 2 * DINNER, xz, NTOK, 2 * DINNER, DMODEL);
        }
        {
            dim3 g(DINNER / 256, BATCH);
            k_conv<<<g, 256, 0, stream>>>(xz, conv_w + (size_t)i * DINNER * 4,
                                          conv_b + (size_t)i * DINNER, u);
        }
        {
            dim3 g(1, (NTOK + 63) / 64);
            k_gemm<false><<<g, 256, 0, stream>>>(
                u, xproj + (size_t)i * DINNER * 64, dbc, NTOK, 64, DINNER);
        }
        k_dt<<<NTOK, 256, 0, stream>>>(dbc, dt_w + (size_t)i * DRANK * DINNER,
                                       dt_b + (size_t)i * DINNER, dt);
        {
            dim3 g(DINNER / 256, BATCH);
            k_scan<<<g, 256, 0, stream>>>(dt, u, dbc,
                                          A_log + (size_t)i * DINNER * NSTATE,
                                          Dp + (size_t)i * DINNER, ysc);
        }
        k_gate<<<(NTOK * DINNER + 255) / 256, 256, 0, stream>>>(ysc, xz, ysc);
        {
            dim3 g(DMODEL / 64, (NTOK + 63) / 64);
            k_gemm<true><<<g, 256, 0, stream>>>(
                ysc, out_w + (size_t)i * DINNER * DMODEL, xtok, NTOK, DMODEL, DINNER);
        }
    }

    // ---- head ----
    {
        dim3 g((NCLS + 255) / 256, BATCH);
        k_head<<<g, 256, 0, stream>>>(xtok, hlnw, hlnb, head_w, head_b, out);
    }
}

// Round 2
// 1577.859 us; speedup vs baseline: 2.2192x; 2.2192x over previous
//
#include <hip/hip_runtime.h>
#include <hip/hip_fp16.h>
#include <math.h>

#define BATCH   8
#define LSEQ    197
#define NPATCH  196
#define NPTOK   (BATCH * NPATCH)   // 1568
#define NTOK    (BATCH * LSEQ)     // 1576
#define MPAD    1664               // 13*128, padded row count for f16 act arrays
#define DMODEL  512
#define DINNER  1024
#define NSTATE  16
#define DRANK   32
#define NLAYER  8
#define NCLS    1000
#define PDIM    3840               // 16*16*15

typedef _Float16 f16x8 __attribute__((ext_vector_type(8)));
typedef float    f32x4 __attribute__((ext_vector_type(4)));

__device__ __forceinline__ float sp_silu(float x) { return x / (1.0f + expf(-x)); }
__device__ __forceinline__ float sp_softplus(float x) {
    return x > 0.0f ? x + log1pf(expf(-x)) : log1pf(expf(x));
}

// Store value v as f16 hi/lo split at swizzled position (row, k) of a [*][K] array.
// Swizzle: byte-in-row ^= (row&7)<<4  (permutes 16B blocks within 128B chunks).
__device__ __forceinline__ void store_split(char* __restrict__ Hb, char* __restrict__ Lb,
                                            int row, int k, int K, float v) {
    size_t byte = (size_t)row * (size_t)(K * 2) +
                  (size_t)(((unsigned)(k * 2)) ^ (unsigned)((row & 7) << 4));
    __half h = __float2half_rn(v);
    *(__half*)(Hb + byte) = h;
    *(__half*)(Lb + byte) = __float2half_rn((v - __half2float(h)) * 2048.0f);
}

// 256-thread block reduction of two values; lds must be 8 floats.
__device__ __forceinline__ float2 block_reduce2(float a, float b, float* lds) {
#pragma unroll
    for (int off = 32; off > 0; off >>= 1) {
        a += __shfl_down(a, off);
        b += __shfl_down(b, off);
    }
    int lane = threadIdx.x & 63, w = threadIdx.x >> 6;
    if (lane == 0) { lds[w] = a; lds[4 + w] = b; }
    __syncthreads();
    float sa = lds[0] + lds[1] + lds[2] + lds[3];
    float sb = lds[4] + lds[5] + lds[6] + lds[7];
    return make_float2(sa, sb);
}

// ---------------------------------------------------------------- patch stage
__global__ __launch_bounds__(256) void k_patch_ln(
    const float* __restrict__ img, const float* __restrict__ lnw,
    const float* __restrict__ lnb, char* __restrict__ Xph, char* __restrict__ Xpl) {
    __shared__ float vals[PDIM];
    __shared__ float red[8];
    int tok = blockIdx.x;
    int b = tok / NPATCH, p = tok % NPATCH;
    int gy = p / 14, gx = p % 14;
    int tid = threadIdx.x;
    int py = tid >> 4, px = tid & 15;
    int h0 = gy * 16 + py, w0 = gx * 16 + px;
    const int dh[5] = {0, 0, 0, -1, 1};
    const int dw[5] = {0, -1, 1, 0, 0};
    float s = 0.f, ss = 0.f;
#pragma unroll
    for (int c = 0; c < 15; ++c) {
        int g = c / 3, ch = c % 3;
        int h = h0 + dh[g], w = w0 + dw[g];
        float v = 0.f;
        if ((unsigned)h < 224u && (unsigned)w < 224u)
            v = img[((b * 3 + ch) * 224 + h) * 224 + w];
        vals[tid * 15 + c] = v;
        s += v; ss += v * v;
    }
    float2 t2 = block_reduce2(s, ss, red);
    float mean = t2.x * (1.0f / PDIM);
    float var  = t2.y * (1.0f / PDIM) - mean * mean;
    float rstd = 1.0f / sqrtf(var + 1e-5f);
    for (int j = 0; j < 15; ++j) {
        int e = tid + j * 256;
        float v = (vals[e] - mean) * rstd * lnw[e] + lnb[e];
        store_split(Xph, Xpl, tok, e, PDIM, v);
    }
}

// ------------------------------------------------------------------- token LN
__global__ __launch_bounds__(256) void k_ln(
    const float* __restrict__ x, const float* __restrict__ w,
    const float* __restrict__ b, char* __restrict__ yh, char* __restrict__ yl) {
    __shared__ float red[8];
    int t = blockIdx.x, tid = threadIdx.x;
    const float* xr = x + (size_t)t * DMODEL;
    float v0 = xr[tid], v1 = xr[tid + 256];
    float2 t2 = block_reduce2(v0 + v1, v0 * v0 + v1 * v1, red);
    float mean = t2.x * (1.0f / DMODEL);
    float var  = t2.y * (1.0f / DMODEL) - mean * mean;
    float rstd = 1.0f / sqrtf(var + 1e-5f);
    store_split(yh, yl, t, tid,       DMODEL, (v0 - mean) * rstd * w[tid]       + b[tid]);
    store_split(yh, yl, t, tid + 256, DMODEL, (v1 - mean) * rstd * w[tid + 256] + b[tid + 256]);
}

// --------------------------------------------- weight transpose + f16 split
// W [Ks][Ns] fp32 -> Th/Tl [n][Ks] f16, swizzled; grid (Npad/32, Ks/32, layers)
__global__ __launch_bounds__(256) void k_wT(
    const float* __restrict__ W, char* __restrict__ Th, char* __restrict__ Tl,
    int Ks, int Ns, size_t wStride, size_t tByteStride) {
    __shared__ float t[32][33];
    int z = blockIdx.z;
    const float* Wz = W + (size_t)z * wStride;
    char* ThZ = Th + (size_t)z * tByteStride;
    char* TlZ = Tl + (size_t)z * tByteStride;
    int n0 = blockIdx.x * 32, k0 = blockIdx.y * 32;
    int tx = threadIdx.x, ty = threadIdx.y;
#pragma unroll
    for (int r = 0; r < 4; ++r) {
        int k = k0 + ty + r * 8, n = n0 + tx;
        t[tx][ty + r * 8] = (n < Ns) ? Wz[(size_t)k * Ns + n] : 0.f;
    }
    __syncthreads();
#pragma unroll
    for (int r = 0; r < 4; ++r) {
        int n = n0 + ty + r * 8, k = k0 + tx;
        float v = t[ty + r * 8][tx];
        size_t byte = (size_t)n * (size_t)(Ks * 2) +
                      (size_t)(((unsigned)(k * 2)) ^ (unsigned)((n & 7) << 4));
        __half h = __float2half_rn(v);
        *(__half*)(ThZ + byte) = h;
        *(__half*)(TlZ + byte) = __float2half_rn((v - __half2float(h)) * 2048.0f);
    }
}

// ------------------------------------------------- f16 split-2 MFMA GEMM
// C[M][N] = A[M][K] @ B[K][N] where A = Ah + Al/2048, B^T rows in Bh/Bl.
// A: [MPAD][K] f16 swizzled; B: [Npad][K] f16 swizzled (pre-transposed).
// 128x128 tile, BK=64, 4 waves of 64x64. K-split via blockIdx.z (kchunk).
__global__ __launch_bounds__(256, 1) void k_gemm_f16s(
    const char* __restrict__ Ah, const char* __restrict__ Al,
    const char* __restrict__ Bh, const char* __restrict__ Bl,
    float* __restrict__ C, int M, int N, int K, int kchunk, long partStride) {
    __shared__ __half LAh[128 * 64], LAl[128 * 64], LBh[128 * 64], LBl[128 * 64];
    const int tid = threadIdx.x, w = tid >> 6, lane = tid & 63;
    const int m0 = blockIdx.y * 128, n0 = blockIdx.x * 128;
    const int kbeg = blockIdx.z * kchunk;
    int kend = kbeg + kchunk; if (kend > K) kend = K;
    C += (size_t)blockIdx.z * (size_t)partStride;
    const size_t K2 = (size_t)K * 2;
    const int srowBase = 32 * w;          // wave-uniform
    const int srLane = lane >> 3;         // 0..7
    const int scol = (lane & 7) * 16;

    f32x4 acch[4][4], accx[4][4];
#pragma unroll
    for (int i = 0; i < 4; ++i)
#pragma unroll
        for (int j = 0; j < 4; ++j) {
            acch[i][j] = (f32x4)(0.f); accx[i][j] = (f32x4)(0.f);
        }

    for (int k0 = kbeg; k0 < kend; k0 += 64) {
#pragma unroll
        for (int t = 0; t < 4; ++t) {
            int lr = srowBase + 8 * t;                 // uniform LDS row base
            size_t ao = (size_t)(m0 + lr + srLane) * K2 + (size_t)k0 * 2 + scol;
            size_t bo = (size_t)(n0 + lr + srLane) * K2 + (size_t)k0 * 2 + scol;
            __builtin_amdgcn_global_load_lds(
                (const __attribute__((address_space(1))) void*)(Ah + ao),
                (__attribute__((address_space(3))) void*)&LAh[lr * 64], 16, 0, 0);
            __builtin_amdgcn_global_load_lds(
                (const __attribute__((address_space(1))) void*)(Al + ao),
                (__attribute__((address_space(3))) void*)&LAl[lr * 64], 16, 0, 0);
            __builtin_amdgcn_global_load_lds(
                (const __attribute__((address_space(1))) void*)(Bh + bo),
                (__attribute__((address_space(3))) void*)&LBh[lr * 64], 16, 0, 0);
            __builtin_amdgcn_global_load_lds(
                (const __attribute__((address_space(1))) void*)(Bl + bo),
                (__attribute__((address_space(3))) void*)&LBl[lr * 64], 16, 0, 0);
        }
        asm volatile("s_waitcnt vmcnt(0)" ::: "memory");
        __syncthreads();

        const int wr = (w >> 1) * 64, wc = (w & 1) * 64;
        const int g = lane >> 4, r = lane & 15;
#pragma unroll
        for (int kk = 0; kk < 2; ++kk) {
            f16x8 afh[4], afl[4], bfh[4], bfl[4];
#pragma unroll
            for (int mf = 0; mf < 4; ++mf) {
                int row = wr + mf * 16 + r;
                int off = row * 128 + ((kk * 64 + g * 16) ^ ((row & 7) << 4));
                afh[mf] = *(const f16x8*)((const char*)LAh + off);
                afl[mf] = *(const f16x8*)((const char*)LAl + off);
            }
#pragma unroll
            for (int nf = 0; nf < 4; ++nf) {
                int row = wc + nf * 16 + r;
                int off = row * 128 + ((kk * 64 + g * 16) ^ ((row & 7) << 4));
                bfh[nf] = *(const f16x8*)((const char*)LBh + off);
                bfl[nf] = *(const f16x8*)((const char*)LBl + off);
            }
#pragma unroll
            for (int mf = 0; mf < 4; ++mf)
#pragma unroll
                for (int nf = 0; nf < 4; ++nf) {
                    acch[mf][nf] = __builtin_amdgcn_mfma_f32_16x16x32_f16(
                        afh[mf], bfh[nf], acch[mf][nf], 0, 0, 0);
                    accx[mf][nf] = __builtin_amdgcn_mfma_f32_16x16x32_f16(
                        afl[mf], bfh[nf], accx[mf][nf], 0, 0, 0);
                    accx[mf][nf] = __builtin_amdgcn_mfma_f32_16x16x32_f16(
                        afh[mf], bfl[nf], accx[mf][nf], 0, 0, 0);
                }
        }
        __syncthreads();
    }

    const int wr = (w >> 1) * 64, wc = (w & 1) * 64;
    const int g = lane >> 4, r = lane & 15;
#pragma unroll
    for (int mf = 0; mf < 4; ++mf)
#pragma unroll
        for (int nf = 0; nf < 4; ++nf)
#pragma unroll
            for (int e = 0; e < 4; ++e) {
                int gm = m0 + wr + mf * 16 + g * 4 + e;
                int gn = n0 + wc + nf * 16 + r;
                if (gm < M && gn < N)
                    C[(size_t)gm * N + gn] =
                        acch[mf][nf][e] + accx[mf][nf][e] * (1.0f / 2048.0f);
            }
}

// ------------------------------------------------------ split-K reduce
template <int SK, bool ACC>
__global__ __launch_bounds__(256) void k_reduce(
    const float* __restrict__ part, float* __restrict__ out, int total, int stride) {
    int i = blockIdx.x * 256 + threadIdx.x;
    if (i >= total) return;
    float s = 0.f;
#pragma unroll
    for (int k = 0; k < SK; ++k) s += part[(size_t)k * stride + i];
    out[i] = ACC ? out[i] + s : s;
}

// ---------------------------------------------- assemble tokens (+cls, +pos)
__global__ __launch_bounds__(256) void k_assemble(
    const float* __restrict__ Pe, const float* __restrict__ patch_b,
    const float* __restrict__ cls, const float* __restrict__ pos,
    float* __restrict__ xtok) {
    int idx = blockIdx.x * 256 + threadIdx.x;
    if (idx >= NTOK * DMODEL) return;
    int d = idx % DMODEL;
    int t = (idx / DMODEL) % LSEQ;
    int b = idx / (DMODEL * LSEQ);
    float v = (t < NPATCH) ? (Pe[((size_t)b * NPATCH + t) * DMODEL + d] + patch_b[d])
                           : cls[d];
    xtok[idx] = v + pos[t * DMODEL + d];
}

// ------------------------------- causal depthwise conv (K=4) + SiLU + split
__global__ __launch_bounds__(256) void k_conv(
    const float* __restrict__ xz, const float* __restrict__ cw,
    const float* __restrict__ cb, float* __restrict__ u,
    char* __restrict__ uh, char* __restrict__ ul) {
    int idx = blockIdx.x * 256 + threadIdx.x;
    if (idx >= NTOK * DINNER) return;
    int d = idx & (DINNER - 1);
    int t = idx >> 10;
    int l = t % LSEQ;
    float acc = cb[d];
#pragma unroll
    for (int j = 0; j < 4; ++j) {
        int ls = l - 3 + j;
        if (ls >= 0) acc += cw[d * 4 + j] * xz[(size_t)(t - 3 + j) * (2 * DINNER) + d];
    }
    float uv = sp_silu(acc);
    u[idx] = uv;
    store_split(uh, ul, t, d, DINNER, uv);
}

// -------------------------------------------------- dt = softplus(dbc@dtw+b)
__global__ __launch_bounds__(256) void k_dt(
    const float* __restrict__ dbc, const float* __restrict__ dtw,
    const float* __restrict__ dtb, float* __restrict__ dt) {
    __shared__ float r[DRANK];
    int t = blockIdx.x, tid = threadIdx.x;
    if (tid < DRANK) r[tid] = dbc[(size_t)t * 64 + tid];
    __syncthreads();
#pragma unroll
    for (int j = 0; j < 4; ++j) {
        int d = tid + j * 256;
        float acc = dtb[d];
#pragma unroll
        for (int k = 0; k < DRANK; ++k) acc += r[k] * dtw[k * DINNER + d];
        dt[(size_t)t * DINNER + d] = sp_softplus(acc);
    }
}

// --------------------------------------- selective scan, n-parallel (16 lanes)
__global__ __launch_bounds__(256) void k_scan(
    const float* __restrict__ dt, const float* __restrict__ u,
    const float* __restrict__ dbc, const float* __restrict__ Alog,
    const float* __restrict__ Dp, float* __restrict__ y) {
    int tid = threadIdx.x;
    int n = tid & 15, dsub = tid >> 4;
    int d = blockIdx.x * 16 + dsub;
    int b = blockIdx.y;
    float A = -expf(Alog[d * NSTATE + n]);
    float Dv = Dp[d];
    float hn = 0.f;
    for (int l = 0; l < LSEQ; ++l) {
        int t = b * LSEQ + l;
        float dtv = dt[(size_t)t * DINNER + d];
        float uv  = u[(size_t)t * DINNER + d];
        float Bn = dbc[(size_t)t * 64 + DRANK + n];
        float Cn = dbc[(size_t)t * 64 + DRANK + NSTATE + n];
        hn = expf(dtv * A) * hn + dtv * uv * Bn;
        float yv = hn * Cn;
        yv += __shfl_xor(yv, 1);
        yv += __shfl_xor(yv, 2);
        yv += __shfl_xor(yv, 4);
        yv += __shfl_xor(yv, 8);
        if (n == 0) y[(size_t)t * DINNER + d] = yv + uv * Dv;
    }
}

// ------------------------------------------------- gate y*silu(z) -> f16 split
__global__ __launch_bounds__(256) void k_gate(
    const float* __restrict__ y, const float* __restrict__ xz,
    char* __restrict__ gh, char* __restrict__ gl) {
    int idx = blockIdx.x * 256 + threadIdx.x;
    if (idx >= NTOK * DINNER) return;
    int t = idx >> 10, d = idx & (DINNER - 1);
    float z = xz[(size_t)t * (2 * DINNER) + DINNER + d];
    float gv = y[idx] * sp_silu(z);
    store_split(gh, gl, t, d, DINNER, gv);
}

// ------------------------------------------------------------ head: LN + FC
__global__ __launch_bounds__(256) void k_head(
    const float* __restrict__ xtok, const float* __restrict__ lnw,
    const float* __restrict__ lnb, const float* __restrict__ hw,
    const float* __restrict__ hb, float* __restrict__ out) {
    __shared__ float red[8];
    __shared__ float xr[DMODEL];
    int b = blockIdx.y, tid = threadIdx.x;
    const float* row = xtok + ((size_t)(b * LSEQ + NPATCH)) * DMODEL;
    float v0 = row[tid], v1 = row[tid + 256];
    float2 t2 = block_reduce2(v0 + v1, v0 * v0 + v1 * v1, red);
    float mean = t2.x * (1.0f / DMODEL);
    float var  = t2.y * (1.0f / DMODEL) - mean * mean;
    float rstd = 1.0f / sqrtf(var + 1e-5f);
    xr[tid]       = (v0 - mean) * rstd * lnw[tid] + lnb[tid];
    xr[tid + 256] = (v1 - mean) * rstd * lnw[tid + 256] + lnb[tid + 256];
    __syncthreads();
    int c = blockIdx.x * 256 + tid;
    if (c < NCLS) {
        float acc = hb[c];
#pragma unroll 8
        for (int k = 0; k < DMODEL; ++k) acc += xr[k] * hw[k * NCLS + c];
        out[b * NCLS + c] = acc;
    }
}

extern "C" void kernel_launch(void* const* d_in, const int* in_sizes, int n_in,
                              void* d_out, int out_size, void* d_ws, size_t ws_size,
                              hipStream_t stream) {
    const float* img     = (const float*)d_in[0];
    const float* plnw    = (const float*)d_in[1];
    const float* plnb    = (const float*)d_in[2];
    const float* patch_w = (const float*)d_in[3];
    const float* patch_b = (const float*)d_in[4];
    const float* pos     = (const float*)d_in[5];
    const float* cls     = (const float*)d_in[6];
    const float* ln_w    = (const float*)d_in[7];
    const float* ln_b    = (const float*)d_in[8];
    const float* in_w    = (const float*)d_in[9];
    const float* conv_w  = (const float*)d_in[10];
    const float* conv_b  = (const float*)d_in[11];
    const float* xproj   = (const float*)d_in[12];
    const float* dt_w    = (const float*)d_in[13];
    const float* dt_b    = (const float*)d_in[14];
    const float* A_log   = (const float*)d_in[15];
    const float* Dp      = (const float*)d_in[16];
    const float* out_w   = (const float*)d_in[17];
    const float* hlnw    = (const float*)d_in[18];
    const float* hlnb    = (const float*)d_in[19];
    const float* head_w  = (const float*)d_in[20];
    const float* head_b  = (const float*)d_in[21];
    float* out = (float*)d_out;

    char* p = (char*)d_ws;
    auto alloc = [&](size_t bytes) { char* r = p; p += (bytes + 255) & ~(size_t)255; return r; };
    float* xtok = (float*)alloc((size_t)NTOK * DMODEL * 4);
    float* xz   = (float*)alloc((size_t)NTOK * 2 * DINNER * 4);
    float* u    = (float*)alloc((size_t)NTOK * DINNER * 4);
    float* dbc  = (float*)alloc((size_t)NTOK * 64 * 4);
    float* dtb_ = (float*)alloc((size_t)NTOK * DINNER * 4);
    float* ysc  = (float*)alloc((size_t)NTOK * DINNER * 4);
    float* Pe   = (float*)alloc((size_t)NPTOK * DMODEL * 4);
    float* part = (float*)alloc((size_t)4 * NTOK * DMODEL * 4);
    char* ylnH = alloc((size_t)MPAD * DMODEL * 2);
    char* ylnL = alloc((size_t)MPAD * DMODEL * 2);
    char* uH   = alloc((size_t)MPAD * DINNER * 2);
    char* uL   = alloc((size_t)MPAD * DINNER * 2);
    char* gH   = alloc((size_t)MPAD * DINNER * 2);
    char* gL   = alloc((size_t)MPAD * DINNER * 2);
    char* XpH  = alloc((size_t)MPAD * PDIM * 2);
    char* XpL  = alloc((size_t)MPAD * PDIM * 2);
    char* inTH  = alloc((size_t)NLAYER * 2 * DINNER * DMODEL * 2);
    char* inTL  = alloc((size_t)NLAYER * 2 * DINNER * DMODEL * 2);
    char* outTH = alloc((size_t)NLAYER * DMODEL * DINNER * 2);
    char* outTL = alloc((size_t)NLAYER * DMODEL * DINNER * 2);
    char* patTH = alloc((size_t)DMODEL * PDIM * 2);
    char* patTL = alloc((size_t)DMODEL * PDIM * 2);
    char* xprTH = alloc((size_t)NLAYER * 128 * DINNER * 2);
    char* xprTL = alloc((size_t)NLAYER * 128 * DINNER * 2);

    const size_t IN_T_B  = (size_t)2 * DINNER * DMODEL * 2;   // bytes/layer
    const size_t OUT_T_B = (size_t)DMODEL * DINNER * 2;
    const size_t XPR_T_B = (size_t)128 * DINNER * 2;

    // ---- one-time weight transpose + split (per call) ----
    k_wT<<<dim3(2 * DINNER / 32, DMODEL / 32, NLAYER), dim3(32, 8), 0, stream>>>(
        in_w, inTH, inTL, DMODEL, 2 * DINNER, (size_t)DMODEL * 2 * DINNER, IN_T_B);
    k_wT<<<dim3(DMODEL / 32, DINNER / 32, NLAYER), dim3(32, 8), 0, stream>>>(
        out_w, outTH, outTL, DINNER, DMODEL, (size_t)DINNER * DMODEL, OUT_T_B);
    k_wT<<<dim3(DMODEL / 32, PDIM / 32, 1), dim3(32, 8), 0, stream>>>(
        patch_w, patTH, patTL, PDIM, DMODEL, 0, 0);
    k_wT<<<dim3(128 / 32, DINNER / 32, NLAYER), dim3(32, 8), 0, stream>>>(
        xproj, xprTH, xprTL, DINNER, 64, (size_t)DINNER * 64, XPR_T_B);

    // ---- patch embedding ----
    k_patch_ln<<<NPTOK, 256, 0, stream>>>(img, plnw, plnb, XpH, XpL);
    k_gemm_f16s<<<dim3(4, 13, 4), 256, 0, stream>>>(
        XpH, XpL, patTH, patTL, part, NPTOK, DMODEL, PDIM, 960, (long)NPTOK * DMODEL);
    k_reduce<4, false><<<(NPTOK * DMODEL + 255) / 256, 256, 0, stream>>>(
        part, Pe, NPTOK * DMODEL, NPTOK * DMODEL);
    k_assemble<<<(NTOK * DMODEL + 255) / 256, 256, 0, stream>>>(Pe, patch_b, cls, pos, xtok);

    // ---- mamba layers ----
    for (int i = 0; i < NLAYER; ++i) {
        k_ln<<<NTOK, 256, 0, stream>>>(xtok, ln_w + i * DMODEL, ln_b + i * DMODEL, ylnH, ylnL);
        k_gemm_f16s<<<dim3(16, 13, 1), 256, 0, stream>>>(
            ylnH, ylnL, inTH + i * IN_T_B, inTL + i * IN_T_B,
            xz, NTOK, 2 * DINNER, DMODEL, DMODEL, 0);
        k_conv<<<(NTOK * DINNER) / 256, 256, 0, stream>>>(
            xz, conv_w + (size_t)i * DINNER * 4, conv_b + (size_t)i * DINNER, u, uH, uL);
        k_gemm_f16s<<<dim3(1, 13, 8), 256, 0, stream>>>(
            uH, uL, xprTH + i * XPR_T_B, xprTL + i * XPR_T_B,
            part, NTOK, 64, DINNER, 128, (long)NTOK * 64);
        k_reduce<8, false><<<(NTOK * 64 + 255) / 256, 256, 0, stream>>>(
            part, dbc, NTOK * 64, NTOK * 64);
        k_dt<<<NTOK, 256, 0, stream>>>(dbc, dt_w + (size_t)i * DRANK * DINNER,
                                       dt_b + (size_t)i * DINNER, dtb_);
        k_scan<<<dim3(DINNER / 16, BATCH), 256, 0, stream>>>(
            dtb_, u, dbc, A_log + (size_t)i * DINNER * NSTATE, Dp + (size_t)i * DINNER, ysc);
        k_gate<<<(NTOK * DINNER) / 256, 256, 0, stream>>>(ysc, xz, gH, gL);
        k_gemm_f16s<<<dim3(4, 13, 4), 256, 0, stream>>>(
            gH, gL, outTH + i * OUT_T_B, outTL + i * OUT_T_B,
            part, NTOK, DMODEL, DINNER, 256, (long)NTOK * DMODEL);
        k_reduce<4, true><<<(NTOK * DMODEL + 255) / 256, 256, 0, stream>>>(
            part, xtok, NTOK * DMODEL, NTOK * DMODEL);
    }

    // ---- head ----
    k_head<<<dim3((NCLS + 255) / 256, BATCH), 256, 0, stream>>>(
        xtok, hlnw, hlnb, head_w, head_b, out);
}

// Round 5
// 1181.782 us; speedup vs baseline: 2.9630x; 1.3352x over previous
//
#include <hip/hip_runtime.h>
#include <hip/hip_fp16.h>
#include <math.h>

#define BATCH   8
#define LSEQ    197
#define NPATCH  196
#define NPTOK   (BATCH * NPATCH)   // 1568
#define NTOK    (BATCH * LSEQ)     // 1576
#define MPAD    1664               // 13*128, padded row count for f16 act arrays
#define DMODEL  512
#define DINNER  1024
#define NSTATE  16
#define DRANK   32
#define NLAYER  8
#define NCLS    1000
#define PDIM    3840               // 16*16*15

typedef _Float16 f16x8 __attribute__((ext_vector_type(8)));
typedef float    f32x4 __attribute__((ext_vector_type(4)));

__device__ __forceinline__ float sp_silu(float x) { return x / (1.0f + expf(-x)); }
__device__ __forceinline__ float sp_softplus(float x) {
    return x > 0.0f ? x + log1pf(expf(-x)) : log1pf(expf(x));
}

// Store value v as f16 hi/lo split at swizzled position (row, k) of a [*][K] array.
// Swizzle: byte-in-row ^= (row&7)<<4  (permutes 16B blocks within 128B chunks).
__device__ __forceinline__ void store_split(char* __restrict__ Hb, char* __restrict__ Lb,
                                            int row, int k, int K, float v) {
    size_t byte = (size_t)row * (size_t)(K * 2) +
                  (size_t)(((unsigned)(k * 2)) ^ (unsigned)((row & 7) << 4));
    __half h = __float2half_rn(v);
    *(__half*)(Hb + byte) = h;
    *(__half*)(Lb + byte) = __float2half_rn((v - __half2float(h)) * 2048.0f);
}

// 256-thread block reduction of two values; lds must be 8 floats.
__device__ __forceinline__ float2 block_reduce2(float a, float b, float* lds) {
#pragma unroll
    for (int off = 32; off > 0; off >>= 1) {
        a += __shfl_down(a, off);
        b += __shfl_down(b, off);
    }
    int lane = threadIdx.x & 63, w = threadIdx.x >> 6;
    if (lane == 0) { lds[w] = a; lds[4 + w] = b; }
    __syncthreads();
    float sa = lds[0] + lds[1] + lds[2] + lds[3];
    float sb = lds[4] + lds[5] + lds[6] + lds[7];
    return make_float2(sa, sb);
}

// ---------------------------------------------------------------- patch stage
__global__ __launch_bounds__(256) void k_patch_ln(
    const float* __restrict__ img, const float* __restrict__ lnw,
    const float* __restrict__ lnb, char* __restrict__ Xph, char* __restrict__ Xpl) {
    __shared__ float vals[PDIM];
    __shared__ float red[8];
    int tok = blockIdx.x;
    int b = tok / NPATCH, p = tok % NPATCH;
    int gy = p / 14, gx = p % 14;
    int tid = threadIdx.x;
    int py = tid >> 4, px = tid & 15;
    int h0 = gy * 16 + py, w0 = gx * 16 + px;
    const int dh[5] = {0, 0, 0, -1, 1};
    const int dw[5] = {0, -1, 1, 0, 0};
    float s = 0.f, ss = 0.f;
#pragma unroll
    for (int c = 0; c < 15; ++c) {
        int g = c / 3, ch = c % 3;
        int h = h0 + dh[g], w = w0 + dw[g];
        float v = 0.f;
        if ((unsigned)h < 224u && (unsigned)w < 224u)
            v = img[((b * 3 + ch) * 224 + h) * 224 + w];
        vals[tid * 15 + c] = v;
        s += v; ss += v * v;
    }
    float2 t2 = block_reduce2(s, ss, red);
    float mean = t2.x * (1.0f / PDIM);
    float var  = t2.y * (1.0f / PDIM) - mean * mean;
    float rstd = 1.0f / sqrtf(var + 1e-5f);
    for (int j = 0; j < 15; ++j) {
        int e = tid + j * 256;
        float v = (vals[e] - mean) * rstd * lnw[e] + lnb[e];
        store_split(Xph, Xpl, tok, e, PDIM, v);
    }
}

// ------------------------------------------------------------------- token LN
__global__ __launch_bounds__(256) void k_ln(
    const float* __restrict__ x, const float* __restrict__ w,
    const float* __restrict__ b, char* __restrict__ yh, char* __restrict__ yl) {
    __shared__ float red[8];
    int t = blockIdx.x, tid = threadIdx.x;
    const float* xr = x + (size_t)t * DMODEL;
    float v0 = xr[tid], v1 = xr[tid + 256];
    float2 t2 = block_reduce2(v0 + v1, v0 * v0 + v1 * v1, red);
    float mean = t2.x * (1.0f / DMODEL);
    float var  = t2.y * (1.0f / DMODEL) - mean * mean;
    float rstd = 1.0f / sqrtf(var + 1e-5f);
    store_split(yh, yl, t, tid,       DMODEL, (v0 - mean) * rstd * w[tid]       + b[tid]);
    store_split(yh, yl, t, tid + 256, DMODEL, (v1 - mean) * rstd * w[tid + 256] + b[tid + 256]);
}

// --------------------------------------------- weight transpose + f16 split
// W [Ks][Ns] fp32 -> Th/Tl [n][Ks] f16, swizzled; grid (Npad/32, Ks/32, layers)
__global__ __launch_bounds__(256) void k_wT(
    const float* __restrict__ W, char* __restrict__ Th, char* __restrict__ Tl,
    int Ks, int Ns, size_t wStride, size_t tByteStride) {
    __shared__ float t[32][33];
    int z = blockIdx.z;
    const float* Wz = W + (size_t)z * wStride;
    char* ThZ = Th + (size_t)z * tByteStride;
    char* TlZ = Tl + (size_t)z * tByteStride;
    int n0 = blockIdx.x * 32, k0 = blockIdx.y * 32;
    int tx = threadIdx.x, ty = threadIdx.y;
#pragma unroll
    for (int r = 0; r < 4; ++r) {
        int k = k0 + ty + r * 8, n = n0 + tx;
        t[tx][ty + r * 8] = (n < Ns) ? Wz[(size_t)k * Ns + n] : 0.f;
    }
    __syncthreads();
#pragma unroll
    for (int r = 0; r < 4; ++r) {
        int n = n0 + ty + r * 8, k = k0 + tx;
        float v = t[ty + r * 8][tx];
        size_t byte = (size_t)n * (size_t)(Ks * 2) +
                      (size_t)(((unsigned)(k * 2)) ^ (unsigned)((n & 7) << 4));
        __half h = __float2half_rn(v);
        *(__half*)(ThZ + byte) = h;
        *(__half*)(TlZ + byte) = __float2half_rn((v - __half2float(h)) * 2048.0f);
    }
}

// ------------------------------------------------- f16 split-2 MFMA GEMM
// C[M][N] = A[M][K] @ B[K][N] where A = Ah + Al/2048, B^T rows in Bh/Bl.
// A: [MPAD][K] f16 swizzled; B: [Npad][K] f16 swizzled (pre-transposed).
// 128x128 tile, BK=64, 4 waves of 64x64. K-split via blockIdx.z (kchunk).
__global__ __launch_bounds__(256, 1) void k_gemm_f16s(
    const char* __restrict__ Ah, const char* __restrict__ Al,
    const char* __restrict__ Bh, const char* __restrict__ Bl,
    float* __restrict__ C, int M, int N, int K, int kchunk, long partStride) {
    __shared__ __half LAh[128 * 64], LAl[128 * 64], LBh[128 * 64], LBl[128 * 64];
    const int tid = threadIdx.x, w = tid >> 6, lane = tid & 63;
    const int m0 = blockIdx.y * 128, n0 = blockIdx.x * 128;
    const int kbeg = blockIdx.z * kchunk;
    int kend = kbeg + kchunk; if (kend > K) kend = K;
    C += (size_t)blockIdx.z * (size_t)partStride;
    const size_t K2 = (size_t)K * 2;
    const int srowBase = 32 * w;          // wave-uniform
    const int srLane = lane >> 3;         // 0..7
    const int scol = (lane & 7) * 16;

    f32x4 acch[4][4], accx[4][4];
#pragma unroll
    for (int i = 0; i < 4; ++i)
#pragma unroll
        for (int j = 0; j < 4; ++j) {
            acch[i][j] = (f32x4)(0.f); accx[i][j] = (f32x4)(0.f);
        }

    for (int k0 = kbeg; k0 < kend; k0 += 64) {
#pragma unroll
        for (int t = 0; t < 4; ++t) {
            int lr = srowBase + 8 * t;                 // uniform LDS row base
            size_t ao = (size_t)(m0 + lr + srLane) * K2 + (size_t)k0 * 2 + scol;
            size_t bo = (size_t)(n0 + lr + srLane) * K2 + (size_t)k0 * 2 + scol;
            __builtin_amdgcn_global_load_lds(
                (const __attribute__((address_space(1))) void*)(Ah + ao),
                (__attribute__((address_space(3))) void*)&LAh[lr * 64], 16, 0, 0);
            __builtin_amdgcn_global_load_lds(
                (const __attribute__((address_space(1))) void*)(Al + ao),
                (__attribute__((address_space(3))) void*)&LAl[lr * 64], 16, 0, 0);
            __builtin_amdgcn_global_load_lds(
                (const __attribute__((address_space(1))) void*)(Bh + bo),
                (__attribute__((address_space(3))) void*)&LBh[lr * 64], 16, 0, 0);
            __builtin_amdgcn_global_load_lds(
                (const __attribute__((address_space(1))) void*)(Bl + bo),
                (__attribute__((address_space(3))) void*)&LBl[lr * 64], 16, 0, 0);
        }
        asm volatile("s_waitcnt vmcnt(0)" ::: "memory");
        __syncthreads();

        const int wr = (w >> 1) * 64, wc = (w & 1) * 64;
        const int g = lane >> 4, r = lane & 15;
#pragma unroll
        for (int kk = 0; kk < 2; ++kk) {
            f16x8 afh[4], afl[4], bfh[4], bfl[4];
#pragma unroll
            for (int mf = 0; mf < 4; ++mf) {
                int row = wr + mf * 16 + r;
                int off = row * 128 + ((kk * 64 + g * 16) ^ ((row & 7) << 4));
                afh[mf] = *(const f16x8*)((const char*)LAh + off);
                afl[mf] = *(const f16x8*)((const char*)LAl + off);
            }
#pragma unroll
            for (int nf = 0; nf < 4; ++nf) {
                int row = wc + nf * 16 + r;
                int off = row * 128 + ((kk * 64 + g * 16) ^ ((row & 7) << 4));
                bfh[nf] = *(const f16x8*)((const char*)LBh + off);
                bfl[nf] = *(const f16x8*)((const char*)LBl + off);
            }
#pragma unroll
            for (int mf = 0; mf < 4; ++mf)
#pragma unroll
                for (int nf = 0; nf < 4; ++nf) {
                    acch[mf][nf] = __builtin_amdgcn_mfma_f32_16x16x32_f16(
                        afh[mf], bfh[nf], acch[mf][nf], 0, 0, 0);
                    accx[mf][nf] = __builtin_amdgcn_mfma_f32_16x16x32_f16(
                        afl[mf], bfh[nf], accx[mf][nf], 0, 0, 0);
                    accx[mf][nf] = __builtin_amdgcn_mfma_f32_16x16x32_f16(
                        afh[mf], bfl[nf], accx[mf][nf], 0, 0, 0);
                }
        }
        __syncthreads();
    }

    const int wr = (w >> 1) * 64, wc = (w & 1) * 64;
    const int g = lane >> 4, r = lane & 15;
#pragma unroll
    for (int mf = 0; mf < 4; ++mf)
#pragma unroll
        for (int nf = 0; nf < 4; ++nf)
#pragma unroll
            for (int e = 0; e < 4; ++e) {
                int gm = m0 + wr + mf * 16 + g * 4 + e;
                int gn = n0 + wc + nf * 16 + r;
                if (gm < M && gn < N)
                    C[(size_t)gm * N + gn] =
                        acch[mf][nf][e] + accx[mf][nf][e] * (1.0f / 2048.0f);
            }
}

// ------------------------------------------------------ split-K reduce
template <int SK, bool ACC>
__global__ __launch_bounds__(256) void k_reduce(
    const float* __restrict__ part, float* __restrict__ out, int total, int stride) {
    int i = blockIdx.x * 256 + threadIdx.x;
    if (i >= total) return;
    float s = 0.f;
#pragma unroll
    for (int k = 0; k < SK; ++k) s += part[(size_t)k * stride + i];
    out[i] = ACC ? out[i] + s : s;
}

// ---------------------------------------------- assemble tokens (+cls, +pos)
__global__ __launch_bounds__(256) void k_assemble(
    const float* __restrict__ Pe, const float* __restrict__ patch_b,
    const float* __restrict__ cls, const float* __restrict__ pos,
    float* __restrict__ xtok) {
    int idx = blockIdx.x * 256 + threadIdx.x;
    if (idx >= NTOK * DMODEL) return;
    int d = idx % DMODEL;
    int t = (idx / DMODEL) % LSEQ;
    int b = idx / (DMODEL * LSEQ);
    float v = (t < NPATCH) ? (Pe[((size_t)b * NPATCH + t) * DMODEL + d] + patch_b[d])
                           : cls[d];
    xtok[idx] = v + pos[t * DMODEL + d];
}

// ------------------------------- causal depthwise conv (K=4) + SiLU + split
__global__ __launch_bounds__(256) void k_conv(
    const float* __restrict__ xz, const float* __restrict__ cw,
    const float* __restrict__ cb, float* __restrict__ u,
    char* __restrict__ uh, char* __restrict__ ul) {
    int idx = blockIdx.x * 256 + threadIdx.x;
    if (idx >= NTOK * DINNER) return;
    int d = idx & (DINNER - 1);
    int t = idx >> 10;
    int l = t % LSEQ;
    float acc = cb[d];
#pragma unroll
    for (int j = 0; j < 4; ++j) {
        int ls = l - 3 + j;
        if (ls >= 0) acc += cw[d * 4 + j] * xz[(size_t)(t - 3 + j) * (2 * DINNER) + d];
    }
    float uv = sp_silu(acc);
    u[idx] = uv;
    store_split(uh, ul, t, d, DINNER, uv);
}

// -------------------------------------------------- dt = softplus(dbc@dtw+b)
__global__ __launch_bounds__(256) void k_dt(
    const float* __restrict__ dbc, const float* __restrict__ dtw,
    const float* __restrict__ dtb, float* __restrict__ dt) {
    __shared__ float r[DRANK];
    int t = blockIdx.x, tid = threadIdx.x;
    if (tid < DRANK) r[tid] = dbc[(size_t)t * 64 + tid];
    __syncthreads();
#pragma unroll
    for (int j = 0; j < 4; ++j) {
        int d = tid + j * 256;
        float acc = dtb[d];
#pragma unroll
        for (int k = 0; k < DRANK; ++k) acc += r[k] * dtw[k * DINNER + d];
        dt[(size_t)t * DINNER + d] = sp_softplus(acc);
    }
}

// ---------------- selective scan v2: LDS-staged + fused gate + f16-split out
// grid (DINNER/16, BATCH), 256 thr. LDS: u/dt/B/C slices (197x16 each).
__global__ __launch_bounds__(256) void k_scan2(
    const float* __restrict__ dt, const float* __restrict__ u,
    const float* __restrict__ dbc, const float* __restrict__ Alog,
    const float* __restrict__ Dp, const float* __restrict__ xz,
    char* __restrict__ gh, char* __restrict__ gl) {
    __shared__ float uS[LSEQ * 16];
    __shared__ float dS[LSEQ * 16];   // dt in, y out (slot l dead after iter l)
    __shared__ float bS[LSEQ * 16];
    __shared__ float cS[LSEQ * 16];
    const int tid = threadIdx.x;
    const int b = blockIdx.y, d0 = blockIdx.x * 16;

    const float* ub  = u   + ((size_t)b * LSEQ) * DINNER + d0;
    const float* db  = dt  + ((size_t)b * LSEQ) * DINNER + d0;
    const float* dcb = dbc + ((size_t)b * LSEQ) * 64 + DRANK;
    for (int i = tid; i < LSEQ * 4; i += 256) {
        int l = i >> 2, j = (i & 3) << 2;
        *(float4*)&uS[l * 16 + j] = *(const float4*)&ub[(size_t)l * DINNER + j];
        *(float4*)&dS[l * 16 + j] = *(const float4*)&db[(size_t)l * DINNER + j];
        *(float4*)&bS[l * 16 + j] = *(const float4*)&dcb[(size_t)l * 64 + j];
        *(float4*)&cS[l * 16 + j] = *(const float4*)&dcb[(size_t)l * 64 + 16 + j];
    }
    const int n = tid & 15, dsub = tid >> 4;
    const int d = d0 + dsub;
    const float A  = -expf(Alog[d * NSTATE + n]);
    const float Dv = Dp[d];
    __syncthreads();

    float hn = 0.f;
    for (int l = 0; l < LSEQ; ++l) {
        float dtv = dS[l * 16 + dsub];
        float uv  = uS[l * 16 + dsub];
        float Bn  = bS[l * 16 + n];
        float Cn  = cS[l * 16 + n];
        hn = __expf(dtv * A) * hn + dtv * uv * Bn;
        float yv = hn * Cn;
        yv += __shfl_xor(yv, 1);
        yv += __shfl_xor(yv, 2);
        yv += __shfl_xor(yv, 4);
        yv += __shfl_xor(yv, 8);
        if (n == 0) dS[l * 16 + dsub] = yv + uv * Dv;   // own dsub column only
    }
    __syncthreads();

    // fused gate: g = y * silu(z); write f16 hi/lo swizzled
    const float* zb = xz + ((size_t)b * LSEQ) * (2 * DINNER) + DINNER + d0;
    for (int i = tid; i < LSEQ * 4; i += 256) {
        int l = i >> 2, j = (i & 3) << 2;
        float4 z4 = *(const float4*)&zb[(size_t)l * (2 * DINNER) + j];
        int t = b * LSEQ + l;
        store_split(gh, gl, t, d0 + j + 0, DINNER, dS[l * 16 + j + 0] * sp_silu(z4.x));
        store_split(gh, gl, t, d0 + j + 1, DINNER, dS[l * 16 + j + 1] * sp_silu(z4.y));
        store_split(gh, gl, t, d0 + j + 2, DINNER, dS[l * 16 + j + 2] * sp_silu(z4.z));
        store_split(gh, gl, t, d0 + j + 3, DINNER, dS[l * 16 + j + 3] * sp_silu(z4.w));
    }
}

// ------------------------------------------------------------ head: LN + FC
__global__ __launch_bounds__(256) void k_head(
    const float* __restrict__ xtok, const float* __restrict__ lnw,
    const float* __restrict__ lnb, const float* __restrict__ hw,
    const float* __restrict__ hb, float* __restrict__ out) {
    __shared__ float red[8];
    __shared__ float xr[DMODEL];
    int b = blockIdx.y, tid = threadIdx.x;
    const float* row = xtok + ((size_t)(b * LSEQ + NPATCH)) * DMODEL;
    float v0 = row[tid], v1 = row[tid + 256];
    float2 t2 = block_reduce2(v0 + v1, v0 * v0 + v1 * v1, red);
    float mean = t2.x * (1.0f / DMODEL);
    float var  = t2.y * (1.0f / DMODEL) - mean * mean;
    float rstd = 1.0f / sqrtf(var + 1e-5f);
    xr[tid]       = (v0 - mean) * rstd * lnw[tid] + lnb[tid];
    xr[tid + 256] = (v1 - mean) * rstd * lnw[tid + 256] + lnb[tid + 256];
    __syncthreads();
    int c = blockIdx.x * 256 + tid;
    if (c < NCLS) {
        float acc = hb[c];
#pragma unroll 8
        for (int k = 0; k < DMODEL; ++k) acc += xr[k] * hw[k * NCLS + c];
        out[b * NCLS + c] = acc;
    }
}

extern "C" void kernel_launch(void* const* d_in, const int* in_sizes, int n_in,
                              void* d_out, int out_size, void* d_ws, size_t ws_size,
                              hipStream_t stream) {
    const float* img     = (const float*)d_in[0];
    const float* plnw    = (const float*)d_in[1];
    const float* plnb    = (const float*)d_in[2];
    const float* patch_w = (const float*)d_in[3];
    const float* patch_b = (const float*)d_in[4];
    const float* pos     = (const float*)d_in[5];
    const float* cls     = (const float*)d_in[6];
    const float* ln_w    = (const float*)d_in[7];
    const float* ln_b    = (const float*)d_in[8];
    const float* in_w    = (const float*)d_in[9];
    const float* conv_w  = (const float*)d_in[10];
    const float* conv_b  = (const float*)d_in[11];
    const float* xproj   = (const float*)d_in[12];
    const float* dt_w    = (const float*)d_in[13];
    const float* dt_b    = (const float*)d_in[14];
    const float* A_log   = (const float*)d_in[15];
    const float* Dp      = (const float*)d_in[16];
    const float* out_w   = (const float*)d_in[17];
    const float* hlnw    = (const float*)d_in[18];
    const float* hlnb    = (const float*)d_in[19];
    const float* head_w  = (const float*)d_in[20];
    const float* head_b  = (const float*)d_in[21];
    float* out = (float*)d_out;

    char* p = (char*)d_ws;
    auto alloc = [&](size_t bytes) { char* r = p; p += (bytes + 255) & ~(size_t)255; return r; };
    float* xtok = (float*)alloc((size_t)NTOK * DMODEL * 4);
    float* xz   = (float*)alloc((size_t)NTOK * 2 * DINNER * 4);
    float* u    = (float*)alloc((size_t)NTOK * DINNER * 4);
    float* dbc  = (float*)alloc((size_t)NTOK * 64 * 4);
    float* dtb_ = (float*)alloc((size_t)NTOK * DINNER * 4);
    float* Pe   = (float*)alloc((size_t)NPTOK * DMODEL * 4);
    float* part = (float*)alloc((size_t)4 * NTOK * DMODEL * 4);
    char* ylnH = alloc((size_t)MPAD * DMODEL * 2);
    char* ylnL = alloc((size_t)MPAD * DMODEL * 2);
    char* uH   = alloc((size_t)MPAD * DINNER * 2);
    char* uL   = alloc((size_t)MPAD * DINNER * 2);
    char* gH   = alloc((size_t)MPAD * DINNER * 2);
    char* gL   = alloc((size_t)MPAD * DINNER * 2);
    char* XpH  = alloc((size_t)MPAD * PDIM * 2);
    char* XpL  = alloc((size_t)MPAD * PDIM * 2);
    char* inTH  = alloc((size_t)NLAYER * 2 * DINNER * DMODEL * 2);
    char* inTL  = alloc((size_t)NLAYER * 2 * DINNER * DMODEL * 2);
    char* outTH = alloc((size_t)NLAYER * DMODEL * DINNER * 2);
    char* outTL = alloc((size_t)NLAYER * DMODEL * DINNER * 2);
    char* patTH = alloc((size_t)DMODEL * PDIM * 2);
    char* patTL = alloc((size_t)DMODEL * PDIM * 2);
    char* xprTH = alloc((size_t)NLAYER * 128 * DINNER * 2);
    char* xprTL = alloc((size_t)NLAYER * 128 * DINNER * 2);

    const size_t IN_T_B  = (size_t)2 * DINNER * DMODEL * 2;   // bytes/layer
    const size_t OUT_T_B = (size_t)DMODEL * DINNER * 2;
    const size_t XPR_T_B = (size_t)128 * DINNER * 2;

    // ---- one-time weight transpose + split (per call) ----
    k_wT<<<dim3(2 * DINNER / 32, DMODEL / 32, NLAYER), dim3(32, 8), 0, stream>>>(
        in_w, inTH, inTL, DMODEL, 2 * DINNER, (size_t)DMODEL * 2 * DINNER, IN_T_B);
    k_wT<<<dim3(DMODEL / 32, DINNER / 32, NLAYER), dim3(32, 8), 0, stream>>>(
        out_w, outTH, outTL, DINNER, DMODEL, (size_t)DINNER * DMODEL, OUT_T_B);
    k_wT<<<dim3(DMODEL / 32, PDIM / 32, 1), dim3(32, 8), 0, stream>>>(
        patch_w, patTH, patTL, PDIM, DMODEL, 0, 0);
    k_wT<<<dim3(128 / 32, DINNER / 32, NLAYER), dim3(32, 8), 0, stream>>>(
        xproj, xprTH, xprTL, DINNER, 64, (size_t)DINNER * 64, XPR_T_B);

    // ---- patch embedding ----
    k_patch_ln<<<NPTOK, 256, 0, stream>>>(img, plnw, plnb, XpH, XpL);
    k_gemm_f16s<<<dim3(4, 13, 4), 256, 0, stream>>>(
        XpH, XpL, patTH, patTL, part, NPTOK, DMODEL, PDIM, 960, (long)NPTOK * DMODEL);
    k_reduce<4, false><<<(NPTOK * DMODEL + 255) / 256, 256, 0, stream>>>(
        part, Pe, NPTOK * DMODEL, NPTOK * DMODEL);
    k_assemble<<<(NTOK * DMODEL + 255) / 256, 256, 0, stream>>>(Pe, patch_b, cls, pos, xtok);

    // ---- mamba layers ----
    for (int i = 0; i < NLAYER; ++i) {
        k_ln<<<NTOK, 256, 0, stream>>>(xtok, ln_w + i * DMODEL, ln_b + i * DMODEL, ylnH, ylnL);
        k_gemm_f16s<<<dim3(16, 13, 1), 256, 0, stream>>>(
            ylnH, ylnL, inTH + i * IN_T_B, inTL + i * IN_T_B,
            xz, NTOK, 2 * DINNER, DMODEL, DMODEL, 0);
        k_conv<<<(NTOK * DINNER) / 256, 256, 0, stream>>>(
            xz, conv_w + (size_t)i * DINNER * 4, conv_b + (size_t)i * DINNER, u, uH, uL);
        k_gemm_f16s<<<dim3(1, 13, 8), 256, 0, stream>>>(
            uH, uL, xprTH + i * XPR_T_B, xprTL + i * XPR_T_B,
            part, NTOK, 64, DINNER, 128, (long)NTOK * 64);
        k_reduce<8, false><<<(NTOK * 64 + 255) / 256, 256, 0, stream>>>(
            part, dbc, NTOK * 64, NTOK * 64);
        k_dt<<<NTOK, 256, 0, stream>>>(dbc, dt_w + (size_t)i * DRANK * DINNER,
                                       dt_b + (size_t)i * DINNER, dtb_);
        k_scan2<<<dim3(DINNER / 16, BATCH), 256, 0, stream>>>(
            dtb_, u, dbc, A_log + (size_t)i * DINNER * NSTATE, Dp + (size_t)i * DINNER,
            xz, gH, gL);
        k_gemm_f16s<<<dim3(4, 13, 4), 256, 0, stream>>>(
            gH, gL, outTH + i * OUT_T_B, outTL + i * OUT_T_B,
            part, NTOK, DMODEL, DINNER, 256, (long)NTOK * DMODEL);
        k_reduce<4, true><<<(NTOK * DMODEL + 255) / 256, 256, 0, stream>>>(
            part, xtok, NTOK * DMODEL, NTOK * DMODEL);
    }

    // ---- head ----
    k_head<<<dim3((NCLS + 255) / 256, BATCH), 256, 0, stream>>>(
        xtok, hlnw, hlnb, head_w, head_b, out);
}

// Round 6
// 869.347 us; speedup vs baseline: 4.0279x; 1.3594x over previous
//
#include <hip/hip_runtime.h>
#include <hip/hip_fp16.h>
#include <math.h>

#define BATCH   8
#define LSEQ    197
#define NPATCH  196
#define NPTOK   (BATCH * NPATCH)   // 1568
#define NTOK    (BATCH * LSEQ)     // 1576
#define MPAD    1664               // 13*128, padded row count for f16 act arrays
#define DMODEL  512
#define DINNER  1024
#define NSTATE  16
#define DRANK   32
#define NLAYER  8
#define NCLS    1000
#define PDIM    3840               // 16*16*15

typedef _Float16 f16x8 __attribute__((ext_vector_type(8)));
typedef float    f32x4 __attribute__((ext_vector_type(4)));

__device__ __forceinline__ float sp_silu(float x) { return x / (1.0f + expf(-x)); }
__device__ __forceinline__ float sp_softplus(float x) {
    return x > 0.0f ? x + log1pf(expf(-x)) : log1pf(expf(x));
}

// Sum across each 16-lane DPP row via row_shr adds; lane 15 of the row gets the sum.
__device__ __forceinline__ float row_sum16(float x) {
    float v = x;
    int t;
    t = __builtin_amdgcn_update_dpp(0, __float_as_int(v), 0x111, 0xF, 0xF, true); // shr:1
    v = v + __int_as_float(t);
    t = __builtin_amdgcn_update_dpp(0, __float_as_int(v), 0x112, 0xF, 0xF, true); // shr:2
    v = v + __int_as_float(t);
    t = __builtin_amdgcn_update_dpp(0, __float_as_int(v), 0x114, 0xF, 0xF, true); // shr:4
    v = v + __int_as_float(t);
    t = __builtin_amdgcn_update_dpp(0, __float_as_int(v), 0x118, 0xF, 0xF, true); // shr:8
    v = v + __int_as_float(t);
    return v;
}

// Store value v as f16 hi/lo split at swizzled position (row, k) of a [*][K] array.
// Swizzle: byte-in-row ^= (row&7)<<4  (permutes 16B blocks within 128B chunks).
__device__ __forceinline__ void store_split(char* __restrict__ Hb, char* __restrict__ Lb,
                                            int row, int k, int K, float v) {
    size_t byte = (size_t)row * (size_t)(K * 2) +
                  (size_t)(((unsigned)(k * 2)) ^ (unsigned)((row & 7) << 4));
    __half h = __float2half_rn(v);
    *(__half*)(Hb + byte) = h;
    *(__half*)(Lb + byte) = __float2half_rn((v - __half2float(h)) * 2048.0f);
}

// 256-thread block reduction of two values; lds must be 8 floats.
__device__ __forceinline__ float2 block_reduce2(float a, float b, float* lds) {
#pragma unroll
    for (int off = 32; off > 0; off >>= 1) {
        a += __shfl_down(a, off);
        b += __shfl_down(b, off);
    }
    int lane = threadIdx.x & 63, w = threadIdx.x >> 6;
    if (lane == 0) { lds[w] = a; lds[4 + w] = b; }
    __syncthreads();
    float sa = lds[0] + lds[1] + lds[2] + lds[3];
    float sb = lds[4] + lds[5] + lds[6] + lds[7];
    return make_float2(sa, sb);
}

// ---------------------------------------------------------------- patch stage
__global__ __launch_bounds__(256) void k_patch_ln(
    const float* __restrict__ img, const float* __restrict__ lnw,
    const float* __restrict__ lnb, char* __restrict__ Xph, char* __restrict__ Xpl) {
    __shared__ float vals[PDIM];
    __shared__ float red[8];
    int tok = blockIdx.x;
    int b = tok / NPATCH, p = tok % NPATCH;
    int gy = p / 14, gx = p % 14;
    int tid = threadIdx.x;
    int py = tid >> 4, px = tid & 15;
    int h0 = gy * 16 + py, w0 = gx * 16 + px;
    const int dh[5] = {0, 0, 0, -1, 1};
    const int dw[5] = {0, -1, 1, 0, 0};
    float s = 0.f, ss = 0.f;
#pragma unroll
    for (int c = 0; c < 15; ++c) {
        int g = c / 3, ch = c % 3;
        int h = h0 + dh[g], w = w0 + dw[g];
        float v = 0.f;
        if ((unsigned)h < 224u && (unsigned)w < 224u)
            v = img[((b * 3 + ch) * 224 + h) * 224 + w];
        vals[tid * 15 + c] = v;
        s += v; ss += v * v;
    }
    float2 t2 = block_reduce2(s, ss, red);
    float mean = t2.x * (1.0f / PDIM);
    float var  = t2.y * (1.0f / PDIM) - mean * mean;
    float rstd = 1.0f / sqrtf(var + 1e-5f);
    for (int j = 0; j < 15; ++j) {
        int e = tid + j * 256;
        float v = (vals[e] - mean) * rstd * lnw[e] + lnb[e];
        store_split(Xph, Xpl, tok, e, PDIM, v);
    }
}

// ------------------------------------------------------------------- token LN
__global__ __launch_bounds__(256) void k_ln(
    const float* __restrict__ x, const float* __restrict__ w,
    const float* __restrict__ b, char* __restrict__ yh, char* __restrict__ yl) {
    __shared__ float red[8];
    int t = blockIdx.x, tid = threadIdx.x;
    const float* xr = x + (size_t)t * DMODEL;
    float v0 = xr[tid], v1 = xr[tid + 256];
    float2 t2 = block_reduce2(v0 + v1, v0 * v0 + v1 * v1, red);
    float mean = t2.x * (1.0f / DMODEL);
    float var  = t2.y * (1.0f / DMODEL) - mean * mean;
    float rstd = 1.0f / sqrtf(var + 1e-5f);
    store_split(yh, yl, t, tid,       DMODEL, (v0 - mean) * rstd * w[tid]       + b[tid]);
    store_split(yh, yl, t, tid + 256, DMODEL, (v1 - mean) * rstd * w[tid + 256] + b[tid + 256]);
}

// --------------------------------------------- weight transpose + f16 split
__global__ __launch_bounds__(256) void k_wT(
    const float* __restrict__ W, char* __restrict__ Th, char* __restrict__ Tl,
    int Ks, int Ns, size_t wStride, size_t tByteStride) {
    __shared__ float t[32][33];
    int z = blockIdx.z;
    const float* Wz = W + (size_t)z * wStride;
    char* ThZ = Th + (size_t)z * tByteStride;
    char* TlZ = Tl + (size_t)z * tByteStride;
    int n0 = blockIdx.x * 32, k0 = blockIdx.y * 32;
    int tx = threadIdx.x, ty = threadIdx.y;
#pragma unroll
    for (int r = 0; r < 4; ++r) {
        int k = k0 + ty + r * 8, n = n0 + tx;
        t[tx][ty + r * 8] = (n < Ns) ? Wz[(size_t)k * Ns + n] : 0.f;
    }
    __syncthreads();
#pragma unroll
    for (int r = 0; r < 4; ++r) {
        int n = n0 + ty + r * 8, k = k0 + tx;
        float v = t[ty + r * 8][tx];
        size_t byte = (size_t)n * (size_t)(Ks * 2) +
                      (size_t)(((unsigned)(k * 2)) ^ (unsigned)((n & 7) << 4));
        __half h = __float2half_rn(v);
        *(__half*)(ThZ + byte) = h;
        *(__half*)(TlZ + byte) = __float2half_rn((v - __half2float(h)) * 2048.0f);
    }
}

// ------------------------------------------------- f16 split-2 MFMA GEMM
// Double-buffered LDS (128 KB) + bijective XCD-aware block remap.
__global__ __launch_bounds__(256, 1) void k_gemm_f16s(
    const char* __restrict__ Ah, const char* __restrict__ Al,
    const char* __restrict__ Bh, const char* __restrict__ Bl,
    float* __restrict__ C, int M, int N, int K, int kchunk, long partStride) {
    __shared__ __half L[2][4][128 * 64];
    const int tid = threadIdx.x, w = tid >> 6, lane = tid & 63;

    // XCD-aware remap: hw-linear id -> contiguous chunk of (m-fastest) work order
    const int GX = gridDim.x, GY = gridDim.y;
    const int nwg = GX * GY * gridDim.z;
    const int orig = blockIdx.x + GX * (blockIdx.y + GY * blockIdx.z);
    const int q = nwg >> 3, r = nwg & 7, xcd = orig & 7, pos = orig >> 3;
    const int wrk = (xcd < r ? xcd * (q + 1) : r * (q + 1) + (xcd - r) * q) + pos;
    const int bm = wrk % GY;
    const int t1 = wrk / GY;
    const int bn = t1 % GX, bz = t1 / GX;

    const int m0 = bm * 128, n0 = bn * 128;
    const int kbeg = bz * kchunk;
    int kend = kbeg + kchunk; if (kend > K) kend = K;
    C += (size_t)bz * (size_t)partStride;
    const size_t K2 = (size_t)K * 2;
    const int srowBase = 32 * w;          // wave-uniform
    const int srLane = lane >> 3;         // 0..7
    const int scol = (lane & 7) * 16;

    f32x4 acch[4][4], accx[4][4];
#pragma unroll
    for (int i = 0; i < 4; ++i)
#pragma unroll
        for (int j = 0; j < 4; ++j) {
            acch[i][j] = (f32x4)(0.f); accx[i][j] = (f32x4)(0.f);
        }

    auto STAGE = [&](int buf, int k0) {
#pragma unroll
        for (int t = 0; t < 4; ++t) {
            int lr = srowBase + 8 * t;                 // uniform LDS row base
            size_t ao = (size_t)(m0 + lr + srLane) * K2 + (size_t)k0 * 2 + scol;
            size_t bo = (size_t)(n0 + lr + srLane) * K2 + (size_t)k0 * 2 + scol;
            __builtin_amdgcn_global_load_lds(
                (const __attribute__((address_space(1))) void*)(Ah + ao),
                (__attribute__((address_space(3))) void*)&L[buf][0][lr * 64], 16, 0, 0);
            __builtin_amdgcn_global_load_lds(
                (const __attribute__((address_space(1))) void*)(Al + ao),
                (__attribute__((address_space(3))) void*)&L[buf][1][lr * 64], 16, 0, 0);
            __builtin_amdgcn_global_load_lds(
                (const __attribute__((address_space(1))) void*)(Bh + bo),
                (__attribute__((address_space(3))) void*)&L[buf][2][lr * 64], 16, 0, 0);
            __builtin_amdgcn_global_load_lds(
                (const __attribute__((address_space(1))) void*)(Bl + bo),
                (__attribute__((address_space(3))) void*)&L[buf][3][lr * 64], 16, 0, 0);
        }
    };

    const int wr = (w >> 1) * 64, wc = (w & 1) * 64;
    const int g = lane >> 4, rr = lane & 15;
    const int nk = (kend - kbeg + 63) / 64;

    STAGE(0, kbeg);
    asm volatile("s_waitcnt vmcnt(0)" ::: "memory");
    __syncthreads();

    for (int t = 0; t < nk; ++t) {
        int cur = t & 1;
        if (t + 1 < nk) STAGE(cur ^ 1, kbeg + (t + 1) * 64);
        const __half* LAh = L[cur][0];
        const __half* LAl = L[cur][1];
        const __half* LBh = L[cur][2];
        const __half* LBl = L[cur][3];
#pragma unroll
        for (int kk = 0; kk < 2; ++kk) {
            f16x8 afh[4], afl[4], bfh[4], bfl[4];
#pragma unroll
            for (int mf = 0; mf < 4; ++mf) {
                int row = wr + mf * 16 + rr;
                int off = row * 128 + ((kk * 64 + g * 16) ^ ((row & 7) << 4));
                afh[mf] = *(const f16x8*)((const char*)LAh + off);
                afl[mf] = *(const f16x8*)((const char*)LAl + off);
            }
#pragma unroll
            for (int nf = 0; nf < 4; ++nf) {
                int row = wc + nf * 16 + rr;
                int off = row * 128 + ((kk * 64 + g * 16) ^ ((row & 7) << 4));
                bfh[nf] = *(const f16x8*)((const char*)LBh + off);
                bfl[nf] = *(const f16x8*)((const char*)LBl + off);
            }
#pragma unroll
            for (int mf = 0; mf < 4; ++mf)
#pragma unroll
                for (int nf = 0; nf < 4; ++nf) {
                    acch[mf][nf] = __builtin_amdgcn_mfma_f32_16x16x32_f16(
                        afh[mf], bfh[nf], acch[mf][nf], 0, 0, 0);
                    accx[mf][nf] = __builtin_amdgcn_mfma_f32_16x16x32_f16(
                        afl[mf], bfh[nf], accx[mf][nf], 0, 0, 0);
                    accx[mf][nf] = __builtin_amdgcn_mfma_f32_16x16x32_f16(
                        afh[mf], bfl[nf], accx[mf][nf], 0, 0, 0);
                }
        }
        asm volatile("s_waitcnt vmcnt(0)" ::: "memory");
        __syncthreads();
    }

#pragma unroll
    for (int mf = 0; mf < 4; ++mf)
#pragma unroll
        for (int nf = 0; nf < 4; ++nf)
#pragma unroll
            for (int e = 0; e < 4; ++e) {
                int gm = m0 + wr + mf * 16 + g * 4 + e;
                int gn = n0 + wc + nf * 16 + rr;
                if (gm < M && gn < N)
                    C[(size_t)gm * N + gn] =
                        acch[mf][nf][e] + accx[mf][nf][e] * (1.0f / 2048.0f);
            }
}

// ------------------------------------------------------ split-K reduce
template <int SK, bool ACC>
__global__ __launch_bounds__(256) void k_reduce(
    const float* __restrict__ part, float* __restrict__ out, int total, int stride) {
    int i = blockIdx.x * 256 + threadIdx.x;
    if (i >= total) return;
    float s = 0.f;
#pragma unroll
    for (int k = 0; k < SK; ++k) s += part[(size_t)k * stride + i];
    out[i] = ACC ? out[i] + s : s;
}

// ---------------------------------------------- assemble tokens (+cls, +pos)
__global__ __launch_bounds__(256) void k_assemble(
    const float* __restrict__ Pe, const float* __restrict__ patch_b,
    const float* __restrict__ cls, const float* __restrict__ pos,
    float* __restrict__ xtok) {
    int idx = blockIdx.x * 256 + threadIdx.x;
    if (idx >= NTOK * DMODEL) return;
    int d = idx % DMODEL;
    int t = (idx / DMODEL) % LSEQ;
    int b = idx / (DMODEL * LSEQ);
    float v = (t < NPATCH) ? (Pe[((size_t)b * NPATCH + t) * DMODEL + d] + patch_b[d])
                           : cls[d];
    xtok[idx] = v + pos[t * DMODEL + d];
}

// ------------------------------- causal depthwise conv (K=4) + SiLU + split
__global__ __launch_bounds__(256) void k_conv(
    const float* __restrict__ xz, const float* __restrict__ cw,
    const float* __restrict__ cb, float* __restrict__ u,
    char* __restrict__ uh, char* __restrict__ ul) {
    int idx = blockIdx.x * 256 + threadIdx.x;
    if (idx >= NTOK * DINNER) return;
    int d = idx & (DINNER - 1);
    int t = idx >> 10;
    int l = t % LSEQ;
    float acc = cb[d];
#pragma unroll
    for (int j = 0; j < 4; ++j) {
        int ls = l - 3 + j;
        if (ls >= 0) acc += cw[d * 4 + j] * xz[(size_t)(t - 3 + j) * (2 * DINNER) + d];
    }
    float uv = sp_silu(acc);
    u[idx] = uv;
    store_split(uh, ul, t, d, DINNER, uv);
}

// ------- selective scan v3: fused dt-proj + LDS stage + DPP reduce + gate
// grid (DINNER/16, BATCH), 256 thr.
__global__ __launch_bounds__(256) void k_scan2(
    const float* __restrict__ u, const float* __restrict__ dbc,
    const float* __restrict__ dtw, const float* __restrict__ dtb,
    const float* __restrict__ Alog, const float* __restrict__ Dp,
    const float* __restrict__ xz, char* __restrict__ gh, char* __restrict__ gl) {
    __shared__ float uS[LSEQ * 16];
    __shared__ float dS[LSEQ * 16];   // dt in, y out (slot l dead after iter l)
    __shared__ float bS[LSEQ * 16];
    __shared__ float cS[LSEQ * 16];
    __shared__ float wS[DRANK * 16];  // dt_w columns d0..d0+15
    const int tid = threadIdx.x;
    const int b = blockIdx.y, d0 = blockIdx.x * 16;

    // phase 0: dtw columns to LDS
    for (int i = tid; i < DRANK * 16; i += 256)
        wS[i] = dtw[(size_t)(i >> 4) * DINNER + d0 + (i & 15)];
    __syncthreads();

    // phase 1: stage u/B/C, compute dt = softplus(r@dtw + b)
    const float* ub   = u   + ((size_t)b * LSEQ) * DINNER + d0;
    const float* dbcB = dbc + ((size_t)b * LSEQ) * 64;
    for (int i = tid; i < LSEQ * 4; i += 256) {
        int l = i >> 2, j = (i & 3) << 2;
        *(float4*)&uS[l * 16 + j] = *(const float4*)&ub[(size_t)l * DINNER + j];
        *(float4*)&bS[l * 16 + j] = *(const float4*)&dbcB[(size_t)l * 64 + DRANK + j];
        *(float4*)&cS[l * 16 + j] = *(const float4*)&dbcB[(size_t)l * 64 + DRANK + 16 + j];
        float4 acc = *(const float4*)&dtb[d0 + j];
#pragma unroll
        for (int kq = 0; kq < DRANK / 4; ++kq) {
            float4 r4 = *(const float4*)&dbcB[(size_t)l * 64 + kq * 4];
#pragma unroll
            for (int m = 0; m < 4; ++m) {
                float rv = (&r4.x)[m];
                float4 w4 = *(const float4*)&wS[(kq * 4 + m) * 16 + j];
                acc.x += rv * w4.x; acc.y += rv * w4.y;
                acc.z += rv * w4.z; acc.w += rv * w4.w;
            }
        }
        dS[l * 16 + j + 0] = sp_softplus(acc.x);
        dS[l * 16 + j + 1] = sp_softplus(acc.y);
        dS[l * 16 + j + 2] = sp_softplus(acc.z);
        dS[l * 16 + j + 3] = sp_softplus(acc.w);
    }
    const int n = tid & 15, dsub = tid >> 4;
    const int d = d0 + dsub;
    const float A  = -expf(Alog[d * NSTATE + n]);
    const float Dv = Dp[d];
    __syncthreads();

    // phase 2: serial recurrence; prefetch next iter BEFORE the y write.
    float dt_c = dS[dsub], uv_c = uS[dsub], B_c = bS[n], C_c = cS[n];
    float hn = 0.f;
    for (int l = 0; l < LSEQ; ++l) {
        float dt_n = 0.f, uv_n = 0.f, B_n = 0.f, C_n = 0.f;
        if (l + 1 < LSEQ) {
            int o = (l + 1) * 16;
            dt_n = dS[o + dsub]; uv_n = uS[o + dsub];
            B_n  = bS[o + n];    C_n  = cS[o + n];
        }
        hn = __expf(dt_c * A) * hn + dt_c * uv_c * B_c;
        float ys = row_sum16(hn * C_c);          // lane n==15 has the sum
        if (n == 15) dS[l * 16 + dsub] = ys + uv_c * Dv;
        dt_c = dt_n; uv_c = uv_n; B_c = B_n; C_c = C_n;
    }
    __syncthreads();

    // phase 3: fused gate g = y * silu(z); write f16 hi/lo swizzled
    const float* zb = xz + ((size_t)b * LSEQ) * (2 * DINNER) + DINNER + d0;
    for (int i = tid; i < LSEQ * 4; i += 256) {
        int l = i >> 2, j = (i & 3) << 2;
        float4 z4 = *(const float4*)&zb[(size_t)l * (2 * DINNER) + j];
        int t = b * LSEQ + l;
        store_split(gh, gl, t, d0 + j + 0, DINNER, dS[l * 16 + j + 0] * sp_silu(z4.x));
        store_split(gh, gl, t, d0 + j + 1, DINNER, dS[l * 16 + j + 1] * sp_silu(z4.y));
        store_split(gh, gl, t, d0 + j + 2, DINNER, dS[l * 16 + j + 2] * sp_silu(z4.z));
        store_split(gh, gl, t, d0 + j + 3, DINNER, dS[l * 16 + j + 3] * sp_silu(z4.w));
    }
}

// ------------------------------------------------------------ head: LN + FC
__global__ __launch_bounds__(256) void k_head(
    const float* __restrict__ xtok, const float* __restrict__ lnw,
    const float* __restrict__ lnb, const float* __restrict__ hw,
    const float* __restrict__ hb, float* __restrict__ out) {
    __shared__ float red[8];
    __shared__ float xr[DMODEL];
    int b = blockIdx.y, tid = threadIdx.x;
    const float* row = xtok + ((size_t)(b * LSEQ + NPATCH)) * DMODEL;
    float v0 = row[tid], v1 = row[tid + 256];
    float2 t2 = block_reduce2(v0 + v1, v0 * v0 + v1 * v1, red);
    float mean = t2.x * (1.0f / DMODEL);
    float var  = t2.y * (1.0f / DMODEL) - mean * mean;
    float rstd = 1.0f / sqrtf(var + 1e-5f);
    xr[tid]       = (v0 - mean) * rstd * lnw[tid] + lnb[tid];
    xr[tid + 256] = (v1 - mean) * rstd * lnw[tid + 256] + lnb[tid + 256];
    __syncthreads();
    int c = blockIdx.x * 256 + tid;
    if (c < NCLS) {
        float acc = hb[c];
#pragma unroll 8
        for (int k = 0; k < DMODEL; ++k) acc += xr[k] * hw[k * NCLS + c];
        out[b * NCLS + c] = acc;
    }
}

extern "C" void kernel_launch(void* const* d_in, const int* in_sizes, int n_in,
                              void* d_out, int out_size, void* d_ws, size_t ws_size,
                              hipStream_t stream) {
    const float* img     = (const float*)d_in[0];
    const float* plnw    = (const float*)d_in[1];
    const float* plnb    = (const float*)d_in[2];
    const float* patch_w = (const float*)d_in[3];
    const float* patch_b = (const float*)d_in[4];
    const float* pos     = (const float*)d_in[5];
    const float* cls     = (const float*)d_in[6];
    const float* ln_w    = (const float*)d_in[7];
    const float* ln_b    = (const float*)d_in[8];
    const float* in_w    = (const float*)d_in[9];
    const float* conv_w  = (const float*)d_in[10];
    const float* conv_b  = (const float*)d_in[11];
    const float* xproj   = (const float*)d_in[12];
    const float* dt_w    = (const float*)d_in[13];
    const float* dt_b    = (const float*)d_in[14];
    const float* A_log   = (const float*)d_in[15];
    const float* Dp      = (const float*)d_in[16];
    const float* out_w   = (const float*)d_in[17];
    const float* hlnw    = (const float*)d_in[18];
    const float* hlnb    = (const float*)d_in[19];
    const float* head_w  = (const float*)d_in[20];
    const float* head_b  = (const float*)d_in[21];
    float* out = (float*)d_out;

    char* p = (char*)d_ws;
    auto alloc = [&](size_t bytes) { char* r = p; p += (bytes + 255) & ~(size_t)255; return r; };
    float* xtok = (float*)alloc((size_t)NTOK * DMODEL * 4);
    float* xz   = (float*)alloc((size_t)NTOK * 2 * DINNER * 4);
    float* u    = (float*)alloc((size_t)NTOK * DINNER * 4);
    float* dbc  = (float*)alloc((size_t)NTOK * 64 * 4);
    float* Pe   = (float*)alloc((size_t)NPTOK * DMODEL * 4);
    float* part = (float*)alloc((size_t)4 * NTOK * DMODEL * 4);
    char* ylnH = alloc((size_t)MPAD * DMODEL * 2);
    char* ylnL = alloc((size_t)MPAD * DMODEL * 2);
    char* uH   = alloc((size_t)MPAD * DINNER * 2);
    char* uL   = alloc((size_t)MPAD * DINNER * 2);
    char* gH   = alloc((size_t)MPAD * DINNER * 2);
    char* gL   = alloc((size_t)MPAD * DINNER * 2);
    char* XpH  = alloc((size_t)MPAD * PDIM * 2);
    char* XpL  = alloc((size_t)MPAD * PDIM * 2);
    char* inTH  = alloc((size_t)NLAYER * 2 * DINNER * DMODEL * 2);
    char* inTL  = alloc((size_t)NLAYER * 2 * DINNER * DMODEL * 2);
    char* outTH = alloc((size_t)NLAYER * DMODEL * DINNER * 2);
    char* outTL = alloc((size_t)NLAYER * DMODEL * DINNER * 2);
    char* patTH = alloc((size_t)DMODEL * PDIM * 2);
    char* patTL = alloc((size_t)DMODEL * PDIM * 2);
    char* xprTH = alloc((size_t)NLAYER * 128 * DINNER * 2);
    char* xprTL = alloc((size_t)NLAYER * 128 * DINNER * 2);

    const size_t IN_T_B  = (size_t)2 * DINNER * DMODEL * 2;   // bytes/layer
    const size_t OUT_T_B = (size_t)DMODEL * DINNER * 2;
    const size_t XPR_T_B = (size_t)128 * DINNER * 2;

    // ---- one-time weight transpose + split (per call) ----
    k_wT<<<dim3(2 * DINNER / 32, DMODEL / 32, NLAYER), dim3(32, 8), 0, stream>>>(
        in_w, inTH, inTL, DMODEL, 2 * DINNER, (size_t)DMODEL * 2 * DINNER, IN_T_B);
    k_wT<<<dim3(DMODEL / 32, DINNER / 32, NLAYER), dim3(32, 8), 0, stream>>>(
        out_w, outTH, outTL, DINNER, DMODEL, (size_t)DINNER * DMODEL, OUT_T_B);
    k_wT<<<dim3(DMODEL / 32, PDIM / 32, 1), dim3(32, 8), 0, stream>>>(
        patch_w, patTH, patTL, PDIM, DMODEL, 0, 0);
    k_wT<<<dim3(128 / 32, DINNER / 32, NLAYER), dim3(32, 8), 0, stream>>>(
        xproj, xprTH, xprTL, DINNER, 64, (size_t)DINNER * 64, XPR_T_B);

    // ---- patch embedding ----
    k_patch_ln<<<NPTOK, 256, 0, stream>>>(img, plnw, plnb, XpH, XpL);
    k_gemm_f16s<<<dim3(4, 13, 4), 256, 0, stream>>>(
        XpH, XpL, patTH, patTL, part, NPTOK, DMODEL, PDIM, 960, (long)NPTOK * DMODEL);
    k_reduce<4, false><<<(NPTOK * DMODEL + 255) / 256, 256, 0, stream>>>(
        part, Pe, NPTOK * DMODEL, NPTOK * DMODEL);
    k_assemble<<<(NTOK * DMODEL + 255) / 256, 256, 0, stream>>>(Pe, patch_b, cls, pos, xtok);

    // ---- mamba layers ----
    for (int i = 0; i < NLAYER; ++i) {
        k_ln<<<NTOK, 256, 0, stream>>>(xtok, ln_w + i * DMODEL, ln_b + i * DMODEL, ylnH, ylnL);
        k_gemm_f16s<<<dim3(16, 13, 1), 256, 0, stream>>>(
            ylnH, ylnL, inTH + i * IN_T_B, inTL + i * IN_T_B,
            xz, NTOK, 2 * DINNER, DMODEL, DMODEL, 0);
        k_conv<<<(NTOK * DINNER) / 256, 256, 0, stream>>>(
            xz, conv_w + (size_t)i * DINNER * 4, conv_b + (size_t)i * DINNER, u, uH, uL);
        k_gemm_f16s<<<dim3(1, 13, 8), 256, 0, stream>>>(
            uH, uL, xprTH + i * XPR_T_B, xprTL + i * XPR_T_B,
            part, NTOK, 64, DINNER, 128, (long)NTOK * 64);
        k_reduce<8, false><<<(NTOK * 64 + 255) / 256, 256, 0, stream>>>(
            part, dbc, NTOK * 64, NTOK * 64);
        k_scan2<<<dim3(DINNER / 16, BATCH), 256, 0, stream>>>(
            u, dbc, dt_w + (size_t)i * DRANK * DINNER, dt_b + (size_t)i * DINNER,
            A_log + (size_t)i * DINNER * NSTATE, Dp + (size_t)i * DINNER,
            xz, gH, gL);
        k_gemm_f16s<<<dim3(4, 13, 4), 256, 0, stream>>>(
            gH, gL, outTH + i * OUT_T_B, outTL + i * OUT_T_B,
            part, NTOK, DMODEL, DINNER, 256, (long)NTOK * DMODEL);
        k_reduce<4, true><<<(NTOK * DMODEL + 255) / 256, 256, 0, stream>>>(
            part, xtok, NTOK * DMODEL, NTOK * DMODEL);
    }

    // ---- head ----
    k_head<<<dim3((NCLS + 255) / 256, BATCH), 256, 0, stream>>>(
        xtok, hlnw, hlnb, head_w, head_b, out);
}

// Round 7
// 864.877 us; speedup vs baseline: 4.0487x; 1.0052x over previous
//
#include <hip/hip_runtime.h>
#include <hip/hip_fp16.h>
#include <math.h>

#define BATCH   8
#define LSEQ    197
#define LPAD    200                // LSEQ padded to multiple of 4 for scan batches
#define NPATCH  196
#define NPTOK   (BATCH * NPATCH)   // 1568
#define NTOK    (BATCH * LSEQ)     // 1576
#define MPAD    1664               // 13*128, padded row count for f16 act arrays
#define DMODEL  512
#define DINNER  1024
#define NSTATE  16
#define DRANK   32
#define NLAYER  8
#define NCLS    1000
#define PDIM    3840               // 16*16*15

typedef _Float16 f16x8 __attribute__((ext_vector_type(8)));
typedef float    f32x4 __attribute__((ext_vector_type(4)));

__device__ __forceinline__ float sp_silu(float x) { return x / (1.0f + expf(-x)); }
__device__ __forceinline__ float sp_softplus(float x) {
    return x > 0.0f ? x + log1pf(expf(-x)) : log1pf(expf(x));
}

// Four interleaved 16-lane row sums (row_shr DPP tree); lane 15 of each row
// ends with the full sum. Interleaving hides the per-step dependent latency.
#define DPP_STEP4(P, CTRL)                                                     \
    {                                                                          \
        int t0 = __builtin_amdgcn_update_dpp(0, __float_as_int(P[0]), CTRL, 0xF, 0xF, true); \
        int t1 = __builtin_amdgcn_update_dpp(0, __float_as_int(P[1]), CTRL, 0xF, 0xF, true); \
        int t2 = __builtin_amdgcn_update_dpp(0, __float_as_int(P[2]), CTRL, 0xF, 0xF, true); \
        int t3 = __builtin_amdgcn_update_dpp(0, __float_as_int(P[3]), CTRL, 0xF, 0xF, true); \
        P[0] += __int_as_float(t0); P[1] += __int_as_float(t1);                \
        P[2] += __int_as_float(t2); P[3] += __int_as_float(t3);                \
    }

__device__ __forceinline__ void row_sum16x4(float* p) {
    DPP_STEP4(p, 0x111);   // row_shr:1
    DPP_STEP4(p, 0x112);   // row_shr:2
    DPP_STEP4(p, 0x114);   // row_shr:4
    DPP_STEP4(p, 0x118);   // row_shr:8
}

// Store value v as f16 hi/lo split at swizzled position (row, k) of a [*][K] array.
// Swizzle: byte-in-row ^= (row&7)<<4  (permutes 16B blocks within 128B chunks).
__device__ __forceinline__ void store_split(char* __restrict__ Hb, char* __restrict__ Lb,
                                            int row, int k, int K, float v) {
    size_t byte = (size_t)row * (size_t)(K * 2) +
                  (size_t)(((unsigned)(k * 2)) ^ (unsigned)((row & 7) << 4));
    __half h = __float2half_rn(v);
    *(__half*)(Hb + byte) = h;
    *(__half*)(Lb + byte) = __float2half_rn((v - __half2float(h)) * 2048.0f);
}

// 256-thread block reduction of two values; lds must be 8 floats.
__device__ __forceinline__ float2 block_reduce2(float a, float b, float* lds) {
#pragma unroll
    for (int off = 32; off > 0; off >>= 1) {
        a += __shfl_down(a, off);
        b += __shfl_down(b, off);
    }
    int lane = threadIdx.x & 63, w = threadIdx.x >> 6;
    if (lane == 0) { lds[w] = a; lds[4 + w] = b; }
    __syncthreads();
    float sa = lds[0] + lds[1] + lds[2] + lds[3];
    float sb = lds[4] + lds[5] + lds[6] + lds[7];
    return make_float2(sa, sb);
}

// ---------------------------------------------------------------- patch stage
__global__ __launch_bounds__(256) void k_patch_ln(
    const float* __restrict__ img, const float* __restrict__ lnw,
    const float* __restrict__ lnb, char* __restrict__ Xph, char* __restrict__ Xpl) {
    __shared__ float vals[PDIM];
    __shared__ float red[8];
    int tok = blockIdx.x;
    int b = tok / NPATCH, p = tok % NPATCH;
    int gy = p / 14, gx = p % 14;
    int tid = threadIdx.x;
    int py = tid >> 4, px = tid & 15;
    int h0 = gy * 16 + py, w0 = gx * 16 + px;
    const int dh[5] = {0, 0, 0, -1, 1};
    const int dw[5] = {0, -1, 1, 0, 0};
    float s = 0.f, ss = 0.f;
#pragma unroll
    for (int c = 0; c < 15; ++c) {
        int g = c / 3, ch = c % 3;
        int h = h0 + dh[g], w = w0 + dw[g];
        float v = 0.f;
        if ((unsigned)h < 224u && (unsigned)w < 224u)
            v = img[((b * 3 + ch) * 224 + h) * 224 + w];
        vals[tid * 15 + c] = v;
        s += v; ss += v * v;
    }
    float2 t2 = block_reduce2(s, ss, red);
    float mean = t2.x * (1.0f / PDIM);
    float var  = t2.y * (1.0f / PDIM) - mean * mean;
    float rstd = 1.0f / sqrtf(var + 1e-5f);
    for (int j = 0; j < 15; ++j) {
        int e = tid + j * 256;
        float v = (vals[e] - mean) * rstd * lnw[e] + lnb[e];
        store_split(Xph, Xpl, tok, e, PDIM, v);
    }
}

// ------------------------------------------------------------------- token LN
__global__ __launch_bounds__(256) void k_ln(
    const float* __restrict__ x, const float* __restrict__ w,
    const float* __restrict__ b, char* __restrict__ yh, char* __restrict__ yl) {
    __shared__ float red[8];
    int t = blockIdx.x, tid = threadIdx.x;
    const float* xr = x + (size_t)t * DMODEL;
    float v0 = xr[tid], v1 = xr[tid + 256];
    float2 t2 = block_reduce2(v0 + v1, v0 * v0 + v1 * v1, red);
    float mean = t2.x * (1.0f / DMODEL);
    float var  = t2.y * (1.0f / DMODEL) - mean * mean;
    float rstd = 1.0f / sqrtf(var + 1e-5f);
    store_split(yh, yl, t, tid,       DMODEL, (v0 - mean) * rstd * w[tid]       + b[tid]);
    store_split(yh, yl, t, tid + 256, DMODEL, (v1 - mean) * rstd * w[tid + 256] + b[tid + 256]);
}

// --------------------------------------------- weight transpose + f16 split
__global__ __launch_bounds__(256) void k_wT(
    const float* __restrict__ W, char* __restrict__ Th, char* __restrict__ Tl,
    int Ks, int Ns, size_t wStride, size_t tByteStride) {
    __shared__ float t[32][33];
    int z = blockIdx.z;
    const float* Wz = W + (size_t)z * wStride;
    char* ThZ = Th + (size_t)z * tByteStride;
    char* TlZ = Tl + (size_t)z * tByteStride;
    int n0 = blockIdx.x * 32, k0 = blockIdx.y * 32;
    int tx = threadIdx.x, ty = threadIdx.y;
#pragma unroll
    for (int r = 0; r < 4; ++r) {
        int k = k0 + ty + r * 8, n = n0 + tx;
        t[tx][ty + r * 8] = (n < Ns) ? Wz[(size_t)k * Ns + n] : 0.f;
    }
    __syncthreads();
#pragma unroll
    for (int r = 0; r < 4; ++r) {
        int n = n0 + ty + r * 8, k = k0 + tx;
        float v = t[ty + r * 8][tx];
        size_t byte = (size_t)n * (size_t)(Ks * 2) +
                      (size_t)(((unsigned)(k * 2)) ^ (unsigned)((n & 7) << 4));
        __half h = __float2half_rn(v);
        *(__half*)(ThZ + byte) = h;
        *(__half*)(TlZ + byte) = __float2half_rn((v - __half2float(h)) * 2048.0f);
    }
}

// ------------------------------------------------- f16 split-2 MFMA GEMM
// Double-buffered LDS (128 KB) + bijective XCD-aware block remap.
__global__ __launch_bounds__(256, 1) void k_gemm_f16s(
    const char* __restrict__ Ah, const char* __restrict__ Al,
    const char* __restrict__ Bh, const char* __restrict__ Bl,
    float* __restrict__ C, int M, int N, int K, int kchunk, long partStride) {
    __shared__ __half L[2][4][128 * 64];
    const int tid = threadIdx.x, w = tid >> 6, lane = tid & 63;

    // XCD-aware remap: hw-linear id -> contiguous chunk of (m-fastest) work order
    const int GX = gridDim.x, GY = gridDim.y;
    const int nwg = GX * GY * gridDim.z;
    const int orig = blockIdx.x + GX * (blockIdx.y + GY * blockIdx.z);
    const int q = nwg >> 3, r = nwg & 7, xcd = orig & 7, pos = orig >> 3;
    const int wrk = (xcd < r ? xcd * (q + 1) : r * (q + 1) + (xcd - r) * q) + pos;
    const int bm = wrk % GY;
    const int t1 = wrk / GY;
    const int bn = t1 % GX, bz = t1 / GX;

    const int m0 = bm * 128, n0 = bn * 128;
    const int kbeg = bz * kchunk;
    int kend = kbeg + kchunk; if (kend > K) kend = K;
    C += (size_t)bz * (size_t)partStride;
    const size_t K2 = (size_t)K * 2;
    const int srowBase = 32 * w;          // wave-uniform
    const int srLane = lane >> 3;         // 0..7
    const int scol = (lane & 7) * 16;

    f32x4 acch[4][4], accx[4][4];
#pragma unroll
    for (int i = 0; i < 4; ++i)
#pragma unroll
        for (int j = 0; j < 4; ++j) {
            acch[i][j] = (f32x4)(0.f); accx[i][j] = (f32x4)(0.f);
        }

    auto STAGE = [&](int buf, int k0) {
#pragma unroll
        for (int t = 0; t < 4; ++t) {
            int lr = srowBase + 8 * t;                 // uniform LDS row base
            size_t ao = (size_t)(m0 + lr + srLane) * K2 + (size_t)k0 * 2 + scol;
            size_t bo = (size_t)(n0 + lr + srLane) * K2 + (size_t)k0 * 2 + scol;
            __builtin_amdgcn_global_load_lds(
                (const __attribute__((address_space(1))) void*)(Ah + ao),
                (__attribute__((address_space(3))) void*)&L[buf][0][lr * 64], 16, 0, 0);
            __builtin_amdgcn_global_load_lds(
                (const __attribute__((address_space(1))) void*)(Al + ao),
                (__attribute__((address_space(3))) void*)&L[buf][1][lr * 64], 16, 0, 0);
            __builtin_amdgcn_global_load_lds(
                (const __attribute__((address_space(1))) void*)(Bh + bo),
                (__attribute__((address_space(3))) void*)&L[buf][2][lr * 64], 16, 0, 0);
            __builtin_amdgcn_global_load_lds(
                (const __attribute__((address_space(1))) void*)(Bl + bo),
                (__attribute__((address_space(3))) void*)&L[buf][3][lr * 64], 16, 0, 0);
        }
    };

    const int wr = (w >> 1) * 64, wc = (w & 1) * 64;
    const int g = lane >> 4, rr = lane & 15;
    const int nk = (kend - kbeg + 63) / 64;

    STAGE(0, kbeg);
    asm volatile("s_waitcnt vmcnt(0)" ::: "memory");
    __syncthreads();

    for (int t = 0; t < nk; ++t) {
        int cur = t & 1;
        if (t + 1 < nk) STAGE(cur ^ 1, kbeg + (t + 1) * 64);
        const __half* LAh = L[cur][0];
        const __half* LAl = L[cur][1];
        const __half* LBh = L[cur][2];
        const __half* LBl = L[cur][3];
#pragma unroll
        for (int kk = 0; kk < 2; ++kk) {
            f16x8 afh[4], afl[4], bfh[4], bfl[4];
#pragma unroll
            for (int mf = 0; mf < 4; ++mf) {
                int row = wr + mf * 16 + rr;
                int off = row * 128 + ((kk * 64 + g * 16) ^ ((row & 7) << 4));
                afh[mf] = *(const f16x8*)((const char*)LAh + off);
                afl[mf] = *(const f16x8*)((const char*)LAl + off);
            }
#pragma unroll
            for (int nf = 0; nf < 4; ++nf) {
                int row = wc + nf * 16 + rr;
                int off = row * 128 + ((kk * 64 + g * 16) ^ ((row & 7) << 4));
                bfh[nf] = *(const f16x8*)((const char*)LBh + off);
                bfl[nf] = *(const f16x8*)((const char*)LBl + off);
            }
#pragma unroll
            for (int mf = 0; mf < 4; ++mf)
#pragma unroll
                for (int nf = 0; nf < 4; ++nf) {
                    acch[mf][nf] = __builtin_amdgcn_mfma_f32_16x16x32_f16(
                        afh[mf], bfh[nf], acch[mf][nf], 0, 0, 0);
                    accx[mf][nf] = __builtin_amdgcn_mfma_f32_16x16x32_f16(
                        afl[mf], bfh[nf], accx[mf][nf], 0, 0, 0);
                    accx[mf][nf] = __builtin_amdgcn_mfma_f32_16x16x32_f16(
                        afh[mf], bfl[nf], accx[mf][nf], 0, 0, 0);
                }
        }
        asm volatile("s_waitcnt vmcnt(0)" ::: "memory");
        __syncthreads();
    }

#pragma unroll
    for (int mf = 0; mf < 4; ++mf)
#pragma unroll
        for (int nf = 0; nf < 4; ++nf)
#pragma unroll
            for (int e = 0; e < 4; ++e) {
                int gm = m0 + wr + mf * 16 + g * 4 + e;
                int gn = n0 + wc + nf * 16 + rr;
                if (gm < M && gn < N)
                    C[(size_t)gm * N + gn] =
                        acch[mf][nf][e] + accx[mf][nf][e] * (1.0f / 2048.0f);
            }
}

// ------------------------------------------------------ split-K reduce
template <int SK, bool ACC>
__global__ __launch_bounds__(256) void k_reduce(
    const float* __restrict__ part, float* __restrict__ out, int total, int stride) {
    int i = blockIdx.x * 256 + threadIdx.x;
    if (i >= total) return;
    float s = 0.f;
#pragma unroll
    for (int k = 0; k < SK; ++k) s += part[(size_t)k * stride + i];
    out[i] = ACC ? out[i] + s : s;
}

// ---------------------------------------------- assemble tokens (+cls, +pos)
__global__ __launch_bounds__(256) void k_assemble(
    const float* __restrict__ Pe, const float* __restrict__ patch_b,
    const float* __restrict__ cls, const float* __restrict__ pos,
    float* __restrict__ xtok) {
    int idx = blockIdx.x * 256 + threadIdx.x;
    if (idx >= NTOK * DMODEL) return;
    int d = idx % DMODEL;
    int t = (idx / DMODEL) % LSEQ;
    int b = idx / (DMODEL * LSEQ);
    float v = (t < NPATCH) ? (Pe[((size_t)b * NPATCH + t) * DMODEL + d] + patch_b[d])
                           : cls[d];
    xtok[idx] = v + pos[t * DMODEL + d];
}

// ------------------------------- causal depthwise conv (K=4) + SiLU + split
__global__ __launch_bounds__(256) void k_conv(
    const float* __restrict__ xz, const float* __restrict__ cw,
    const float* __restrict__ cb, float* __restrict__ u,
    char* __restrict__ uh, char* __restrict__ ul) {
    int idx = blockIdx.x * 256 + threadIdx.x;
    if (idx >= NTOK * DINNER) return;
    int d = idx & (DINNER - 1);
    int t = idx >> 10;
    int l = t % LSEQ;
    float acc = cb[d];
#pragma unroll
    for (int j = 0; j < 4; ++j) {
        int ls = l - 3 + j;
        if (ls >= 0) acc += cw[d * 4 + j] * xz[(size_t)(t - 3 + j) * (2 * DINNER) + d];
    }
    float uv = sp_silu(acc);
    u[idx] = uv;
    store_split(uh, ul, t, d, DINNER, uv);
}

// ------- selective scan v4: fused dt-proj + LDS stage + pipelined batch-4
// recurrence with interleaved DPP rowsums + fused gate.
// grid (DINNER/16, BATCH), 256 thr.
__global__ __launch_bounds__(256) void k_scan2(
    const float* __restrict__ u, const float* __restrict__ dbc,
    const float* __restrict__ dtw, const float* __restrict__ dtb,
    const float* __restrict__ Alog, const float* __restrict__ Dp,
    const float* __restrict__ xz, char* __restrict__ gh, char* __restrict__ gl) {
    __shared__ float uS[LPAD * 16];
    __shared__ float dS[LPAD * 16];   // dt in, y out (slot l dead after iter l)
    __shared__ float bS[LPAD * 16];
    __shared__ float cS[LPAD * 16];
    __shared__ float wS[DRANK * 16];  // dt_w columns d0..d0+15
    const int tid = threadIdx.x;
    const int b = blockIdx.y, d0 = blockIdx.x * 16;

    // phase 0: dtw columns to LDS
    for (int i = tid; i < DRANK * 16; i += 256)
        wS[i] = dtw[(size_t)(i >> 4) * DINNER + d0 + (i & 15)];
    __syncthreads();

    // phase 1: stage u/B/C, compute dt = softplus(r@dtw + b); zero-fill pad rows
    const float* ub   = u   + ((size_t)b * LSEQ) * DINNER + d0;
    const float* dbcB = dbc + ((size_t)b * LSEQ) * 64;
    for (int i = tid; i < LPAD * 4; i += 256) {
        int l = i >> 2, j = (i & 3) << 2;
        if (l >= LSEQ) {
            float4 z = make_float4(0.f, 0.f, 0.f, 0.f);
            *(float4*)&uS[l * 16 + j] = z;
            *(float4*)&dS[l * 16 + j] = z;
            *(float4*)&bS[l * 16 + j] = z;
            *(float4*)&cS[l * 16 + j] = z;
            continue;
        }
        *(float4*)&uS[l * 16 + j] = *(const float4*)&ub[(size_t)l * DINNER + j];
        *(float4*)&bS[l * 16 + j] = *(const float4*)&dbcB[(size_t)l * 64 + DRANK + j];
        *(float4*)&cS[l * 16 + j] = *(const float4*)&dbcB[(size_t)l * 64 + DRANK + 16 + j];
        float4 acc = *(const float4*)&dtb[d0 + j];
#pragma unroll
        for (int kq = 0; kq < DRANK / 4; ++kq) {
            float4 r4 = *(const float4*)&dbcB[(size_t)l * 64 + kq * 4];
#pragma unroll
            for (int m = 0; m < 4; ++m) {
                float rv = (&r4.x)[m];
                float4 w4 = *(const float4*)&wS[(kq * 4 + m) * 16 + j];
                acc.x += rv * w4.x; acc.y += rv * w4.y;
                acc.z += rv * w4.z; acc.w += rv * w4.w;
            }
        }
        dS[l * 16 + j + 0] = sp_softplus(acc.x);
        dS[l * 16 + j + 1] = sp_softplus(acc.y);
        dS[l * 16 + j + 2] = sp_softplus(acc.z);
        dS[l * 16 + j + 3] = sp_softplus(acc.w);
    }
    const int n = tid & 15, dsub = tid >> 4;
    const int d = d0 + dsub;
    const float A  = -expf(Alog[d * NSTATE + n]);
    const float Dv = Dp[d];
    __syncthreads();

    // phase 2: batch-4 software-pipelined recurrence.
    // dsub columns are wave-private (wave w covers dsub 4w..4w+3), so the
    // in-loop dS y-writes never race with other waves' reads.
    float hn = 0.f;
    float dt4[4], uv4[4], Bn4[4], Cn4[4];
#pragma unroll
    for (int i = 0; i < 4; ++i) {
        int o = i * 16;
        dt4[i] = dS[o + dsub]; uv4[i] = uS[o + dsub];
        Bn4[i] = bS[o + n];    Cn4[i] = cS[o + n];
    }
    for (int lb = 0; lb < LPAD; lb += 4) {
        float dtN[4], uvN[4], BnN[4], CnN[4];
        if (lb + 4 < LPAD) {
#pragma unroll
            for (int i = 0; i < 4; ++i) {
                int o = (lb + 4 + i) * 16;
                dtN[i] = dS[o + dsub]; uvN[i] = uS[o + dsub];
                BnN[i] = bS[o + n];    CnN[i] = cS[o + n];
            }
        } else {
#pragma unroll
            for (int i = 0; i < 4; ++i) { dtN[i] = uvN[i] = BnN[i] = CnN[i] = 0.f; }
        }
        float a4[4], b4[4], p4[4];
#pragma unroll
        for (int i = 0; i < 4; ++i) {
            a4[i] = __expf(dt4[i] * A);
            b4[i] = dt4[i] * uv4[i] * Bn4[i];
        }
#pragma unroll
        for (int i = 0; i < 4; ++i) {
            hn = a4[i] * hn + b4[i];
            p4[i] = hn * Cn4[i];
        }
        row_sum16x4(p4);
#pragma unroll
        for (int i = 0; i < 4; ++i)
            if (n == 15) dS[(lb + i) * 16 + dsub] = p4[i] + uv4[i] * Dv;
#pragma unroll
        for (int i = 0; i < 4; ++i) {
            dt4[i] = dtN[i]; uv4[i] = uvN[i]; Bn4[i] = BnN[i]; Cn4[i] = CnN[i];
        }
    }
    __syncthreads();

    // phase 3: fused gate g = y * silu(z); write f16 hi/lo swizzled
    const float* zb = xz + ((size_t)b * LSEQ) * (2 * DINNER) + DINNER + d0;
    for (int i = tid; i < LSEQ * 4; i += 256) {
        int l = i >> 2, j = (i & 3) << 2;
        float4 z4 = *(const float4*)&zb[(size_t)l * (2 * DINNER) + j];
        int t = b * LSEQ + l;
        store_split(gh, gl, t, d0 + j + 0, DINNER, dS[l * 16 + j + 0] * sp_silu(z4.x));
        store_split(gh, gl, t, d0 + j + 1, DINNER, dS[l * 16 + j + 1] * sp_silu(z4.y));
        store_split(gh, gl, t, d0 + j + 2, DINNER, dS[l * 16 + j + 2] * sp_silu(z4.z));
        store_split(gh, gl, t, d0 + j + 3, DINNER, dS[l * 16 + j + 3] * sp_silu(z4.w));
    }
}

// ------------------------------------------------------------ head: LN + FC
__global__ __launch_bounds__(256) void k_head(
    const float* __restrict__ xtok, const float* __restrict__ lnw,
    const float* __restrict__ lnb, const float* __restrict__ hw,
    const float* __restrict__ hb, float* __restrict__ out) {
    __shared__ float red[8];
    __shared__ float xr[DMODEL];
    int b = blockIdx.y, tid = threadIdx.x;
    const float* row = xtok + ((size_t)(b * LSEQ + NPATCH)) * DMODEL;
    float v0 = row[tid], v1 = row[tid + 256];
    float2 t2 = block_reduce2(v0 + v1, v0 * v0 + v1 * v1, red);
    float mean = t2.x * (1.0f / DMODEL);
    float var  = t2.y * (1.0f / DMODEL) - mean * mean;
    float rstd = 1.0f / sqrtf(var + 1e-5f);
    xr[tid]       = (v0 - mean) * rstd * lnw[tid] + lnb[tid];
    xr[tid + 256] = (v1 - mean) * rstd * lnw[tid + 256] + lnb[tid + 256];
    __syncthreads();
    int c = blockIdx.x * 256 + tid;
    if (c < NCLS) {
        float acc = hb[c];
#pragma unroll 8
        for (int k = 0; k < DMODEL; ++k) acc += xr[k] * hw[k * NCLS + c];
        out[b * NCLS + c] = acc;
    }
}

extern "C" void kernel_launch(void* const* d_in, const int* in_sizes, int n_in,
                              void* d_out, int out_size, void* d_ws, size_t ws_size,
                              hipStream_t stream) {
    const float* img     = (const float*)d_in[0];
    const float* plnw    = (const float*)d_in[1];
    const float* plnb    = (const float*)d_in[2];
    const float* patch_w = (const float*)d_in[3];
    const float* patch_b = (const float*)d_in[4];
    const float* pos     = (const float*)d_in[5];
    const float* cls     = (const float*)d_in[6];
    const float* ln_w    = (const float*)d_in[7];
    const float* ln_b    = (const float*)d_in[8];
    const float* in_w    = (const float*)d_in[9];
    const float* conv_w  = (const float*)d_in[10];
    const float* conv_b  = (const float*)d_in[11];
    const float* xproj   = (const float*)d_in[12];
    const float* dt_w    = (const float*)d_in[13];
    const float* dt_b    = (const float*)d_in[14];
    const float* A_log   = (const float*)d_in[15];
    const float* Dp      = (const float*)d_in[16];
    const float* out_w   = (const float*)d_in[17];
    const float* hlnw    = (const float*)d_in[18];
    const float* hlnb    = (const float*)d_in[19];
    const float* head_w  = (const float*)d_in[20];
    const float* head_b  = (const float*)d_in[21];
    float* out = (float*)d_out;

    char* p = (char*)d_ws;
    auto alloc = [&](size_t bytes) { char* r = p; p += (bytes + 255) & ~(size_t)255; return r; };
    float* xtok = (float*)alloc((size_t)NTOK * DMODEL * 4);
    float* xz   = (float*)alloc((size_t)NTOK * 2 * DINNER * 4);
    float* u    = (float*)alloc((size_t)NTOK * DINNER * 4);
    float* dbc  = (float*)alloc((size_t)NTOK * 64 * 4);
    float* Pe   = (float*)alloc((size_t)NPTOK * DMODEL * 4);
    float* part = (float*)alloc((size_t)4 * NTOK * DMODEL * 4);
    char* ylnH = alloc((size_t)MPAD * DMODEL * 2);
    char* ylnL = alloc((size_t)MPAD * DMODEL * 2);
    char* uH   = alloc((size_t)MPAD * DINNER * 2);
    char* uL   = alloc((size_t)MPAD * DINNER * 2);
    char* gH   = alloc((size_t)MPAD * DINNER * 2);
    char* gL   = alloc((size_t)MPAD * DINNER * 2);
    char* XpH  = alloc((size_t)MPAD * PDIM * 2);
    char* XpL  = alloc((size_t)MPAD * PDIM * 2);
    char* inTH  = alloc((size_t)NLAYER * 2 * DINNER * DMODEL * 2);
    char* inTL  = alloc((size_t)NLAYER * 2 * DINNER * DMODEL * 2);
    char* outTH = alloc((size_t)NLAYER * DMODEL * DINNER * 2);
    char* outTL = alloc((size_t)NLAYER * DMODEL * DINNER * 2);
    char* patTH = alloc((size_t)DMODEL * PDIM * 2);
    char* patTL = alloc((size_t)DMODEL * PDIM * 2);
    char* xprTH = alloc((size_t)NLAYER * 128 * DINNER * 2);
    char* xprTL = alloc((size_t)NLAYER * 128 * DINNER * 2);

    const size_t IN_T_B  = (size_t)2 * DINNER * DMODEL * 2;   // bytes/layer
    const size_t OUT_T_B = (size_t)DMODEL * DINNER * 2;
    const size_t XPR_T_B = (size_t)128 * DINNER * 2;

    // ---- one-time weight transpose + split (per call) ----
    k_wT<<<dim3(2 * DINNER / 32, DMODEL / 32, NLAYER), dim3(32, 8), 0, stream>>>(
        in_w, inTH, inTL, DMODEL, 2 * DINNER, (size_t)DMODEL * 2 * DINNER, IN_T_B);
    k_wT<<<dim3(DMODEL / 32, DINNER / 32, NLAYER), dim3(32, 8), 0, stream>>>(
        out_w, outTH, outTL, DINNER, DMODEL, (size_t)DINNER * DMODEL, OUT_T_B);
    k_wT<<<dim3(DMODEL / 32, PDIM / 32, 1), dim3(32, 8), 0, stream>>>(
        patch_w, patTH, patTL, PDIM, DMODEL, 0, 0);
    k_wT<<<dim3(128 / 32, DINNER / 32, NLAYER), dim3(32, 8), 0, stream>>>(
        xproj, xprTH, xprTL, DINNER, 64, (size_t)DINNER * 64, XPR_T_B);

    // ---- patch embedding ----
    k_patch_ln<<<NPTOK, 256, 0, stream>>>(img, plnw, plnb, XpH, XpL);
    k_gemm_f16s<<<dim3(4, 13, 4), 256, 0, stream>>>(
        XpH, XpL, patTH, patTL, part, NPTOK, DMODEL, PDIM, 960, (long)NPTOK * DMODEL);
    k_reduce<4, false><<<(NPTOK * DMODEL + 255) / 256, 256, 0, stream>>>(
        part, Pe, NPTOK * DMODEL, NPTOK * DMODEL);
    k_assemble<<<(NTOK * DMODEL + 255) / 256, 256, 0, stream>>>(Pe, patch_b, cls, pos, xtok);

    // ---- mamba layers ----
    for (int i = 0; i < NLAYER; ++i) {
        k_ln<<<NTOK, 256, 0, stream>>>(xtok, ln_w + i * DMODEL, ln_b + i * DMODEL, ylnH, ylnL);
        k_gemm_f16s<<<dim3(16, 13, 1), 256, 0, stream>>>(
            ylnH, ylnL, inTH + i * IN_T_B, inTL + i * IN_T_B,
            xz, NTOK, 2 * DINNER, DMODEL, DMODEL, 0);
        k_conv<<<(NTOK * DINNER) / 256, 256, 0, stream>>>(
            xz, conv_w + (size_t)i * DINNER * 4, conv_b + (size_t)i * DINNER, u, uH, uL);
        k_gemm_f16s<<<dim3(1, 13, 8), 256, 0, stream>>>(
            uH, uL, xprTH + i * XPR_T_B, xprTL + i * XPR_T_B,
            part, NTOK, 64, DINNER, 128, (long)NTOK * 64);
        k_reduce<8, false><<<(NTOK * 64 + 255) / 256, 256, 0, stream>>>(
            part, dbc, NTOK * 64, NTOK * 64);
        k_scan2<<<dim3(DINNER / 16, BATCH), 256, 0, stream>>>(
            u, dbc, dt_w + (size_t)i * DRANK * DINNER, dt_b + (size_t)i * DINNER,
            A_log + (size_t)i * DINNER * NSTATE, Dp + (size_t)i * DINNER,
            xz, gH, gL);
        k_gemm_f16s<<<dim3(4, 13, 4), 256, 0, stream>>>(
            gH, gL, outTH + i * OUT_T_B, outTL + i * OUT_T_B,
            part, NTOK, DMODEL, DINNER, 256, (long)NTOK * DMODEL);
        k_reduce<4, true><<<(NTOK * DMODEL + 255) / 256, 256, 0, stream>>>(
            part, xtok, NTOK * DMODEL, NTOK * DMODEL);
    }

    // ---- head ----
    k_head<<<dim3((NCLS + 255) / 256, BATCH), 256, 0, stream>>>(
        xtok, hlnw, hlnb, head_w, head_b, out);
}

// Round 9
// 762.111 us; speedup vs baseline: 4.5946x; 1.1348x over previous
//
#include <hip/hip_runtime.h>
#include <hip/hip_fp16.h>
#include <math.h>

#define BATCH   8
#define LSEQ    197
#define LPAD    200                // LSEQ padded to multiple of 8 for scan batches
#define NPATCH  196
#define NPTOK   (BATCH * NPATCH)   // 1568
#define NTOK    (BATCH * LSEQ)     // 1576
#define MPAD    1664               // 13*128, padded row count for f16 act arrays
#define DMODEL  512
#define DINNER  1024
#define NSTATE  16
#define DRANK   32
#define NLAYER  8
#define NCLS    1000
#define PDIM    3840               // 16*16*15

typedef _Float16 f16x8 __attribute__((ext_vector_type(8)));
typedef float    f32x4 __attribute__((ext_vector_type(4)));

// Fast transcendentals (v_exp/v_log/v_rcp based; ~1e-7 rel err, fine vs 0.0156 absmax)
__device__ __forceinline__ float f_rcp(float x) { return __builtin_amdgcn_rcpf(x); }
__device__ __forceinline__ float sp_silu(float x) { return x * f_rcp(1.0f + __expf(-x)); }
__device__ __forceinline__ float sp_softplus(float x) {
    return x > 20.0f ? x : __logf(1.0f + __expf(x));
}

// N interleaved 16-lane row sums (row_shr DPP tree); lane 15 of each row gets
// the sum. dpp_ctrl must be a literal constant -> explicit 4-step expansion.
#define DPP_ROW_SHR_STEP(P, NB, CTRL)                                          \
    {                                                                          \
        float t_[NB];                                                          \
        _Pragma("unroll")                                                      \
        for (int i_ = 0; i_ < NB; ++i_)                                        \
            t_[i_] = __int_as_float(__builtin_amdgcn_update_dpp(               \
                0, __float_as_int(P[i_]), CTRL, 0xF, 0xF, true));              \
        _Pragma("unroll")                                                      \
        for (int i_ = 0; i_ < NB; ++i_) P[i_] += t_[i_];                       \
    }

template <int NB>
__device__ __forceinline__ void row_sum16v(float* p) {
    DPP_ROW_SHR_STEP(p, NB, 0x111);   // row_shr:1
    DPP_ROW_SHR_STEP(p, NB, 0x112);   // row_shr:2
    DPP_ROW_SHR_STEP(p, NB, 0x114);   // row_shr:4
    DPP_ROW_SHR_STEP(p, NB, 0x118);   // row_shr:8
}

// Store value v as f16 hi/lo split at swizzled position (row, k) of a [*][K] array.
// Swizzle: byte-in-row ^= (row&7)<<4  (permutes 16B blocks within 128B chunks).
__device__ __forceinline__ void store_split(char* __restrict__ Hb, char* __restrict__ Lb,
                                            int row, int k, int K, float v) {
    size_t byte = (size_t)row * (size_t)(K * 2) +
                  (size_t)(((unsigned)(k * 2)) ^ (unsigned)((row & 7) << 4));
    __half h = __float2half_rn(v);
    *(__half*)(Hb + byte) = h;
    *(__half*)(Lb + byte) = __float2half_rn((v - __half2float(h)) * 2048.0f);
}

// 4 consecutive k (k4 multiple of 4): one 8B store per array (coalescable).
__device__ __forceinline__ void store_split4(char* __restrict__ Hb, char* __restrict__ Lb,
                                             int row, int k4, int K, float4 v) {
    size_t byte = (size_t)row * (size_t)(K * 2) +
                  (size_t)(((unsigned)(k4 * 2)) ^ (unsigned)((row & 7) << 4));
    __half h0 = __float2half_rn(v.x), h1 = __float2half_rn(v.y),
           h2 = __float2half_rn(v.z), h3 = __float2half_rn(v.w);
    *(ushort4*)(Hb + byte) = make_ushort4(
        __half_as_ushort(h0), __half_as_ushort(h1),
        __half_as_ushort(h2), __half_as_ushort(h3));
    *(ushort4*)(Lb + byte) = make_ushort4(
        __half_as_ushort(__float2half_rn((v.x - __half2float(h0)) * 2048.0f)),
        __half_as_ushort(__float2half_rn((v.y - __half2float(h1)) * 2048.0f)),
        __half_as_ushort(__float2half_rn((v.z - __half2float(h2)) * 2048.0f)),
        __half_as_ushort(__float2half_rn((v.w - __half2float(h3)) * 2048.0f)));
}

// 256-thread block reduction of two values; lds must be 8 floats.
__device__ __forceinline__ float2 block_reduce2(float a, float b, float* lds) {
#pragma unroll
    for (int off = 32; off > 0; off >>= 1) {
        a += __shfl_down(a, off);
        b += __shfl_down(b, off);
    }
    int lane = threadIdx.x & 63, w = threadIdx.x >> 6;
    if (lane == 0) { lds[w] = a; lds[4 + w] = b; }
    __syncthreads();
    float sa = lds[0] + lds[1] + lds[2] + lds[3];
    float sb = lds[4] + lds[5] + lds[6] + lds[7];
    return make_float2(sa, sb);
}

// ---------------------------------------------------------------- patch stage
__global__ __launch_bounds__(256) void k_patch_ln(
    const float* __restrict__ img, const float* __restrict__ lnw,
    const float* __restrict__ lnb, char* __restrict__ Xph, char* __restrict__ Xpl) {
    __shared__ float vals[PDIM];
    __shared__ float red[8];
    int tok = blockIdx.x;
    int b = tok / NPATCH, p = tok % NPATCH;
    int gy = p / 14, gx = p % 14;
    int tid = threadIdx.x;
    int py = tid >> 4, px = tid & 15;
    int h0 = gy * 16 + py, w0 = gx * 16 + px;
    const int dh[5] = {0, 0, 0, -1, 1};
    const int dw[5] = {0, -1, 1, 0, 0};
    float s = 0.f, ss = 0.f;
#pragma unroll
    for (int c = 0; c < 15; ++c) {
        int g = c / 3, ch = c % 3;
        int h = h0 + dh[g], w = w0 + dw[g];
        float v = 0.f;
        if ((unsigned)h < 224u && (unsigned)w < 224u)
            v = img[((b * 3 + ch) * 224 + h) * 224 + w];
        vals[tid * 15 + c] = v;
        s += v; ss += v * v;
    }
    float2 t2 = block_reduce2(s, ss, red);
    float mean = t2.x * (1.0f / PDIM);
    float var  = t2.y * (1.0f / PDIM) - mean * mean;
    float rstd = 1.0f / sqrtf(var + 1e-5f);
    for (int j = 0; j < 15; ++j) {
        int e = tid + j * 256;
        float v = (vals[e] - mean) * rstd * lnw[e] + lnb[e];
        store_split(Xph, Xpl, tok, e, PDIM, v);
    }
}

// ------------------------------------------------------------------- token LN
__global__ __launch_bounds__(256) void k_ln(
    const float* __restrict__ x, const float* __restrict__ w,
    const float* __restrict__ b, char* __restrict__ yh, char* __restrict__ yl) {
    __shared__ float red[8];
    int t = blockIdx.x, tid = threadIdx.x;
    const float* xr = x + (size_t)t * DMODEL;
    float v0 = xr[tid], v1 = xr[tid + 256];
    float2 t2 = block_reduce2(v0 + v1, v0 * v0 + v1 * v1, red);
    float mean = t2.x * (1.0f / DMODEL);
    float var  = t2.y * (1.0f / DMODEL) - mean * mean;
    float rstd = 1.0f / sqrtf(var + 1e-5f);
    store_split(yh, yl, t, tid,       DMODEL, (v0 - mean) * rstd * w[tid]       + b[tid]);
    store_split(yh, yl, t, tid + 256, DMODEL, (v1 - mean) * rstd * w[tid + 256] + b[tid + 256]);
}

// ------------- fused: xtok += sum(part[0..3]); yln = LN(xtok) (f16 split out)
__global__ __launch_bounds__(256) void k_red_ln(
    const float* __restrict__ part, float* __restrict__ xtok,
    const float* __restrict__ w, const float* __restrict__ b,
    char* __restrict__ yh, char* __restrict__ yl) {
    __shared__ float red[8];
    int t = blockIdx.x, tid = threadIdx.x;
    size_t base = (size_t)t * DMODEL;
    float v0 = xtok[base + tid], v1 = xtok[base + tid + 256];
#pragma unroll
    for (int k = 0; k < 4; ++k) {
        v0 += part[(size_t)k * (NTOK * DMODEL) + base + tid];
        v1 += part[(size_t)k * (NTOK * DMODEL) + base + tid + 256];
    }
    xtok[base + tid] = v0;
    xtok[base + tid + 256] = v1;
    float2 t2 = block_reduce2(v0 + v1, v0 * v0 + v1 * v1, red);
    float mean = t2.x * (1.0f / DMODEL);
    float var  = t2.y * (1.0f / DMODEL) - mean * mean;
    float rstd = 1.0f / sqrtf(var + 1e-5f);
    store_split(yh, yl, t, tid,       DMODEL, (v0 - mean) * rstd * w[tid]       + b[tid]);
    store_split(yh, yl, t, tid + 256, DMODEL, (v1 - mean) * rstd * w[tid + 256] + b[tid + 256]);
}

// --------------------------------------------- weight transpose + f16 split
__global__ __launch_bounds__(256) void k_wT(
    const float* __restrict__ W, char* __restrict__ Th, char* __restrict__ Tl,
    int Ks, int Ns, size_t wStride, size_t tByteStride) {
    __shared__ float t[32][33];
    int z = blockIdx.z;
    const float* Wz = W + (size_t)z * wStride;
    char* ThZ = Th + (size_t)z * tByteStride;
    char* TlZ = Tl + (size_t)z * tByteStride;
    int n0 = blockIdx.x * 32, k0 = blockIdx.y * 32;
    int tx = threadIdx.x, ty = threadIdx.y;
#pragma unroll
    for (int r = 0; r < 4; ++r) {
        int k = k0 + ty + r * 8, n = n0 + tx;
        t[tx][ty + r * 8] = (n < Ns) ? Wz[(size_t)k * Ns + n] : 0.f;
    }
    __syncthreads();
#pragma unroll
    for (int r = 0; r < 4; ++r) {
        int n = n0 + ty + r * 8, k = k0 + tx;
        float v = t[ty + r * 8][tx];
        size_t byte = (size_t)n * (size_t)(Ks * 2) +
                      (size_t)(((unsigned)(k * 2)) ^ (unsigned)((n & 7) << 4));
        __half h = __float2half_rn(v);
        *(__half*)(ThZ + byte) = h;
        *(__half*)(TlZ + byte) = __float2half_rn((v - __half2float(h)) * 2048.0f);
    }
}

// ------------------------------------------------- f16 split-2 MFMA GEMM
// Double-buffered LDS (128 KB) + bijective XCD-aware block remap.
__global__ __launch_bounds__(256, 1) void k_gemm_f16s(
    const char* __restrict__ Ah, const char* __restrict__ Al,
    const char* __restrict__ Bh, const char* __restrict__ Bl,
    float* __restrict__ C, int M, int N, int K, int kchunk, long partStride) {
    __shared__ __half L[2][4][128 * 64];
    const int tid = threadIdx.x, w = tid >> 6, lane = tid & 63;

    // XCD-aware remap: hw-linear id -> contiguous chunk of (m-fastest) work order
    const int GX = gridDim.x, GY = gridDim.y;
    const int nwg = GX * GY * gridDim.z;
    const int orig = blockIdx.x + GX * (blockIdx.y + GY * blockIdx.z);
    const int q = nwg >> 3, r = nwg & 7, xcd = orig & 7, pos = orig >> 3;
    const int wrk = (xcd < r ? xcd * (q + 1) : r * (q + 1) + (xcd - r) * q) + pos;
    const int bm = wrk % GY;
    const int t1 = wrk / GY;
    const int bn = t1 % GX, bz = t1 / GX;

    const int m0 = bm * 128, n0 = bn * 128;
    const int kbeg = bz * kchunk;
    int kend = kbeg + kchunk; if (kend > K) kend = K;
    C += (size_t)bz * (size_t)partStride;
    const size_t K2 = (size_t)K * 2;
    const int srowBase = 32 * w;          // wave-uniform
    const int srLane = lane >> 3;         // 0..7
    const int scol = (lane & 7) * 16;

    f32x4 acch[4][4], accx[4][4];
#pragma unroll
    for (int i = 0; i < 4; ++i)
#pragma unroll
        for (int j = 0; j < 4; ++j) {
            acch[i][j] = (f32x4)(0.f); accx[i][j] = (f32x4)(0.f);
        }

    auto STAGE = [&](int buf, int k0) {
#pragma unroll
        for (int t = 0; t < 4; ++t) {
            int lr = srowBase + 8 * t;                 // uniform LDS row base
            size_t ao = (size_t)(m0 + lr + srLane) * K2 + (size_t)k0 * 2 + scol;
            size_t bo = (size_t)(n0 + lr + srLane) * K2 + (size_t)k0 * 2 + scol;
            __builtin_amdgcn_global_load_lds(
                (const __attribute__((address_space(1))) void*)(Ah + ao),
                (__attribute__((address_space(3))) void*)&L[buf][0][lr * 64], 16, 0, 0);
            __builtin_amdgcn_global_load_lds(
                (const __attribute__((address_space(1))) void*)(Al + ao),
                (__attribute__((address_space(3))) void*)&L[buf][1][lr * 64], 16, 0, 0);
            __builtin_amdgcn_global_load_lds(
                (const __attribute__((address_space(1))) void*)(Bh + bo),
                (__attribute__((address_space(3))) void*)&L[buf][2][lr * 64], 16, 0, 0);
            __builtin_amdgcn_global_load_lds(
                (const __attribute__((address_space(1))) void*)(Bl + bo),
                (__attribute__((address_space(3))) void*)&L[buf][3][lr * 64], 16, 0, 0);
        }
    };

    const int wr = (w >> 1) * 64, wc = (w & 1) * 64;
    const int g = lane >> 4, rr = lane & 15;
    const int nk = (kend - kbeg + 63) / 64;

    STAGE(0, kbeg);
    asm volatile("s_waitcnt vmcnt(0)" ::: "memory");
    __syncthreads();

    for (int t = 0; t < nk; ++t) {
        int cur = t & 1;
        if (t + 1 < nk) STAGE(cur ^ 1, kbeg + (t + 1) * 64);
        const __half* LAh = L[cur][0];
        const __half* LAl = L[cur][1];
        const __half* LBh = L[cur][2];
        const __half* LBl = L[cur][3];
#pragma unroll
        for (int kk = 0; kk < 2; ++kk) {
            f16x8 afh[4], afl[4], bfh[4], bfl[4];
#pragma unroll
            for (int mf = 0; mf < 4; ++mf) {
                int row = wr + mf * 16 + rr;
                int off = row * 128 + ((kk * 64 + g * 16) ^ ((row & 7) << 4));
                afh[mf] = *(const f16x8*)((const char*)LAh + off);
                afl[mf] = *(const f16x8*)((const char*)LAl + off);
            }
#pragma unroll
            for (int nf = 0; nf < 4; ++nf) {
                int row = wc + nf * 16 + rr;
                int off = row * 128 + ((kk * 64 + g * 16) ^ ((row & 7) << 4));
                bfh[nf] = *(const f16x8*)((const char*)LBh + off);
                bfl[nf] = *(const f16x8*)((const char*)LBl + off);
            }
#pragma unroll
            for (int mf = 0; mf < 4; ++mf)
#pragma unroll
                for (int nf = 0; nf < 4; ++nf) {
                    acch[mf][nf] = __builtin_amdgcn_mfma_f32_16x16x32_f16(
                        afh[mf], bfh[nf], acch[mf][nf], 0, 0, 0);
                    accx[mf][nf] = __builtin_amdgcn_mfma_f32_16x16x32_f16(
                        afl[mf], bfh[nf], accx[mf][nf], 0, 0, 0);
                    accx[mf][nf] = __builtin_amdgcn_mfma_f32_16x16x32_f16(
                        afh[mf], bfl[nf], accx[mf][nf], 0, 0, 0);
                }
        }
        asm volatile("s_waitcnt vmcnt(0)" ::: "memory");
        __syncthreads();
    }

#pragma unroll
    for (int mf = 0; mf < 4; ++mf)
#pragma unroll
        for (int nf = 0; nf < 4; ++nf)
#pragma unroll
            for (int e = 0; e < 4; ++e) {
                int gm = m0 + wr + mf * 16 + g * 4 + e;
                int gn = n0 + wc + nf * 16 + rr;
                if (gm < M && gn < N)
                    C[(size_t)gm * N + gn] =
                        acch[mf][nf][e] + accx[mf][nf][e] * (1.0f / 2048.0f);
            }
}

// ------------------------------------------------------ split-K reduce
template <int SK, bool ACC>
__global__ __launch_bounds__(256) void k_reduce(
    const float* __restrict__ part, float* __restrict__ out, int total, int stride) {
    int i = blockIdx.x * 256 + threadIdx.x;
    if (i >= total) return;
    float s = 0.f;
#pragma unroll
    for (int k = 0; k < SK; ++k) s += part[(size_t)k * stride + i];
    out[i] = ACC ? out[i] + s : s;
}

// ---------------------------------------------- assemble tokens (+cls, +pos)
__global__ __launch_bounds__(256) void k_assemble(
    const float* __restrict__ Pe, const float* __restrict__ patch_b,
    const float* __restrict__ cls, const float* __restrict__ pos,
    float* __restrict__ xtok) {
    int idx = blockIdx.x * 256 + threadIdx.x;
    if (idx >= NTOK * DMODEL) return;
    int d = idx % DMODEL;
    int t = (idx / DMODEL) % LSEQ;
    int b = idx / (DMODEL * LSEQ);
    float v = (t < NPATCH) ? (Pe[((size_t)b * NPATCH + t) * DMODEL + d] + patch_b[d])
                           : cls[d];
    xtok[idx] = v + pos[t * DMODEL + d];
}

// ------------- causal depthwise conv (K=4) + SiLU + split, 4 d's per thread
__global__ __launch_bounds__(256) void k_conv(
    const float* __restrict__ xz, const float* __restrict__ cw,
    const float* __restrict__ cb, float* __restrict__ u,
    char* __restrict__ uh, char* __restrict__ ul) {
    int idx = blockIdx.x * 256 + threadIdx.x;
    if (idx >= NTOK * (DINNER / 4)) return;
    int dq = idx & (DINNER / 4 - 1);
    int t  = idx / (DINNER / 4);
    int l  = t % LSEQ;
    int d  = dq * 4;
    float4 w0 = *(const float4*)&cw[(d + 0) * 4];
    float4 w1 = *(const float4*)&cw[(d + 1) * 4];
    float4 w2 = *(const float4*)&cw[(d + 2) * 4];
    float4 w3 = *(const float4*)&cw[(d + 3) * 4];
    float4 acc = *(const float4*)&cb[d];
#pragma unroll
    for (int j = 0; j < 4; ++j) {
        int ls = l - 3 + j;
        if (ls >= 0) {
            float4 x4 = *(const float4*)&xz[(size_t)(t - 3 + j) * (2 * DINNER) + d];
            acc.x += (&w0.x)[j] * x4.x;
            acc.y += (&w1.x)[j] * x4.y;
            acc.z += (&w2.x)[j] * x4.z;
            acc.w += (&w3.x)[j] * x4.w;
        }
    }
    float4 uv = make_float4(sp_silu(acc.x), sp_silu(acc.y),
                            sp_silu(acc.z), sp_silu(acc.w));
    *(float4*)&u[(size_t)t * DINNER + d] = uv;
    store_split4(uh, ul, t, d, DINNER, uv);
}

// ------- selective scan v5: fused dt-proj + LDS stage + pipelined batch-8
// recurrence with interleaved DPP rowsums + fused gate (vectorized stores).
// grid (DINNER/16, BATCH), 256 thr.
__global__ __launch_bounds__(256) void k_scan2(
    const float* __restrict__ u, const float* __restrict__ dbc,
    const float* __restrict__ dtw, const float* __restrict__ dtb,
    const float* __restrict__ Alog, const float* __restrict__ Dp,
    const float* __restrict__ xz, char* __restrict__ gh, char* __restrict__ gl) {
    __shared__ float uS[LPAD * 16];
    __shared__ float dS[LPAD * 16];   // dt in, y out (slot l dead after iter l)
    __shared__ float bS[LPAD * 16];
    __shared__ float cS[LPAD * 16];
    __shared__ float wS[DRANK * 16];  // dt_w columns d0..d0+15
    const int tid = threadIdx.x;
    const int b = blockIdx.y, d0 = blockIdx.x * 16;

    // phase 0: dtw columns to LDS
    for (int i = tid; i < DRANK * 16; i += 256)
        wS[i] = dtw[(size_t)(i >> 4) * DINNER + d0 + (i & 15)];
    __syncthreads();

    // phase 1: stage u/B/C, compute dt = softplus(r@dtw + b); zero-fill pad rows
    const float* ub   = u   + ((size_t)b * LSEQ) * DINNER + d0;
    const float* dbcB = dbc + ((size_t)b * LSEQ) * 64;
    for (int i = tid; i < LPAD * 4; i += 256) {
        int l = i >> 2, j = (i & 3) << 2;
        if (l >= LSEQ) {
            float4 z = make_float4(0.f, 0.f, 0.f, 0.f);
            *(float4*)&uS[l * 16 + j] = z;
            *(float4*)&dS[l * 16 + j] = z;
            *(float4*)&bS[l * 16 + j] = z;
            *(float4*)&cS[l * 16 + j] = z;
            continue;
        }
        *(float4*)&uS[l * 16 + j] = *(const float4*)&ub[(size_t)l * DINNER + j];
        *(float4*)&bS[l * 16 + j] = *(const float4*)&dbcB[(size_t)l * 64 + DRANK + j];
        *(float4*)&cS[l * 16 + j] = *(const float4*)&dbcB[(size_t)l * 64 + DRANK + 16 + j];
        float4 acc = *(const float4*)&dtb[d0 + j];
#pragma unroll
        for (int kq = 0; kq < DRANK / 4; ++kq) {
            float4 r4 = *(const float4*)&dbcB[(size_t)l * 64 + kq * 4];
#pragma unroll
            for (int m = 0; m < 4; ++m) {
                float rv = (&r4.x)[m];
                float4 w4 = *(const float4*)&wS[(kq * 4 + m) * 16 + j];
                acc.x += rv * w4.x; acc.y += rv * w4.y;
                acc.z += rv * w4.z; acc.w += rv * w4.w;
            }
        }
        dS[l * 16 + j + 0] = sp_softplus(acc.x);
        dS[l * 16 + j + 1] = sp_softplus(acc.y);
        dS[l * 16 + j + 2] = sp_softplus(acc.z);
        dS[l * 16 + j + 3] = sp_softplus(acc.w);
    }
    const int n = tid & 15, dsub = tid >> 4;
    const int d = d0 + dsub;
    const float A  = -__expf(Alog[d * NSTATE + n]);
    const float Dv = Dp[d];
    __syncthreads();

    // phase 2: batch-8 software-pipelined recurrence.
    // dsub columns are wave-private (wave w covers dsub 4w..4w+3), so the
    // in-loop dS y-writes never race with other waves' reads.
    float hn = 0.f;
    float dtc[8], uvc[8], Bnc[8], Cnc[8];
#pragma unroll
    for (int i = 0; i < 8; ++i) {
        int o = i * 16;
        dtc[i] = dS[o + dsub]; uvc[i] = uS[o + dsub];
        Bnc[i] = bS[o + n];    Cnc[i] = cS[o + n];
    }
    for (int lb = 0; lb < LPAD; lb += 8) {
        float dtN[8], uvN[8], BnN[8], CnN[8];
        if (lb + 8 < LPAD) {
#pragma unroll
            for (int i = 0; i < 8; ++i) {
                int o = (lb + 8 + i) * 16;
                dtN[i] = dS[o + dsub]; uvN[i] = uS[o + dsub];
                BnN[i] = bS[o + n];    CnN[i] = cS[o + n];
            }
        } else {
#pragma unroll
            for (int i = 0; i < 8; ++i) { dtN[i] = uvN[i] = BnN[i] = CnN[i] = 0.f; }
        }
        float a8[8], b8[8], p8[8];
#pragma unroll
        for (int i = 0; i < 8; ++i) {
            a8[i] = __expf(dtc[i] * A);
            b8[i] = dtc[i] * uvc[i] * Bnc[i];
        }
#pragma unroll
        for (int i = 0; i < 8; ++i) {
            hn = a8[i] * hn + b8[i];
            p8[i] = hn * Cnc[i];
        }
        row_sum16v<8>(p8);
#pragma unroll
        for (int i = 0; i < 8; ++i)
            if (n == 15) dS[(lb + i) * 16 + dsub] = p8[i] + uvc[i] * Dv;
#pragma unroll
        for (int i = 0; i < 8; ++i) {
            dtc[i] = dtN[i]; uvc[i] = uvN[i]; Bnc[i] = BnN[i]; Cnc[i] = CnN[i];
        }
    }
    __syncthreads();

    // phase 3: fused gate g = y * silu(z); vectorized f16 hi/lo swizzled stores
    const float* zb = xz + ((size_t)b * LSEQ) * (2 * DINNER) + DINNER + d0;
    for (int i = tid; i < LSEQ * 4; i += 256) {
        int l = i >> 2, j = (i & 3) << 2;
        float4 z4 = *(const float4*)&zb[(size_t)l * (2 * DINNER) + j];
        int t = b * LSEQ + l;
        float4 g4 = make_float4(dS[l * 16 + j + 0] * sp_silu(z4.x),
                                dS[l * 16 + j + 1] * sp_silu(z4.y),
                                dS[l * 16 + j + 2] * sp_silu(z4.z),
                                dS[l * 16 + j + 3] * sp_silu(z4.w));
        store_split4(gh, gl, t, d0 + j, DINNER, g4);
    }
}

// ------------------------------------------------------------ head: LN + FC
__global__ __launch_bounds__(256) void k_head(
    const float* __restrict__ xtok, const float* __restrict__ lnw,
    const float* __restrict__ lnb, const float* __restrict__ hw,
    const float* __restrict__ hb, float* __restrict__ out) {
    __shared__ float red[8];
    __shared__ float xr[DMODEL];
    int b = blockIdx.y, tid = threadIdx.x;
    const float* row = xtok + ((size_t)(b * LSEQ + NPATCH)) * DMODEL;
    float v0 = row[tid], v1 = row[tid + 256];
    float2 t2 = block_reduce2(v0 + v1, v0 * v0 + v1 * v1, red);
    float mean = t2.x * (1.0f / DMODEL);
    float var  = t2.y * (1.0f / DMODEL) - mean * mean;
    float rstd = 1.0f / sqrtf(var + 1e-5f);
    xr[tid]       = (v0 - mean) * rstd * lnw[tid] + lnb[tid];
    xr[tid + 256] = (v1 - mean) * rstd * lnw[tid + 256] + lnb[tid + 256];
    __syncthreads();
    int c = blockIdx.x * 256 + tid;
    if (c < NCLS) {
        float acc = hb[c];
#pragma unroll 8
        for (int k = 0; k < DMODEL; ++k) acc += xr[k] * hw[k * NCLS + c];
        out[b * NCLS + c] = acc;
    }
}

extern "C" void kernel_launch(void* const* d_in, const int* in_sizes, int n_in,
                              void* d_out, int out_size, void* d_ws, size_t ws_size,
                              hipStream_t stream) {
    const float* img     = (const float*)d_in[0];
    const float* plnw    = (const float*)d_in[1];
    const float* plnb    = (const float*)d_in[2];
    const float* patch_w = (const float*)d_in[3];
    const float* patch_b = (const float*)d_in[4];
    const float* pos     = (const float*)d_in[5];
    const float* cls     = (const float*)d_in[6];
    const float* ln_w    = (const float*)d_in[7];
    const float* ln_b    = (const float*)d_in[8];
    const float* in_w    = (const float*)d_in[9];
    const float* conv_w  = (const float*)d_in[10];
    const float* conv_b  = (const float*)d_in[11];
    const float* xproj   = (const float*)d_in[12];
    const float* dt_w    = (const float*)d_in[13];
    const float* dt_b    = (const float*)d_in[14];
    const float* A_log   = (const float*)d_in[15];
    const float* Dp      = (const float*)d_in[16];
    const float* out_w   = (const float*)d_in[17];
    const float* hlnw    = (const float*)d_in[18];
    const float* hlnb    = (const float*)d_in[19];
    const float* head_w  = (const float*)d_in[20];
    const float* head_b  = (const float*)d_in[21];
    float* out = (float*)d_out;

    char* p = (char*)d_ws;
    auto alloc = [&](size_t bytes) { char* r = p; p += (bytes + 255) & ~(size_t)255; return r; };
    float* xtok = (float*)alloc((size_t)NTOK * DMODEL * 4);
    float* xz   = (float*)alloc((size_t)NTOK * 2 * DINNER * 4);
    float* u    = (float*)alloc((size_t)NTOK * DINNER * 4);
    float* dbc  = (float*)alloc((size_t)NTOK * 64 * 4);
    float* Pe   = (float*)alloc((size_t)NPTOK * DMODEL * 4);
    float* part = (float*)alloc((size_t)4 * NTOK * DMODEL * 4);
    char* ylnH = alloc((size_t)MPAD * DMODEL * 2);
    char* ylnL = alloc((size_t)MPAD * DMODEL * 2);
    char* uH   = alloc((size_t)MPAD * DINNER * 2);
    char* uL   = alloc((size_t)MPAD * DINNER * 2);
    char* gH   = alloc((size_t)MPAD * DINNER * 2);
    char* gL   = alloc((size_t)MPAD * DINNER * 2);
    char* XpH  = alloc((size_t)MPAD * PDIM * 2);
    char* XpL  = alloc((size_t)MPAD * PDIM * 2);
    char* inTH  = alloc((size_t)NLAYER * 2 * DINNER * DMODEL * 2);
    char* inTL  = alloc((size_t)NLAYER * 2 * DINNER * DMODEL * 2);
    char* outTH = alloc((size_t)NLAYER * DMODEL * DINNER * 2);
    char* outTL = alloc((size_t)NLAYER * DMODEL * DINNER * 2);
    char* patTH = alloc((size_t)DMODEL * PDIM * 2);
    char* patTL = alloc((size_t)DMODEL * PDIM * 2);
    char* xprTH = alloc((size_t)NLAYER * 128 * DINNER * 2);
    char* xprTL = alloc((size_t)NLAYER * 128 * DINNER * 2);

    const size_t IN_T_B  = (size_t)2 * DINNER * DMODEL * 2;   // bytes/layer
    const size_t OUT_T_B = (size_t)DMODEL * DINNER * 2;
    const size_t XPR_T_B = (size_t)128 * DINNER * 2;

    // ---- one-time weight transpose + split (per call) ----
    k_wT<<<dim3(2 * DINNER / 32, DMODEL / 32, NLAYER), dim3(32, 8), 0, stream>>>(
        in_w, inTH, inTL, DMODEL, 2 * DINNER, (size_t)DMODEL * 2 * DINNER, IN_T_B);
    k_wT<<<dim3(DMODEL / 32, DINNER / 32, NLAYER), dim3(32, 8), 0, stream>>>(
        out_w, outTH, outTL, DINNER, DMODEL, (size_t)DINNER * DMODEL, OUT_T_B);
    k_wT<<<dim3(DMODEL / 32, PDIM / 32, 1), dim3(32, 8), 0, stream>>>(
        patch_w, patTH, patTL, PDIM, DMODEL, 0, 0);
    k_wT<<<dim3(128 / 32, DINNER / 32, NLAYER), dim3(32, 8), 0, stream>>>(
        xproj, xprTH, xprTL, DINNER, 64, (size_t)DINNER * 64, XPR_T_B);

    // ---- patch embedding ----
    k_patch_ln<<<NPTOK, 256, 0, stream>>>(img, plnw, plnb, XpH, XpL);
    k_gemm_f16s<<<dim3(4, 13, 4), 256, 0, stream>>>(
        XpH, XpL, patTH, patTL, part, NPTOK, DMODEL, PDIM, 960, (long)NPTOK * DMODEL);
    k_reduce<4, false><<<(NPTOK * DMODEL + 255) / 256, 256, 0, stream>>>(
        part, Pe, NPTOK * DMODEL, NPTOK * DMODEL);
    k_assemble<<<(NTOK * DMODEL + 255) / 256, 256, 0, stream>>>(Pe, patch_b, cls, pos, xtok);

    // ---- mamba layers ----
    for (int i = 0; i < NLAYER; ++i) {
        if (i == 0) {
            k_ln<<<NTOK, 256, 0, stream>>>(xtok, ln_w, ln_b, ylnH, ylnL);
        } else {
            // fused: xtok += sum(part) from previous layer's out_w, then LN
            k_red_ln<<<NTOK, 256, 0, stream>>>(part, xtok, ln_w + i * DMODEL,
                                               ln_b + i * DMODEL, ylnH, ylnL);
        }
        k_gemm_f16s<<<dim3(16, 13, 1), 256, 0, stream>>>(
            ylnH, ylnL, inTH + i * IN_T_B, inTL + i * IN_T_B,
            xz, NTOK, 2 * DINNER, DMODEL, DMODEL, 0);
        k_conv<<<(NTOK * (DINNER / 4) + 255) / 256, 256, 0, stream>>>(
            xz, conv_w + (size_t)i * DINNER * 4, conv_b + (size_t)i * DINNER, u, uH, uL);
        k_gemm_f16s<<<dim3(1, 13, 8), 256, 0, stream>>>(
            uH, uL, xprTH + i * XPR_T_B, xprTL + i * XPR_T_B,
            part, NTOK, 64, DINNER, 128, (long)NTOK * 64);
        k_reduce<8, false><<<(NTOK * 64 + 255) / 256, 256, 0, stream>>>(
            part, dbc, NTOK * 64, NTOK * 64);
        k_scan2<<<dim3(DINNER / 16, BATCH), 256, 0, stream>>>(
            u, dbc, dt_w + (size_t)i * DRANK * DINNER, dt_b + (size_t)i * DINNER,
            A_log + (size_t)i * DINNER * NSTATE, Dp + (size_t)i * DINNER,
            xz, gH, gL);
        k_gemm_f16s<<<dim3(4, 13, 4), 256, 0, stream>>>(
            gH, gL, outTH + i * OUT_T_B, outTL + i * OUT_T_B,
            part, NTOK, DMODEL, DINNER, 256, (long)NTOK * DMODEL);
    }
    // final residual reduce for layer 7's out_w
    k_reduce<4, true><<<(NTOK * DMODEL + 255) / 256, 256, 0, stream>>>(
        part, xtok, NTOK * DMODEL, NTOK * DMODEL);

    // ---- head ----
    k_head<<<dim3((NCLS + 255) / 256, BATCH), 256, 0, stream>>>(
        xtok, hlnw, hlnb, head_w, head_b, out);
}

// Round 10
// 614.526 us; speedup vs baseline: 5.6981x; 1.2402x over previous
//
#include <hip/hip_runtime.h>
#include <hip/hip_fp16.h>
#include <math.h>

#define BATCH   8
#define LSEQ    197
#define LPAD    200                // LSEQ padded to multiple of 8 for scan batches
#define NPATCH  196
#define NPTOK   (BATCH * NPATCH)   // 1568
#define NTOK    (BATCH * LSEQ)     // 1576
#define MPAD    1664               // 13*128, padded row count for f16 act arrays
#define DMODEL  512
#define DINNER  1024
#define NSTATE  16
#define DRANK   32
#define NLAYER  8
#define NCLS    1000
#define PDIM    3840               // 16*16*15

typedef _Float16 f16x8 __attribute__((ext_vector_type(8)));
typedef float    f32x4 __attribute__((ext_vector_type(4)));
typedef unsigned short us8 __attribute__((ext_vector_type(8)));

// Fast transcendentals (v_exp/v_log/v_rcp based; ~1e-7 rel err, fine vs 0.0156 absmax)
__device__ __forceinline__ float f_rcp(float x) { return __builtin_amdgcn_rcpf(x); }
__device__ __forceinline__ float sp_silu(float x) { return x * f_rcp(1.0f + __expf(-x)); }
__device__ __forceinline__ float sp_softplus(float x) {
    return x > 20.0f ? x : __logf(1.0f + __expf(x));
}

// N interleaved 16-lane row sums (row_shr DPP tree); lane 15 of each row gets
// the sum. dpp_ctrl must be a literal constant -> explicit 4-step expansion.
#define DPP_ROW_SHR_STEP(P, NB, CTRL)                                          \
    {                                                                          \
        float t_[NB];                                                          \
        _Pragma("unroll")                                                      \
        for (int i_ = 0; i_ < NB; ++i_)                                        \
            t_[i_] = __int_as_float(__builtin_amdgcn_update_dpp(               \
                0, __float_as_int(P[i_]), CTRL, 0xF, 0xF, true));              \
        _Pragma("unroll")                                                      \
        for (int i_ = 0; i_ < NB; ++i_) P[i_] += t_[i_];                       \
    }

template <int NB>
__device__ __forceinline__ void row_sum16v(float* p) {
    DPP_ROW_SHR_STEP(p, NB, 0x111);   // row_shr:1
    DPP_ROW_SHR_STEP(p, NB, 0x112);   // row_shr:2
    DPP_ROW_SHR_STEP(p, NB, 0x114);   // row_shr:4
    DPP_ROW_SHR_STEP(p, NB, 0x118);   // row_shr:8
}

// Store f16 value at swizzled position (row, k) of a [*][K] f16 array.
// Swizzle: byte-in-row ^= (row&7)<<4  (permutes 16B blocks within 128B chunks).
__device__ __forceinline__ void store_f16(char* __restrict__ Hb,
                                          int row, int k, int K, float v) {
    size_t byte = (size_t)row * (size_t)(K * 2) +
                  (size_t)(((unsigned)(k * 2)) ^ (unsigned)((row & 7) << 4));
    *(__half*)(Hb + byte) = __float2half_rn(v);
}

// 4 consecutive k (k4 multiple of 4): one 8B store (stays inside a 16B block).
__device__ __forceinline__ void store_f16x4(char* __restrict__ Hb,
                                            int row, int k4, int K, float4 v) {
    size_t byte = (size_t)row * (size_t)(K * 2) +
                  (size_t)(((unsigned)(k4 * 2)) ^ (unsigned)((row & 7) << 4));
    *(ushort4*)(Hb + byte) = make_ushort4(
        __half_as_ushort(__float2half_rn(v.x)), __half_as_ushort(__float2half_rn(v.y)),
        __half_as_ushort(__float2half_rn(v.z)), __half_as_ushort(__float2half_rn(v.w)));
}

// 256-thread block reduction of two values; lds must be 8 floats.
__device__ __forceinline__ float2 block_reduce2(float a, float b, float* lds) {
#pragma unroll
    for (int off = 32; off > 0; off >>= 1) {
        a += __shfl_down(a, off);
        b += __shfl_down(b, off);
    }
    int lane = threadIdx.x & 63, w = threadIdx.x >> 6;
    if (lane == 0) { lds[w] = a; lds[4 + w] = b; }
    __syncthreads();
    float sa = lds[0] + lds[1] + lds[2] + lds[3];
    float sb = lds[4] + lds[5] + lds[6] + lds[7];
    return make_float2(sa, sb);
}

// ---------------------------------------------------------------- patch stage
__global__ __launch_bounds__(256) void k_patch_ln(
    const float* __restrict__ img, const float* __restrict__ lnw,
    const float* __restrict__ lnb, char* __restrict__ Xph) {
    __shared__ float vals[PDIM];
    __shared__ float red[8];
    int tok = blockIdx.x;
    int b = tok / NPATCH, p = tok % NPATCH;
    int gy = p / 14, gx = p % 14;
    int tid = threadIdx.x;
    int py = tid >> 4, px = tid & 15;
    int h0 = gy * 16 + py, w0 = gx * 16 + px;
    const int dh[5] = {0, 0, 0, -1, 1};
    const int dw[5] = {0, -1, 1, 0, 0};
    float s = 0.f, ss = 0.f;
#pragma unroll
    for (int c = 0; c < 15; ++c) {
        int g = c / 3, ch = c % 3;
        int h = h0 + dh[g], w = w0 + dw[g];
        float v = 0.f;
        if ((unsigned)h < 224u && (unsigned)w < 224u)
            v = img[((b * 3 + ch) * 224 + h) * 224 + w];
        vals[tid * 15 + c] = v;
        s += v; ss += v * v;
    }
    float2 t2 = block_reduce2(s, ss, red);
    float mean = t2.x * (1.0f / PDIM);
    float var  = t2.y * (1.0f / PDIM) - mean * mean;
    float rstd = 1.0f / sqrtf(var + 1e-5f);
    for (int j = 0; j < 15; ++j) {
        int e = tid + j * 256;
        float v = (vals[e] - mean) * rstd * lnw[e] + lnb[e];
        store_f16(Xph, tok, e, PDIM, v);
    }
}

// ------------------------------------------------------------------- token LN
__global__ __launch_bounds__(256) void k_ln(
    const float* __restrict__ x, const float* __restrict__ w,
    const float* __restrict__ b, char* __restrict__ yh) {
    __shared__ float red[8];
    int t = blockIdx.x, tid = threadIdx.x;
    const float* xr = x + (size_t)t * DMODEL;
    float v0 = xr[tid], v1 = xr[tid + 256];
    float2 t2 = block_reduce2(v0 + v1, v0 * v0 + v1 * v1, red);
    float mean = t2.x * (1.0f / DMODEL);
    float var  = t2.y * (1.0f / DMODEL) - mean * mean;
    float rstd = 1.0f / sqrtf(var + 1e-5f);
    store_f16(yh, t, tid,       DMODEL, (v0 - mean) * rstd * w[tid]       + b[tid]);
    store_f16(yh, t, tid + 256, DMODEL, (v1 - mean) * rstd * w[tid + 256] + b[tid + 256]);
}

// ------------- fused: xtok += sum(part[0..3]); yln = LN(xtok) (f16 out)
__global__ __launch_bounds__(256) void k_red_ln(
    const float* __restrict__ part, float* __restrict__ xtok,
    const float* __restrict__ w, const float* __restrict__ b,
    char* __restrict__ yh) {
    __shared__ float red[8];
    int t = blockIdx.x, tid = threadIdx.x;
    size_t base = (size_t)t * DMODEL;
    float v0 = xtok[base + tid], v1 = xtok[base + tid + 256];
#pragma unroll
    for (int k = 0; k < 4; ++k) {
        v0 += part[(size_t)k * (NTOK * DMODEL) + base + tid];
        v1 += part[(size_t)k * (NTOK * DMODEL) + base + tid + 256];
    }
    xtok[base + tid] = v0;
    xtok[base + tid + 256] = v1;
    float2 t2 = block_reduce2(v0 + v1, v0 * v0 + v1 * v1, red);
    float mean = t2.x * (1.0f / DMODEL);
    float var  = t2.y * (1.0f / DMODEL) - mean * mean;
    float rstd = 1.0f / sqrtf(var + 1e-5f);
    store_f16(yh, t, tid,       DMODEL, (v0 - mean) * rstd * w[tid]       + b[tid]);
    store_f16(yh, t, tid + 256, DMODEL, (v1 - mean) * rstd * w[tid + 256] + b[tid + 256]);
}

// --------------------------------------------- weight transpose + f16 cast
__global__ __launch_bounds__(256) void k_wT(
    const float* __restrict__ W, char* __restrict__ Th,
    int Ks, int Ns, size_t wStride, size_t tByteStride) {
    __shared__ float t[32][33];
    int z = blockIdx.z;
    const float* Wz = W + (size_t)z * wStride;
    char* ThZ = Th + (size_t)z * tByteStride;
    int n0 = blockIdx.x * 32, k0 = blockIdx.y * 32;
    int tx = threadIdx.x, ty = threadIdx.y;
#pragma unroll
    for (int r = 0; r < 4; ++r) {
        int k = k0 + ty + r * 8, n = n0 + tx;
        t[tx][ty + r * 8] = (n < Ns) ? Wz[(size_t)k * Ns + n] : 0.f;
    }
    __syncthreads();
#pragma unroll
    for (int r = 0; r < 4; ++r) {
        int n = n0 + ty + r * 8, k = k0 + tx;
        float v = t[ty + r * 8][tx];
        size_t byte = (size_t)n * (size_t)(Ks * 2) +
                      (size_t)(((unsigned)(k * 2)) ^ (unsigned)((n & 7) << 4));
        *(__half*)(ThZ + byte) = __float2half_rn(v);
    }
}

// ------------------------------------------------- f16 single MFMA GEMM
// 128x128 tile, BK=64, dbuf LDS 64KB -> 2 blocks/CU. XCD-aware block remap.
// F16OUT: write C as f16 (plain [M][N] ushort) instead of fp32.
template <bool F16OUT>
__global__ __launch_bounds__(256, 2) void k_gemm_f16(
    const char* __restrict__ Ah, const char* __restrict__ Bh,
    float* __restrict__ C, unsigned short* __restrict__ C16,
    int M, int N, int K, int kchunk, long partStride) {
    __shared__ __half L[2][2][128 * 64];
    const int tid = threadIdx.x, w = tid >> 6, lane = tid & 63;

    // XCD-aware remap: hw-linear id -> contiguous chunk of (m-fastest) work order
    const int GX = gridDim.x, GY = gridDim.y;
    const int nwg = GX * GY * gridDim.z;
    const int orig = blockIdx.x + GX * (blockIdx.y + GY * blockIdx.z);
    const int q = nwg >> 3, r = nwg & 7, xcd = orig & 7, pos = orig >> 3;
    const int wrk = (xcd < r ? xcd * (q + 1) : r * (q + 1) + (xcd - r) * q) + pos;
    const int bm = wrk % GY;
    const int t1 = wrk / GY;
    const int bn = t1 % GX, bz = t1 / GX;

    const int m0 = bm * 128, n0 = bn * 128;
    const int kbeg = bz * kchunk;
    int kend = kbeg + kchunk; if (kend > K) kend = K;
    C += (size_t)bz * (size_t)partStride;
    const size_t K2 = (size_t)K * 2;
    const int srowBase = 32 * w;          // wave-uniform
    const int srLane = lane >> 3;         // 0..7
    const int scol = (lane & 7) * 16;

    f32x4 acc[4][4];
#pragma unroll
    for (int i = 0; i < 4; ++i)
#pragma unroll
        for (int j = 0; j < 4; ++j) acc[i][j] = (f32x4)(0.f);

    auto STAGE = [&](int buf, int k0) {
#pragma unroll
        for (int t = 0; t < 4; ++t) {
            int lr = srowBase + 8 * t;                 // uniform LDS row base
            size_t ao = (size_t)(m0 + lr + srLane) * K2 + (size_t)k0 * 2 + scol;
            size_t bo = (size_t)(n0 + lr + srLane) * K2 + (size_t)k0 * 2 + scol;
            __builtin_amdgcn_global_load_lds(
                (const __attribute__((address_space(1))) void*)(Ah + ao),
                (__attribute__((address_space(3))) void*)&L[buf][0][lr * 64], 16, 0, 0);
            __builtin_amdgcn_global_load_lds(
                (const __attribute__((address_space(1))) void*)(Bh + bo),
                (__attribute__((address_space(3))) void*)&L[buf][1][lr * 64], 16, 0, 0);
        }
    };

    const int wr = (w >> 1) * 64, wc = (w & 1) * 64;
    const int g = lane >> 4, rr = lane & 15;
    const int nk = (kend - kbeg + 63) / 64;

    STAGE(0, kbeg);
    asm volatile("s_waitcnt vmcnt(0)" ::: "memory");
    __syncthreads();

    for (int t = 0; t < nk; ++t) {
        int cur = t & 1;
        if (t + 1 < nk) STAGE(cur ^ 1, kbeg + (t + 1) * 64);
        const __half* LA = L[cur][0];
        const __half* LB = L[cur][1];
#pragma unroll
        for (int kk = 0; kk < 2; ++kk) {
            f16x8 af[4], bf[4];
#pragma unroll
            for (int mf = 0; mf < 4; ++mf) {
                int row = wr + mf * 16 + rr;
                int off = row * 128 + ((kk * 64 + g * 16) ^ ((row & 7) << 4));
                af[mf] = *(const f16x8*)((const char*)LA + off);
            }
#pragma unroll
            for (int nf = 0; nf < 4; ++nf) {
                int row = wc + nf * 16 + rr;
                int off = row * 128 + ((kk * 64 + g * 16) ^ ((row & 7) << 4));
                bf[nf] = *(const f16x8*)((const char*)LB + off);
            }
#pragma unroll
            for (int mf = 0; mf < 4; ++mf)
#pragma unroll
                for (int nf = 0; nf < 4; ++nf)
                    acc[mf][nf] = __builtin_amdgcn_mfma_f32_16x16x32_f16(
                        af[mf], bf[nf], acc[mf][nf], 0, 0, 0);
        }
        asm volatile("s_waitcnt vmcnt(0)" ::: "memory");
        __syncthreads();
    }

#pragma unroll
    for (int mf = 0; mf < 4; ++mf)
#pragma unroll
        for (int nf = 0; nf < 4; ++nf)
#pragma unroll
            for (int e = 0; e < 4; ++e) {
                int gm = m0 + wr + mf * 16 + g * 4 + e;
                int gn = n0 + wc + nf * 16 + rr;
                if (gm < M && gn < N) {
                    if (F16OUT)
                        C16[(size_t)gm * N + gn] =
                            __half_as_ushort(__float2half_rn(acc[mf][nf][e]));
                    else
                        C[(size_t)gm * N + gn] = acc[mf][nf][e];
                }
            }
}

// ------------------------------------------------------ split-K reduce
template <int SK, bool ACC>
__global__ __launch_bounds__(256) void k_reduce(
    const float* __restrict__ part, float* __restrict__ out, int total, int stride) {
    int i = blockIdx.x * 256 + threadIdx.x;
    if (i >= total) return;
    float s = 0.f;
#pragma unroll
    for (int k = 0; k < SK; ++k) s += part[(size_t)k * stride + i];
    out[i] = ACC ? out[i] + s : s;
}

// ---------------------------------------------- assemble tokens (+cls, +pos)
__global__ __launch_bounds__(256) void k_assemble(
    const float* __restrict__ Pe, const float* __restrict__ patch_b,
    const float* __restrict__ cls, const float* __restrict__ pos,
    float* __restrict__ xtok) {
    int idx = blockIdx.x * 256 + threadIdx.x;
    if (idx >= NTOK * DMODEL) return;
    int d = idx % DMODEL;
    int t = (idx / DMODEL) % LSEQ;
    int b = idx / (DMODEL * LSEQ);
    float v = (t < NPATCH) ? (Pe[((size_t)b * NPATCH + t) * DMODEL + d] + patch_b[d])
                           : cls[d];
    xtok[idx] = v + pos[t * DMODEL + d];
}

// ------------- causal depthwise conv (K=4) + SiLU, f16 in/out, 4 d's/thread
__global__ __launch_bounds__(256) void k_conv(
    const unsigned short* __restrict__ xzH, const float* __restrict__ cw,
    const float* __restrict__ cb, char* __restrict__ uh) {
    int idx = blockIdx.x * 256 + threadIdx.x;
    if (idx >= NTOK * (DINNER / 4)) return;
    int dq = idx & (DINNER / 4 - 1);
    int t  = idx / (DINNER / 4);
    int l  = t % LSEQ;
    int d  = dq * 4;
    float4 w0 = *(const float4*)&cw[(d + 0) * 4];
    float4 w1 = *(const float4*)&cw[(d + 1) * 4];
    float4 w2 = *(const float4*)&cw[(d + 2) * 4];
    float4 w3 = *(const float4*)&cw[(d + 3) * 4];
    float4 acc = *(const float4*)&cb[d];
#pragma unroll
    for (int j = 0; j < 4; ++j) {
        int ls = l - 3 + j;
        if (ls >= 0) {
            union { ushort4 v; __half h[4]; } xu;
            xu.v = *(const ushort4*)&xzH[(size_t)(t - 3 + j) * (2 * DINNER) + d];
            acc.x += (&w0.x)[j] * __half2float(xu.h[0]);
            acc.y += (&w1.x)[j] * __half2float(xu.h[1]);
            acc.z += (&w2.x)[j] * __half2float(xu.h[2]);
            acc.w += (&w3.x)[j] * __half2float(xu.h[3]);
        }
    }
    float4 uv = make_float4(sp_silu(acc.x), sp_silu(acc.y),
                            sp_silu(acc.z), sp_silu(acc.w));
    store_f16x4(uh, t, d, DINNER, uv);
}

// ------- selective scan v6: fused dt-proj + LDS stage (f16 u) + pipelined
// batch-8 recurrence with interleaved DPP rowsums + fused gate (f16 z/out).
// grid (DINNER/16, BATCH), 256 thr.
__global__ __launch_bounds__(256) void k_scan2(
    const char* __restrict__ uH, const float* __restrict__ dbc,
    const float* __restrict__ dtw, const float* __restrict__ dtb,
    const float* __restrict__ Alog, const float* __restrict__ Dp,
    const unsigned short* __restrict__ xzH, char* __restrict__ gh) {
    __shared__ float uS[LPAD * 16];
    __shared__ float dS[LPAD * 16];   // dt in, y out (slot l dead after iter l)
    __shared__ float bS[LPAD * 16];
    __shared__ float cS[LPAD * 16];
    __shared__ float wS[DRANK * 16];  // dt_w columns d0..d0+15
    const int tid = threadIdx.x;
    const int b = blockIdx.y, d0 = blockIdx.x * 16;

    // phase 0: dtw columns to LDS
    for (int i = tid; i < DRANK * 16; i += 256)
        wS[i] = dtw[(size_t)(i >> 4) * DINNER + d0 + (i & 15)];
    __syncthreads();

    // phase 1a: stage u (f16 swizzled -> fp32 LDS); zero-fill pad rows
    for (int i = tid; i < LPAD * 2; i += 256) {
        int l = i >> 1, jj = i & 1;
        float* dst = &uS[l * 16 + jj * 8];
        if (l >= LSEQ) {
#pragma unroll
            for (int e = 0; e < 8; ++e) dst[e] = 0.f;
            continue;
        }
        int t = b * LSEQ + l;
        size_t byte = (size_t)t * (DINNER * 2) +
                      (size_t)(((unsigned)(d0 * 2 + jj * 16)) ^ (unsigned)((t & 7) << 4));
        union { us8 v; __half h[8]; } uu;
        uu.v = *(const us8*)(uH + byte);
#pragma unroll
        for (int e = 0; e < 8; ++e) dst[e] = __half2float(uu.h[e]);
    }

    // phase 1b: stage B/C, compute dt = softplus(r@dtw + b); zero-fill pad rows
    const float* dbcB = dbc + ((size_t)b * LSEQ) * 64;
    for (int i = tid; i < LPAD * 4; i += 256) {
        int l = i >> 2, j = (i & 3) << 2;
        if (l >= LSEQ) {
            float4 z = make_float4(0.f, 0.f, 0.f, 0.f);
            *(float4*)&dS[l * 16 + j] = z;
            *(float4*)&bS[l * 16 + j] = z;
            *(float4*)&cS[l * 16 + j] = z;
            continue;
        }
        *(float4*)&bS[l * 16 + j] = *(const float4*)&dbcB[(size_t)l * 64 + DRANK + j];
        *(float4*)&cS[l * 16 + j] = *(const float4*)&dbcB[(size_t)l * 64 + DRANK + 16 + j];
        float4 acc = *(const float4*)&dtb[d0 + j];
#pragma unroll
        for (int kq = 0; kq < DRANK / 4; ++kq) {
            float4 r4 = *(const float4*)&dbcB[(size_t)l * 64 + kq * 4];
#pragma unroll
            for (int m = 0; m < 4; ++m) {
                float rv = (&r4.x)[m];
                float4 w4 = *(const float4*)&wS[(kq * 4 + m) * 16 + j];
                acc.x += rv * w4.x; acc.y += rv * w4.y;
                acc.z += rv * w4.z; acc.w += rv * w4.w;
            }
        }
        dS[l * 16 + j + 0] = sp_softplus(acc.x);
        dS[l * 16 + j + 1] = sp_softplus(acc.y);
        dS[l * 16 + j + 2] = sp_softplus(acc.z);
        dS[l * 16 + j + 3] = sp_softplus(acc.w);
    }
    const int n = tid & 15, dsub = tid >> 4;
    const int d = d0 + dsub;
    const float A  = -__expf(Alog[d * NSTATE + n]);
    const float Dv = Dp[d];
    __syncthreads();

    // phase 2: batch-8 software-pipelined recurrence.
    // dsub columns are wave-private, so in-loop dS y-writes never race.
    float hn = 0.f;
    float dtc[8], uvc[8], Bnc[8], Cnc[8];
#pragma unroll
    for (int i = 0; i < 8; ++i) {
        int o = i * 16;
        dtc[i] = dS[o + dsub]; uvc[i] = uS[o + dsub];
        Bnc[i] = bS[o + n];    Cnc[i] = cS[o + n];
    }
    for (int lb = 0; lb < LPAD; lb += 8) {
        float dtN[8], uvN[8], BnN[8], CnN[8];
        if (lb + 8 < LPAD) {
#pragma unroll
            for (int i = 0; i < 8; ++i) {
                int o = (lb + 8 + i) * 16;
                dtN[i] = dS[o + dsub]; uvN[i] = uS[o + dsub];
                BnN[i] = bS[o + n];    CnN[i] = cS[o + n];
            }
        } else {
#pragma unroll
            for (int i = 0; i < 8; ++i) { dtN[i] = uvN[i] = BnN[i] = CnN[i] = 0.f; }
        }
        float a8[8], b8[8], p8[8];
#pragma unroll
        for (int i = 0; i < 8; ++i) {
            a8[i] = __expf(dtc[i] * A);
            b8[i] = dtc[i] * uvc[i] * Bnc[i];
        }
#pragma unroll
        for (int i = 0; i < 8; ++i) {
            hn = a8[i] * hn + b8[i];
            p8[i] = hn * Cnc[i];
        }
        row_sum16v<8>(p8);
#pragma unroll
        for (int i = 0; i < 8; ++i)
            if (n == 15) dS[(lb + i) * 16 + dsub] = p8[i] + uvc[i] * Dv;
#pragma unroll
        for (int i = 0; i < 8; ++i) {
            dtc[i] = dtN[i]; uvc[i] = uvN[i]; Bnc[i] = BnN[i]; Cnc[i] = CnN[i];
        }
    }
    __syncthreads();

    // phase 3: fused gate g = y * silu(z); z from f16 xz, vectorized f16 stores
    for (int i = tid; i < LSEQ * 4; i += 256) {
        int l = i >> 2, j = (i & 3) << 2;
        int t = b * LSEQ + l;
        union { ushort4 v; __half h[4]; } zu;
        zu.v = *(const ushort4*)&xzH[(size_t)t * (2 * DINNER) + DINNER + d0 + j];
        float4 g4 = make_float4(
            dS[l * 16 + j + 0] * sp_silu(__half2float(zu.h[0])),
            dS[l * 16 + j + 1] * sp_silu(__half2float(zu.h[1])),
            dS[l * 16 + j + 2] * sp_silu(__half2float(zu.h[2])),
            dS[l * 16 + j + 3] * sp_silu(__half2float(zu.h[3])));
        store_f16x4(gh, t, d0 + j, DINNER, g4);
    }
}

// ------------------------------------------------------------ head: LN + FC
__global__ __launch_bounds__(256) void k_head(
    const float* __restrict__ xtok, const float* __restrict__ lnw,
    const float* __restrict__ lnb, const float* __restrict__ hw,
    const float* __restrict__ hb, float* __restrict__ out) {
    __shared__ float red[8];
    __shared__ float xr[DMODEL];
    int b = blockIdx.y, tid = threadIdx.x;
    const float* row = xtok + ((size_t)(b * LSEQ + NPATCH)) * DMODEL;
    float v0 = row[tid], v1 = row[tid + 256];
    float2 t2 = block_reduce2(v0 + v1, v0 * v0 + v1 * v1, red);
    float mean = t2.x * (1.0f / DMODEL);
    float var  = t2.y * (1.0f / DMODEL) - mean * mean;
    float rstd = 1.0f / sqrtf(var + 1e-5f);
    xr[tid]       = (v0 - mean) * rstd * lnw[tid] + lnb[tid];
    xr[tid + 256] = (v1 - mean) * rstd * lnw[tid + 256] + lnb[tid + 256];
    __syncthreads();
    int c = blockIdx.x * 256 + tid;
    if (c < NCLS) {
        float acc = hb[c];
#pragma unroll 8
        for (int k = 0; k < DMODEL; ++k) acc += xr[k] * hw[k * NCLS + c];
        out[b * NCLS + c] = acc;
    }
}

extern "C" void kernel_launch(void* const* d_in, const int* in_sizes, int n_in,
                              void* d_out, int out_size, void* d_ws, size_t ws_size,
                              hipStream_t stream) {
    const float* img     = (const float*)d_in[0];
    const float* plnw    = (const float*)d_in[1];
    const float* plnb    = (const float*)d_in[2];
    const float* patch_w = (const float*)d_in[3];
    const float* patch_b = (const float*)d_in[4];
    const float* pos     = (const float*)d_in[5];
    const float* cls     = (const float*)d_in[6];
    const float* ln_w    = (const float*)d_in[7];
    const float* ln_b    = (const float*)d_in[8];
    const float* in_w    = (const float*)d_in[9];
    const float* conv_w  = (const float*)d_in[10];
    const float* conv_b  = (const float*)d_in[11];
    const float* xproj   = (const float*)d_in[12];
    const float* dt_w    = (const float*)d_in[13];
    const float* dt_b    = (const float*)d_in[14];
    const float* A_log   = (const float*)d_in[15];
    const float* Dp      = (const float*)d_in[16];
    const float* out_w   = (const float*)d_in[17];
    const float* hlnw    = (const float*)d_in[18];
    const float* hlnb    = (const float*)d_in[19];
    const float* head_w  = (const float*)d_in[20];
    const float* head_b  = (const float*)d_in[21];
    float* out = (float*)d_out;

    char* p = (char*)d_ws;
    auto alloc = [&](size_t bytes) { char* r = p; p += (bytes + 255) & ~(size_t)255; return r; };
    float* xtok = (float*)alloc((size_t)NTOK * DMODEL * 4);
    unsigned short* xzH = (unsigned short*)alloc((size_t)NTOK * 2 * DINNER * 2);
    float* dbc  = (float*)alloc((size_t)NTOK * 64 * 4);
    float* Pe   = (float*)alloc((size_t)NPTOK * DMODEL * 4);
    float* part = (float*)alloc((size_t)4 * NTOK * DMODEL * 4);
    char* ylnH = alloc((size_t)MPAD * DMODEL * 2);
    char* uH   = alloc((size_t)MPAD * DINNER * 2);
    char* gH   = alloc((size_t)MPAD * DINNER * 2);
    char* XpH  = alloc((size_t)MPAD * PDIM * 2);
    char* inTH  = alloc((size_t)NLAYER * 2 * DINNER * DMODEL * 2);
    char* outTH = alloc((size_t)NLAYER * DMODEL * DINNER * 2);
    char* patTH = alloc((size_t)DMODEL * PDIM * 2);
    char* xprTH = alloc((size_t)NLAYER * 128 * DINNER * 2);

    const size_t IN_T_B  = (size_t)2 * DINNER * DMODEL * 2;   // bytes/layer
    const size_t OUT_T_B = (size_t)DMODEL * DINNER * 2;
    const size_t XPR_T_B = (size_t)128 * DINNER * 2;

    // ---- one-time weight transpose + f16 cast (per call) ----
    k_wT<<<dim3(2 * DINNER / 32, DMODEL / 32, NLAYER), dim3(32, 8), 0, stream>>>(
        in_w, inTH, DMODEL, 2 * DINNER, (size_t)DMODEL * 2 * DINNER, IN_T_B);
    k_wT<<<dim3(DMODEL / 32, DINNER / 32, NLAYER), dim3(32, 8), 0, stream>>>(
        out_w, outTH, DINNER, DMODEL, (size_t)DINNER * DMODEL, OUT_T_B);
    k_wT<<<dim3(DMODEL / 32, PDIM / 32, 1), dim3(32, 8), 0, stream>>>(
        patch_w, patTH, PDIM, DMODEL, 0, 0);
    k_wT<<<dim3(128 / 32, DINNER / 32, NLAYER), dim3(32, 8), 0, stream>>>(
        xproj, xprTH, DINNER, 64, (size_t)DINNER * 64, XPR_T_B);

    // ---- patch embedding ----
    k_patch_ln<<<NPTOK, 256, 0, stream>>>(img, plnw, plnb, XpH);
    k_gemm_f16<false><<<dim3(4, 13, 4), 256, 0, stream>>>(
        XpH, patTH, part, nullptr, NPTOK, DMODEL, PDIM, 960, (long)NPTOK * DMODEL);
    k_reduce<4, false><<<(NPTOK * DMODEL + 255) / 256, 256, 0, stream>>>(
        part, Pe, NPTOK * DMODEL, NPTOK * DMODEL);
    k_assemble<<<(NTOK * DMODEL + 255) / 256, 256, 0, stream>>>(Pe, patch_b, cls, pos, xtok);

    // ---- mamba layers ----
    for (int i = 0; i < NLAYER; ++i) {
        if (i == 0) {
            k_ln<<<NTOK, 256, 0, stream>>>(xtok, ln_w, ln_b, ylnH);
        } else {
            k_red_ln<<<NTOK, 256, 0, stream>>>(part, xtok, ln_w + i * DMODEL,
                                               ln_b + i * DMODEL, ylnH);
        }
        k_gemm_f16<true><<<dim3(16, 13, 1), 256, 0, stream>>>(
            ylnH, inTH + i * IN_T_B, nullptr, xzH, NTOK, 2 * DINNER, DMODEL, DMODEL, 0);
        k_conv<<<(NTOK * (DINNER / 4) + 255) / 256, 256, 0, stream>>>(
            xzH, conv_w + (size_t)i * DINNER * 4, conv_b + (size_t)i * DINNER, uH);
        k_gemm_f16<false><<<dim3(1, 13, 8), 256, 0, stream>>>(
            uH, xprTH + i * XPR_T_B, part, nullptr, NTOK, 64, DINNER, 128, (long)NTOK * 64);
        k_reduce<8, false><<<(NTOK * 64 + 255) / 256, 256, 0, stream>>>(
            part, dbc, NTOK * 64, NTOK * 64);
        k_scan2<<<dim3(DINNER / 16, BATCH), 256, 0, stream>>>(
            uH, dbc, dt_w + (size_t)i * DRANK * DINNER, dt_b + (size_t)i * DINNER,
            A_log + (size_t)i * DINNER * NSTATE, Dp + (size_t)i * DINNER,
            xzH, gH);
        k_gemm_f16<false><<<dim3(4, 13, 4), 256, 0, stream>>>(
            gH, outTH + i * OUT_T_B, part, nullptr, NTOK, DMODEL, DINNER, 256,
            (long)NTOK * DMODEL);
    }
    // final residual reduce for layer 7's out_w
    k_reduce<4, true><<<(NTOK * DMODEL + 255) / 256, 256, 0, stream>>>(
        part, xtok, NTOK * DMODEL, NTOK * DMODEL);

    // ---- head ----
    k_head<<<dim3((NCLS + 255) / 256, BATCH), 256, 0, stream>>>(
        xtok, hlnw, hlnb, head_w, head_b, out);
}

// Round 11
// 574.374 us; speedup vs baseline: 6.0964x; 1.0699x over previous
//
#include <hip/hip_runtime.h>
#include <hip/hip_fp16.h>
#include <math.h>

#define BATCH   8
#define LSEQ    197
#define LPAD    200                // LSEQ padded to multiple of 8 for scan batches
#define NPATCH  196
#define NPTOK   (BATCH * NPATCH)   // 1568
#define NTOK    (BATCH * LSEQ)     // 1576
#define MPAD    1664               // 13*128, padded row count for f16 act arrays
#define DMODEL  512
#define DINNER  1024
#define NSTATE  16
#define DRANK   32
#define NLAYER  8
#define NCLS    1000
#define PDIM    3840               // 16*16*15

typedef _Float16 f16x8 __attribute__((ext_vector_type(8)));
typedef float    f32x4 __attribute__((ext_vector_type(4)));
typedef unsigned short us8 __attribute__((ext_vector_type(8)));

// Fast transcendentals (v_exp/v_log/v_rcp based; ~1e-7 rel err, fine vs 0.0156 absmax)
__device__ __forceinline__ float f_rcp(float x) { return __builtin_amdgcn_rcpf(x); }
__device__ __forceinline__ float sp_silu(float x) { return x * f_rcp(1.0f + __expf(-x)); }
__device__ __forceinline__ float sp_softplus(float x) {
    return x > 20.0f ? x : __logf(1.0f + __expf(x));
}

// N interleaved 16-lane row sums (row_shr DPP tree); lane 15 of each row gets
// the sum. dpp_ctrl must be a literal constant -> explicit 4-step expansion.
#define DPP_ROW_SHR_STEP(P, NB, CTRL)                                          \
    {                                                                          \
        float t_[NB];                                                          \
        _Pragma("unroll")                                                      \
        for (int i_ = 0; i_ < NB; ++i_)                                        \
            t_[i_] = __int_as_float(__builtin_amdgcn_update_dpp(               \
                0, __float_as_int(P[i_]), CTRL, 0xF, 0xF, true));              \
        _Pragma("unroll")                                                      \
        for (int i_ = 0; i_ < NB; ++i_) P[i_] += t_[i_];                       \
    }

template <int NB>
__device__ __forceinline__ void row_sum16v(float* p) {
    DPP_ROW_SHR_STEP(p, NB, 0x111);   // row_shr:1
    DPP_ROW_SHR_STEP(p, NB, 0x112);   // row_shr:2
    DPP_ROW_SHR_STEP(p, NB, 0x114);   // row_shr:4
    DPP_ROW_SHR_STEP(p, NB, 0x118);   // row_shr:8
}

// Store f16 value at swizzled position (row, k) of a [*][K] f16 array.
// Swizzle: byte-in-row ^= (row&7)<<4  (permutes 16B blocks within 128B chunks).
__device__ __forceinline__ void store_f16(char* __restrict__ Hb,
                                          int row, int k, int K, float v) {
    size_t byte = (size_t)row * (size_t)(K * 2) +
                  (size_t)(((unsigned)(k * 2)) ^ (unsigned)((row & 7) << 4));
    *(__half*)(Hb + byte) = __float2half_rn(v);
}

// 4 consecutive k (k4 multiple of 4): one 8B store (stays inside a 16B block).
__device__ __forceinline__ void store_f16x4(char* __restrict__ Hb,
                                            int row, int k4, int K, float4 v) {
    size_t byte = (size_t)row * (size_t)(K * 2) +
                  (size_t)(((unsigned)(k4 * 2)) ^ (unsigned)((row & 7) << 4));
    *(ushort4*)(Hb + byte) = make_ushort4(
        __half_as_ushort(__float2half_rn(v.x)), __half_as_ushort(__float2half_rn(v.y)),
        __half_as_ushort(__float2half_rn(v.z)), __half_as_ushort(__float2half_rn(v.w)));
}

// 256-thread block reduction of two values; lds must be 8 floats.
__device__ __forceinline__ float2 block_reduce2(float a, float b, float* lds) {
#pragma unroll
    for (int off = 32; off > 0; off >>= 1) {
        a += __shfl_down(a, off);
        b += __shfl_down(b, off);
    }
    int lane = threadIdx.x & 63, w = threadIdx.x >> 6;
    if (lane == 0) { lds[w] = a; lds[4 + w] = b; }
    __syncthreads();
    float sa = lds[0] + lds[1] + lds[2] + lds[3];
    float sb = lds[4] + lds[5] + lds[6] + lds[7];
    return make_float2(sa, sb);
}

// ---------------------------------------------------------------- patch stage
__global__ __launch_bounds__(256) void k_patch_ln(
    const float* __restrict__ img, const float* __restrict__ lnw,
    const float* __restrict__ lnb, char* __restrict__ Xph) {
    __shared__ float vals[PDIM];
    __shared__ float red[8];
    int tok = blockIdx.x;
    int b = tok / NPATCH, p = tok % NPATCH;
    int gy = p / 14, gx = p % 14;
    int tid = threadIdx.x;
    int py = tid >> 4, px = tid & 15;
    int h0 = gy * 16 + py, w0 = gx * 16 + px;
    const int dh[5] = {0, 0, 0, -1, 1};
    const int dw[5] = {0, -1, 1, 0, 0};
    float s = 0.f, ss = 0.f;
#pragma unroll
    for (int c = 0; c < 15; ++c) {
        int g = c / 3, ch = c % 3;
        int h = h0 + dh[g], w = w0 + dw[g];
        float v = 0.f;
        if ((unsigned)h < 224u && (unsigned)w < 224u)
            v = img[((b * 3 + ch) * 224 + h) * 224 + w];
        vals[tid * 15 + c] = v;
        s += v; ss += v * v;
    }
    float2 t2 = block_reduce2(s, ss, red);
    float mean = t2.x * (1.0f / PDIM);
    float var  = t2.y * (1.0f / PDIM) - mean * mean;
    float rstd = 1.0f / sqrtf(var + 1e-5f);
    for (int j = 0; j < 15; ++j) {
        int e = tid + j * 256;
        float v = (vals[e] - mean) * rstd * lnw[e] + lnb[e];
        store_f16(Xph, tok, e, PDIM, v);
    }
}

// ------------------------------------------------------------------- token LN
__global__ __launch_bounds__(256) void k_ln(
    const float* __restrict__ x, const float* __restrict__ w,
    const float* __restrict__ b, char* __restrict__ yh) {
    __shared__ float red[8];
    int t = blockIdx.x, tid = threadIdx.x;
    const float* xr = x + (size_t)t * DMODEL;
    float v0 = xr[tid], v1 = xr[tid + 256];
    float2 t2 = block_reduce2(v0 + v1, v0 * v0 + v1 * v1, red);
    float mean = t2.x * (1.0f / DMODEL);
    float var  = t2.y * (1.0f / DMODEL) - mean * mean;
    float rstd = 1.0f / sqrtf(var + 1e-5f);
    store_f16(yh, t, tid,       DMODEL, (v0 - mean) * rstd * w[tid]       + b[tid]);
    store_f16(yh, t, tid + 256, DMODEL, (v1 - mean) * rstd * w[tid + 256] + b[tid + 256]);
}

// ------------- fused: xtok += sum(part[0..3]); yln = LN(xtok) (f16 out)
__global__ __launch_bounds__(256) void k_red_ln(
    const float* __restrict__ part, float* __restrict__ xtok,
    const float* __restrict__ w, const float* __restrict__ b,
    char* __restrict__ yh) {
    __shared__ float red[8];
    int t = blockIdx.x, tid = threadIdx.x;
    size_t base = (size_t)t * DMODEL;
    float v0 = xtok[base + tid], v1 = xtok[base + tid + 256];
#pragma unroll
    for (int k = 0; k < 4; ++k) {
        v0 += part[(size_t)k * (NTOK * DMODEL) + base + tid];
        v1 += part[(size_t)k * (NTOK * DMODEL) + base + tid + 256];
    }
    xtok[base + tid] = v0;
    xtok[base + tid + 256] = v1;
    float2 t2 = block_reduce2(v0 + v1, v0 * v0 + v1 * v1, red);
    float mean = t2.x * (1.0f / DMODEL);
    float var  = t2.y * (1.0f / DMODEL) - mean * mean;
    float rstd = 1.0f / sqrtf(var + 1e-5f);
    store_f16(yh, t, tid,       DMODEL, (v0 - mean) * rstd * w[tid]       + b[tid]);
    store_f16(yh, t, tid + 256, DMODEL, (v1 - mean) * rstd * w[tid + 256] + b[tid + 256]);
}

// --------------------------------------------- weight transpose + f16 cast
__global__ __launch_bounds__(256) void k_wT(
    const float* __restrict__ W, char* __restrict__ Th,
    int Ks, int Ns, size_t wStride, size_t tByteStride) {
    __shared__ float t[32][33];
    int z = blockIdx.z;
    const float* Wz = W + (size_t)z * wStride;
    char* ThZ = Th + (size_t)z * tByteStride;
    int n0 = blockIdx.x * 32, k0 = blockIdx.y * 32;
    int tx = threadIdx.x, ty = threadIdx.y;
#pragma unroll
    for (int r = 0; r < 4; ++r) {
        int k = k0 + ty + r * 8, n = n0 + tx;
        t[tx][ty + r * 8] = (n < Ns) ? Wz[(size_t)k * Ns + n] : 0.f;
    }
    __syncthreads();
#pragma unroll
    for (int r = 0; r < 4; ++r) {
        int n = n0 + ty + r * 8, k = k0 + tx;
        float v = t[ty + r * 8][tx];
        size_t byte = (size_t)n * (size_t)(Ks * 2) +
                      (size_t)(((unsigned)(k * 2)) ^ (unsigned)((n & 7) << 4));
        *(__half*)(ThZ + byte) = __float2half_rn(v);
    }
}

// ------------------------------------------------- f16 single MFMA GEMM
// 128x128 tile, BK=64, dbuf LDS 64KB -> 2 blocks/CU. XCD-aware block remap.
// Counted vmcnt(8): next tile's 8 global_load_lds stay in flight across the
// barrier + MFMA phase (raw s_barrier; __syncthreads would drain vmcnt to 0).
// F16OUT: write C as f16 (plain [M][N] ushort) instead of fp32.
template <bool F16OUT>
__global__ __launch_bounds__(256, 2) void k_gemm_f16(
    const char* __restrict__ Ah, const char* __restrict__ Bh,
    float* __restrict__ C, unsigned short* __restrict__ C16,
    int M, int N, int K, int kchunk, long partStride) {
    __shared__ __half L[2][2][128 * 64];
    const int tid = threadIdx.x, w = tid >> 6, lane = tid & 63;

    // XCD-aware remap: hw-linear id -> contiguous chunk of (m-fastest) work order
    const int GX = gridDim.x, GY = gridDim.y;
    const int nwg = GX * GY * gridDim.z;
    const int orig = blockIdx.x + GX * (blockIdx.y + GY * blockIdx.z);
    const int q = nwg >> 3, r = nwg & 7, xcd = orig & 7, pos = orig >> 3;
    const int wrk = (xcd < r ? xcd * (q + 1) : r * (q + 1) + (xcd - r) * q) + pos;
    const int bm = wrk % GY;
    const int t1 = wrk / GY;
    const int bn = t1 % GX, bz = t1 / GX;

    const int m0 = bm * 128, n0 = bn * 128;
    const int kbeg = bz * kchunk;
    int kend = kbeg + kchunk; if (kend > K) kend = K;
    C += (size_t)bz * (size_t)partStride;
    const size_t K2 = (size_t)K * 2;
    const int srowBase = 32 * w;          // wave-uniform
    const int srLane = lane >> 3;         // 0..7
    const int scol = (lane & 7) * 16;

    f32x4 acc[4][4];
#pragma unroll
    for (int i = 0; i < 4; ++i)
#pragma unroll
        for (int j = 0; j < 4; ++j) acc[i][j] = (f32x4)(0.f);

    auto STAGE = [&](int buf, int k0) {   // 8 global_load_lds per wave
#pragma unroll
        for (int t = 0; t < 4; ++t) {
            int lr = srowBase + 8 * t;                 // uniform LDS row base
            size_t ao = (size_t)(m0 + lr + srLane) * K2 + (size_t)k0 * 2 + scol;
            size_t bo = (size_t)(n0 + lr + srLane) * K2 + (size_t)k0 * 2 + scol;
            __builtin_amdgcn_global_load_lds(
                (const __attribute__((address_space(1))) void*)(Ah + ao),
                (__attribute__((address_space(3))) void*)&L[buf][0][lr * 64], 16, 0, 0);
            __builtin_amdgcn_global_load_lds(
                (const __attribute__((address_space(1))) void*)(Bh + bo),
                (__attribute__((address_space(3))) void*)&L[buf][1][lr * 64], 16, 0, 0);
        }
    };

    const int wr = (w >> 1) * 64, wc = (w & 1) * 64;
    const int g = lane >> 4, rr = lane & 15;
    const int nk = (kend - kbeg + 63) / 64;

    STAGE(0, kbeg);

    for (int t = 0; t < nk; ++t) {
        int cur = t & 1;
        if (t + 1 < nk) {
            STAGE(cur ^ 1, kbeg + (t + 1) * 64);
            asm volatile("s_waitcnt vmcnt(8)" ::: "memory");  // cur's loads done
        } else {
            asm volatile("s_waitcnt vmcnt(0)" ::: "memory");
        }
        __builtin_amdgcn_s_barrier();
        const __half* LA = L[cur][0];
        const __half* LB = L[cur][1];
#pragma unroll
        for (int kk = 0; kk < 2; ++kk) {
            f16x8 af[4], bf[4];
#pragma unroll
            for (int mf = 0; mf < 4; ++mf) {
                int row = wr + mf * 16 + rr;
                int off = row * 128 + ((kk * 64 + g * 16) ^ ((row & 7) << 4));
                af[mf] = *(const f16x8*)((const char*)LA + off);
            }
#pragma unroll
            for (int nf = 0; nf < 4; ++nf) {
                int row = wc + nf * 16 + rr;
                int off = row * 128 + ((kk * 64 + g * 16) ^ ((row & 7) << 4));
                bf[nf] = *(const f16x8*)((const char*)LB + off);
            }
#pragma unroll
            for (int mf = 0; mf < 4; ++mf)
#pragma unroll
                for (int nf = 0; nf < 4; ++nf)
                    acc[mf][nf] = __builtin_amdgcn_mfma_f32_16x16x32_f16(
                        af[mf], bf[nf], acc[mf][nf], 0, 0, 0);
        }
        // all ds_reads consumed (compiler lgkm waits precede MFMA uses);
        // barrier before next iteration's STAGE overwrites L[cur]
        __builtin_amdgcn_s_barrier();
    }

#pragma unroll
    for (int mf = 0; mf < 4; ++mf)
#pragma unroll
        for (int nf = 0; nf < 4; ++nf)
#pragma unroll
            for (int e = 0; e < 4; ++e) {
                int gm = m0 + wr + mf * 16 + g * 4 + e;
                int gn = n0 + wc + nf * 16 + rr;
                if (gm < M && gn < N) {
                    if (F16OUT)
                        C16[(size_t)gm * N + gn] =
                            __half_as_ushort(__float2half_rn(acc[mf][nf][e]));
                    else
                        C[(size_t)gm * N + gn] = acc[mf][nf][e];
                }
            }
}

// ------------------------------------------------------ split-K reduce
template <int SK, bool ACC>
__global__ __launch_bounds__(256) void k_reduce(
    const float* __restrict__ part, float* __restrict__ out, int total, int stride) {
    int i = blockIdx.x * 256 + threadIdx.x;
    if (i >= total) return;
    float s = 0.f;
#pragma unroll
    for (int k = 0; k < SK; ++k) s += part[(size_t)k * stride + i];
    out[i] = ACC ? out[i] + s : s;
}

// ---------------------------------------------- assemble tokens (+cls, +pos)
__global__ __launch_bounds__(256) void k_assemble(
    const float* __restrict__ Pe, const float* __restrict__ patch_b,
    const float* __restrict__ cls, const float* __restrict__ pos,
    float* __restrict__ xtok) {
    int idx = blockIdx.x * 256 + threadIdx.x;
    if (idx >= NTOK * DMODEL) return;
    int d = idx % DMODEL;
    int t = (idx / DMODEL) % LSEQ;
    int b = idx / (DMODEL * LSEQ);
    float v = (t < NPATCH) ? (Pe[((size_t)b * NPATCH + t) * DMODEL + d] + patch_b[d])
                           : cls[d];
    xtok[idx] = v + pos[t * DMODEL + d];
}

// ------------- causal depthwise conv (K=4) + SiLU, f16 in/out, 4 d's/thread
__global__ __launch_bounds__(256) void k_conv(
    const unsigned short* __restrict__ xzH, const float* __restrict__ cw,
    const float* __restrict__ cb, char* __restrict__ uh) {
    int idx = blockIdx.x * 256 + threadIdx.x;
    if (idx >= NTOK * (DINNER / 4)) return;
    int dq = idx & (DINNER / 4 - 1);
    int t  = idx / (DINNER / 4);
    int l  = t % LSEQ;
    int d  = dq * 4;
    float4 w0 = *(const float4*)&cw[(d + 0) * 4];
    float4 w1 = *(const float4*)&cw[(d + 1) * 4];
    float4 w2 = *(const float4*)&cw[(d + 2) * 4];
    float4 w3 = *(const float4*)&cw[(d + 3) * 4];
    float4 acc = *(const float4*)&cb[d];
#pragma unroll
    for (int j = 0; j < 4; ++j) {
        int ls = l - 3 + j;
        if (ls >= 0) {
            union { ushort4 v; __half h[4]; } xu;
            xu.v = *(const ushort4*)&xzH[(size_t)(t - 3 + j) * (2 * DINNER) + d];
            acc.x += (&w0.x)[j] * __half2float(xu.h[0]);
            acc.y += (&w1.x)[j] * __half2float(xu.h[1]);
            acc.z += (&w2.x)[j] * __half2float(xu.h[2]);
            acc.w += (&w3.x)[j] * __half2float(xu.h[3]);
        }
    }
    float4 uv = make_float4(sp_silu(acc.x), sp_silu(acc.y),
                            sp_silu(acc.z), sp_silu(acc.w));
    store_f16x4(uh, t, d, DINNER, uv);
}

// ------- selective scan v6: fused dt-proj + LDS stage (f16 u) + pipelined
// batch-8 recurrence with interleaved DPP rowsums + fused gate (f16 z/out).
// grid (DINNER/16, BATCH), 256 thr.
__global__ __launch_bounds__(256) void k_scan2(
    const char* __restrict__ uH, const float* __restrict__ dbc,
    const float* __restrict__ dtw, const float* __restrict__ dtb,
    const float* __restrict__ Alog, const float* __restrict__ Dp,
    const unsigned short* __restrict__ xzH, char* __restrict__ gh) {
    __shared__ float uS[LPAD * 16];
    __shared__ float dS[LPAD * 16];   // dt in, y out (slot l dead after iter l)
    __shared__ float bS[LPAD * 16];
    __shared__ float cS[LPAD * 16];
    __shared__ float wS[DRANK * 16];  // dt_w columns d0..d0+15
    const int tid = threadIdx.x;
    const int b = blockIdx.y, d0 = blockIdx.x * 16;

    // phase 0: dtw columns to LDS
    for (int i = tid; i < DRANK * 16; i += 256)
        wS[i] = dtw[(size_t)(i >> 4) * DINNER + d0 + (i & 15)];
    __syncthreads();

    // phase 1a: stage u (f16 swizzled -> fp32 LDS); zero-fill pad rows
    for (int i = tid; i < LPAD * 2; i += 256) {
        int l = i >> 1, jj = i & 1;
        float* dst = &uS[l * 16 + jj * 8];
        if (l >= LSEQ) {
#pragma unroll
            for (int e = 0; e < 8; ++e) dst[e] = 0.f;
            continue;
        }
        int t = b * LSEQ + l;
        size_t byte = (size_t)t * (DINNER * 2) +
                      (size_t)(((unsigned)(d0 * 2 + jj * 16)) ^ (unsigned)((t & 7) << 4));
        union { us8 v; __half h[8]; } uu;
        uu.v = *(const us8*)(uH + byte);
#pragma unroll
        for (int e = 0; e < 8; ++e) dst[e] = __half2float(uu.h[e]);
    }

    // phase 1b: stage B/C, compute dt = softplus(r@dtw + b); zero-fill pad rows
    const float* dbcB = dbc + ((size_t)b * LSEQ) * 64;
    for (int i = tid; i < LPAD * 4; i += 256) {
        int l = i >> 2, j = (i & 3) << 2;
        if (l >= LSEQ) {
            float4 z = make_float4(0.f, 0.f, 0.f, 0.f);
            *(float4*)&dS[l * 16 + j] = z;
            *(float4*)&bS[l * 16 + j] = z;
            *(float4*)&cS[l * 16 + j] = z;
            continue;
        }
        *(float4*)&bS[l * 16 + j] = *(const float4*)&dbcB[(size_t)l * 64 + DRANK + j];
        *(float4*)&cS[l * 16 + j] = *(const float4*)&dbcB[(size_t)l * 64 + DRANK + 16 + j];
        float4 acc = *(const float4*)&dtb[d0 + j];
#pragma unroll
        for (int kq = 0; kq < DRANK / 4; ++kq) {
            float4 r4 = *(const float4*)&dbcB[(size_t)l * 64 + kq * 4];
#pragma unroll
            for (int m = 0; m < 4; ++m) {
                float rv = (&r4.x)[m];
                float4 w4 = *(const float4*)&wS[(kq * 4 + m) * 16 + j];
                acc.x += rv * w4.x; acc.y += rv * w4.y;
                acc.z += rv * w4.z; acc.w += rv * w4.w;
            }
        }
        dS[l * 16 + j + 0] = sp_softplus(acc.x);
        dS[l * 16 + j + 1] = sp_softplus(acc.y);
        dS[l * 16 + j + 2] = sp_softplus(acc.z);
        dS[l * 16 + j + 3] = sp_softplus(acc.w);
    }
    const int n = tid & 15, dsub = tid >> 4;
    const int d = d0 + dsub;
    const float A  = -__expf(Alog[d * NSTATE + n]);
    const float Dv = Dp[d];
    __syncthreads();

    // phase 2: batch-8 software-pipelined recurrence.
    // dsub columns are wave-private, so in-loop dS y-writes never race.
    float hn = 0.f;
    float dtc[8], uvc[8], Bnc[8], Cnc[8];
#pragma unroll
    for (int i = 0; i < 8; ++i) {
        int o = i * 16;
        dtc[i] = dS[o + dsub]; uvc[i] = uS[o + dsub];
        Bnc[i] = bS[o + n];    Cnc[i] = cS[o + n];
    }
    for (int lb = 0; lb < LPAD; lb += 8) {
        float dtN[8], uvN[8], BnN[8], CnN[8];
        if (lb + 8 < LPAD) {
#pragma unroll
            for (int i = 0; i < 8; ++i) {
                int o = (lb + 8 + i) * 16;
                dtN[i] = dS[o + dsub]; uvN[i] = uS[o + dsub];
                BnN[i] = bS[o + n];    CnN[i] = cS[o + n];
            }
        } else {
#pragma unroll
            for (int i = 0; i < 8; ++i) { dtN[i] = uvN[i] = BnN[i] = CnN[i] = 0.f; }
        }
        float a8[8], b8[8], p8[8];
#pragma unroll
        for (int i = 0; i < 8; ++i) {
            a8[i] = __expf(dtc[i] * A);
            b8[i] = dtc[i] * uvc[i] * Bnc[i];
        }
#pragma unroll
        for (int i = 0; i < 8; ++i) {
            hn = a8[i] * hn + b8[i];
            p8[i] = hn * Cnc[i];
        }
        row_sum16v<8>(p8);
#pragma unroll
        for (int i = 0; i < 8; ++i)
            if (n == 15) dS[(lb + i) * 16 + dsub] = p8[i] + uvc[i] * Dv;
#pragma unroll
        for (int i = 0; i < 8; ++i) {
            dtc[i] = dtN[i]; uvc[i] = uvN[i]; Bnc[i] = BnN[i]; Cnc[i] = CnN[i];
        }
    }
    __syncthreads();

    // phase 3: fused gate g = y * silu(z); z from f16 xz, vectorized f16 stores
    for (int i = tid; i < LSEQ * 4; i += 256) {
        int l = i >> 2, j = (i & 3) << 2;
        int t = b * LSEQ + l;
        union { ushort4 v; __half h[4]; } zu;
        zu.v = *(const ushort4*)&xzH[(size_t)t * (2 * DINNER) + DINNER + d0 + j];
        float4 g4 = make_float4(
            dS[l * 16 + j + 0] * sp_silu(__half2float(zu.h[0])),
            dS[l * 16 + j + 1] * sp_silu(__half2float(zu.h[1])),
            dS[l * 16 + j + 2] * sp_silu(__half2float(zu.h[2])),
            dS[l * 16 + j + 3] * sp_silu(__half2float(zu.h[3])));
        store_f16x4(gh, t, d0 + j, DINNER, g4);
    }
}

// ------------- head stage 1: final residual reduce (8 rows only) + LN -> xr
__global__ __launch_bounds__(256) void k_head_ln(
    const float* __restrict__ part, const float* __restrict__ xtok,
    const float* __restrict__ lnw, const float* __restrict__ lnb,
    float* __restrict__ xr) {
    __shared__ float red[8];
    int b = blockIdx.x, tid = threadIdx.x;
    size_t base = ((size_t)(b * LSEQ + NPATCH)) * DMODEL;
    float v0 = xtok[base + tid], v1 = xtok[base + tid + 256];
#pragma unroll
    for (int k = 0; k < 4; ++k) {
        v0 += part[(size_t)k * (NTOK * DMODEL) + base + tid];
        v1 += part[(size_t)k * (NTOK * DMODEL) + base + tid + 256];
    }
    float2 t2 = block_reduce2(v0 + v1, v0 * v0 + v1 * v1, red);
    float mean = t2.x * (1.0f / DMODEL);
    float var  = t2.y * (1.0f / DMODEL) - mean * mean;
    float rstd = 1.0f / sqrtf(var + 1e-5f);
    xr[b * DMODEL + tid]       = (v0 - mean) * rstd * lnw[tid] + lnb[tid];
    xr[b * DMODEL + tid + 256] = (v1 - mean) * rstd * lnw[tid + 256] + lnb[tid + 256];
}

// ------------- head stage 2: k-split FC partials. grid (4, BATCH, 8)
__global__ __launch_bounds__(256) void k_head_fc(
    const float* __restrict__ xr, const float* __restrict__ hw,
    float* __restrict__ hpart) {
    __shared__ float xs[64];
    int tid = threadIdx.x;
    int c = blockIdx.x * 256 + tid;
    int b = blockIdx.y, ks = blockIdx.z;
    if (tid < 64) xs[tid] = xr[b * DMODEL + ks * 64 + tid];
    __syncthreads();
    if (c >= NCLS) return;
    float acc = 0.f;
#pragma unroll 8
    for (int k = 0; k < 64; ++k) acc += xs[k] * hw[(size_t)(ks * 64 + k) * NCLS + c];
    hpart[(size_t)(ks * BATCH + b) * NCLS + c] = acc;
}

// ------------- head stage 3: sum 8 partials + bias -> out
__global__ __launch_bounds__(256) void k_head_red(
    const float* __restrict__ hpart, const float* __restrict__ hb,
    float* __restrict__ out) {
    int i = blockIdx.x * 256 + threadIdx.x;
    if (i >= BATCH * NCLS) return;
    int b = i / NCLS, c = i % NCLS;
    float s = hb[c];
#pragma unroll
    for (int ks = 0; ks < 8; ++ks) s += hpart[(size_t)(ks * BATCH + b) * NCLS + c];
    out[i] = s;
}

extern "C" void kernel_launch(void* const* d_in, const int* in_sizes, int n_in,
                              void* d_out, int out_size, void* d_ws, size_t ws_size,
                              hipStream_t stream) {
    const float* img     = (const float*)d_in[0];
    const float* plnw    = (const float*)d_in[1];
    const float* plnb    = (const float*)d_in[2];
    const float* patch_w = (const float*)d_in[3];
    const float* patch_b = (const float*)d_in[4];
    const float* pos     = (const float*)d_in[5];
    const float* cls     = (const float*)d_in[6];
    const float* ln_w    = (const float*)d_in[7];
    const float* ln_b    = (const float*)d_in[8];
    const float* in_w    = (const float*)d_in[9];
    const float* conv_w  = (const float*)d_in[10];
    const float* conv_b  = (const float*)d_in[11];
    const float* xproj   = (const float*)d_in[12];
    const float* dt_w    = (const float*)d_in[13];
    const float* dt_b    = (const float*)d_in[14];
    const float* A_log   = (const float*)d_in[15];
    const float* Dp      = (const float*)d_in[16];
    const float* out_w   = (const float*)d_in[17];
    const float* hlnw    = (const float*)d_in[18];
    const float* hlnb    = (const float*)d_in[19];
    const float* head_w  = (const float*)d_in[20];
    const float* head_b  = (const float*)d_in[21];
    float* out = (float*)d_out;

    char* p = (char*)d_ws;
    auto alloc = [&](size_t bytes) { char* r = p; p += (bytes + 255) & ~(size_t)255; return r; };
    float* xtok = (float*)alloc((size_t)NTOK * DMODEL * 4);
    unsigned short* xzH = (unsigned short*)alloc((size_t)NTOK * 2 * DINNER * 2);
    float* dbc  = (float*)alloc((size_t)NTOK * 64 * 4);
    float* Pe   = (float*)alloc((size_t)NPTOK * DMODEL * 4);
    float* part = (float*)alloc((size_t)4 * NTOK * DMODEL * 4);
    float* xr   = (float*)alloc((size_t)BATCH * DMODEL * 4);
    float* hpart= (float*)alloc((size_t)8 * BATCH * NCLS * 4);
    char* ylnH = alloc((size_t)MPAD * DMODEL * 2);
    char* uH   = alloc((size_t)MPAD * DINNER * 2);
    char* gH   = alloc((size_t)MPAD * DINNER * 2);
    char* XpH  = alloc((size_t)MPAD * PDIM * 2);
    char* inTH  = alloc((size_t)NLAYER * 2 * DINNER * DMODEL * 2);
    char* outTH = alloc((size_t)NLAYER * DMODEL * DINNER * 2);
    char* patTH = alloc((size_t)DMODEL * PDIM * 2);
    char* xprTH = alloc((size_t)NLAYER * 128 * DINNER * 2);

    const size_t IN_T_B  = (size_t)2 * DINNER * DMODEL * 2;   // bytes/layer
    const size_t OUT_T_B = (size_t)DMODEL * DINNER * 2;
    const size_t XPR_T_B = (size_t)128 * DINNER * 2;

    // ---- one-time weight transpose + f16 cast (per call) ----
    k_wT<<<dim3(2 * DINNER / 32, DMODEL / 32, NLAYER), dim3(32, 8), 0, stream>>>(
        in_w, inTH, DMODEL, 2 * DINNER, (size_t)DMODEL * 2 * DINNER, IN_T_B);
    k_wT<<<dim3(DMODEL / 32, DINNER / 32, NLAYER), dim3(32, 8), 0, stream>>>(
        out_w, outTH, DINNER, DMODEL, (size_t)DINNER * DMODEL, OUT_T_B);
    k_wT<<<dim3(DMODEL / 32, PDIM / 32, 1), dim3(32, 8), 0, stream>>>(
        patch_w, patTH, PDIM, DMODEL, 0, 0);
    k_wT<<<dim3(128 / 32, DINNER / 32, NLAYER), dim3(32, 8), 0, stream>>>(
        xproj, xprTH, DINNER, 64, (size_t)DINNER * 64, XPR_T_B);

    // ---- patch embedding ----
    k_patch_ln<<<NPTOK, 256, 0, stream>>>(img, plnw, plnb, XpH);
    k_gemm_f16<false><<<dim3(4, 13, 4), 256, 0, stream>>>(
        XpH, patTH, part, nullptr, NPTOK, DMODEL, PDIM, 960, (long)NPTOK * DMODEL);
    k_reduce<4, false><<<(NPTOK * DMODEL + 255) / 256, 256, 0, stream>>>(
        part, Pe, NPTOK * DMODEL, NPTOK * DMODEL);
    k_assemble<<<(NTOK * DMODEL + 255) / 256, 256, 0, stream>>>(Pe, patch_b, cls, pos, xtok);

    // ---- mamba layers ----
    for (int i = 0; i < NLAYER; ++i) {
        if (i == 0) {
            k_ln<<<NTOK, 256, 0, stream>>>(xtok, ln_w, ln_b, ylnH);
        } else {
            k_red_ln<<<NTOK, 256, 0, stream>>>(part, xtok, ln_w + i * DMODEL,
                                               ln_b + i * DMODEL, ylnH);
        }
        k_gemm_f16<true><<<dim3(16, 13, 1), 256, 0, stream>>>(
            ylnH, inTH + i * IN_T_B, nullptr, xzH, NTOK, 2 * DINNER, DMODEL, DMODEL, 0);
        k_conv<<<(NTOK * (DINNER / 4) + 255) / 256, 256, 0, stream>>>(
            xzH, conv_w + (size_t)i * DINNER * 4, conv_b + (size_t)i * DINNER, uH);
        k_gemm_f16<false><<<dim3(1, 13, 8), 256, 0, stream>>>(
            uH, xprTH + i * XPR_T_B, part, nullptr, NTOK, 64, DINNER, 128, (long)NTOK * 64);
        k_reduce<8, false><<<(NTOK * 64 + 255) / 256, 256, 0, stream>>>(
            part, dbc, NTOK * 64, NTOK * 64);
        k_scan2<<<dim3(DINNER / 16, BATCH), 256, 0, stream>>>(
            uH, dbc, dt_w + (size_t)i * DRANK * DINNER, dt_b + (size_t)i * DINNER,
            A_log + (size_t)i * DINNER * NSTATE, Dp + (size_t)i * DINNER,
            xzH, gH);
        k_gemm_f16<false><<<dim3(4, 13, 4), 256, 0, stream>>>(
            gH, outTH + i * OUT_T_B, part, nullptr, NTOK, DMODEL, DINNER, 256,
            (long)NTOK * DMODEL);
    }

    // ---- head: residual reduce (8 rows) + LN, k-split FC, reduce ----
    k_head_ln<<<BATCH, 256, 0, stream>>>(part, xtok, hlnw, hlnb, xr);
    k_head_fc<<<dim3(4, BATCH, 8), 256, 0, stream>>>(xr, head_w, hpart);
    k_head_red<<<(BATCH * NCLS + 255) / 256, 256, 0, stream>>>(hpart, head_b, out);
}